// Round 1
// 523.708 us; speedup vs baseline: 1.2083x; 1.2083x over previous
//
#include <hip/hip_runtime.h>

// ---------------------------------------------------------------------------
// Problem constants
// ---------------------------------------------------------------------------
#define N_PFAS 20000
#define N_GW   100000
#define N_SW   30000
#define E_PG   1600000
#define E_GP   640000
#define E_PS   480000
#define E_SP   320000
#define E_TOT  (E_PG + E_PS + E_GP + E_SP)
// Concatenated node-count layout: [pg: N_GW][ps: N_SW][gp: N_PFAS][sp: N_PFAS]
#define BASE_PG 0
#define BASE_PS (N_GW)
#define BASE_GP (N_GW + N_SW)
#define BASE_SP (N_GW + N_SW + N_PFAS)
#define NTOT    (N_GW + N_SW + 2 * N_PFAS)
// Bucketed permute: 256 nodes per bucket.
#define NB        ((NTOT + 255) / 256)       // 665
#define BIN_EPT   12
#define BIN_EPB   (1024 * BIN_EPT)
#define BIN_NBLK  ((E_TOT + BIN_EPB - 1) / BIN_EPB)
#define SEG_CAP   15360
#define H_NBLK    128                        // bucket-hist grid
// Unified transform pass tiles (128 rows each)
#define TILES_PF  ((N_PFAS + 127) / 128)     // 157
#define TILES_GW  ((N_GW + 127) / 128)       // 782
#define TILES_SW  ((N_SW + 127) / 128)       // 235
#define TILES_ALL (2 * TILES_PF + TILES_GW + TILES_SW)

// ---------------------------------------------------------------------------
// bf16 helpers
// ---------------------------------------------------------------------------
__device__ __forceinline__ unsigned short f2bf(float f) {
    unsigned u = __float_as_uint(f);
    u += 0x7fffu + ((u >> 16) & 1u);
    return (unsigned short)(u >> 16);
}
__device__ __forceinline__ float u2f(unsigned u) { return __uint_as_float(u); }

// ---------------------------------------------------------------------------
// GEMM tile: NT threads, ROWS rows/block, 32-k chunks in LDS.
// acc must be compile-time indexed by callers (dynamic indexing -> scratch!).
// ---------------------------------------------------------------------------
template<int NT, int ROWS>
__device__ __forceinline__ void tile_gemm(
    const float* __restrict__ X, const float* __restrict__ Wa,
    const float* __restrict__ Wb, int n, int row0, int tid,
    float4* sW4, float* sX, float4* acc)
{
    constexpr int TY  = NT / 32;
    constexpr int RPT = ROWS / TY;
    const int tx = tid & 31;
    const int ty = tid >> 5;
    const float4* X4 = (const float4*)X;
    const float4* Wa4 = (const float4*)Wa;
    const float4* Wb4 = (const float4*)Wb;

    for (int kc = 0; kc < 4; ++kc) {
        __syncthreads();
        for (int i = tid; i < 1024; i += NT) {
            float4 w = Wa4[kc * 1024 + i];
            if (Wb) {
                float4 b = Wb4[kc * 1024 + i];
                w.x += b.x; w.y += b.y; w.z += b.z; w.w += b.w;
            }
            sW4[i] = w;
        }
        for (int j = tid; j < ROWS * 8; j += NT) {
            int rr = j >> 3, k4 = j & 7;
            int r = row0 + rr;
            float4 xv = make_float4(0.f, 0.f, 0.f, 0.f);
            if (r < n) xv = X4[(size_t)r * 32 + kc * 8 + k4];
            int kk = k4 * 4;
            sX[(kk + 0) * ROWS + rr] = xv.x;
            sX[(kk + 1) * ROWS + rr] = xv.y;
            sX[(kk + 2) * ROWS + rr] = xv.z;
            sX[(kk + 3) * ROWS + rr] = xv.w;
        }
        __syncthreads();
#pragma unroll 4
        for (int k = 0; k < 32; ++k) {
            float4 w4 = sW4[k * 32 + tx];
            const float4* xr4 = (const float4*)&sX[k * ROWS + ty * RPT];
#pragma unroll
            for (int q = 0; q < RPT / 4; ++q) {
                float4 x4 = xr4[q];
                acc[q * 4 + 0].x += x4.x * w4.x; acc[q * 4 + 0].y += x4.x * w4.y;
                acc[q * 4 + 0].z += x4.x * w4.z; acc[q * 4 + 0].w += x4.x * w4.w;
                acc[q * 4 + 1].x += x4.y * w4.x; acc[q * 4 + 1].y += x4.y * w4.y;
                acc[q * 4 + 1].z += x4.y * w4.z; acc[q * 4 + 1].w += x4.y * w4.w;
                acc[q * 4 + 2].x += x4.z * w4.x; acc[q * 4 + 2].y += x4.z * w4.y;
                acc[q * 4 + 2].z += x4.z * w4.z; acc[q * 4 + 2].w += x4.z * w4.w;
                acc[q * 4 + 3].x += x4.w * w4.x; acc[q * 4 + 3].y += x4.w * w4.y;
                acc[q * 4 + 3].z += x4.w * w4.z; acc[q * 4 + 3].w += x4.w * w4.w;
            }
        }
    }
}

// ---------------------------------------------------------------------------
// Unified transform pass: bufT_* = X @ Wl  (bf16 out) for all 4 relations.
// 1331 blocks of 128 rows.
// ---------------------------------------------------------------------------
__global__ __launch_bounds__(256, 2) void gemm_t16_all_kernel(
    const float* __restrict__ x_pfas, const float* __restrict__ x_gw,
    const float* __restrict__ x_sw,
    const float* __restrict__ Wl_pg, const float* __restrict__ Wl_ps,
    const float* __restrict__ Wl_gp, const float* __restrict__ Wl_sp,
    unsigned short* __restrict__ bufT_pg, unsigned short* __restrict__ bufT_ps,
    unsigned short* __restrict__ bufT_gp, unsigned short* __restrict__ bufT_sp)
{
    __shared__ float sW[32 * 128];
    __shared__ float sX[32 * 128];
    const int b = blockIdx.x;
    const float* X; const float* W; unsigned short* out; int n; int tile;
    if (b < TILES_PF)            { X = x_pfas; W = Wl_pg; out = bufT_pg; n = N_PFAS; tile = b; }
    else if (b < 2 * TILES_PF)   { X = x_pfas; W = Wl_ps; out = bufT_ps; n = N_PFAS; tile = b - TILES_PF; }
    else if (b < 2 * TILES_PF + TILES_GW)
                                 { X = x_gw;   W = Wl_gp; out = bufT_gp; n = N_GW;   tile = b - 2 * TILES_PF; }
    else                         { X = x_sw;   W = Wl_sp; out = bufT_sp; n = N_SW;   tile = b - 2 * TILES_PF - TILES_GW; }
    const int tid = threadIdx.x;
    const int row0 = tile * 128;

    float4 acc[16];
#pragma unroll
    for (int i = 0; i < 16; ++i) acc[i] = make_float4(0.f, 0.f, 0.f, 0.f);
    tile_gemm<256, 128>(X, W, nullptr, n, row0, tid, (float4*)sW, sX, acc);

    const int tx = tid & 31;
    const int rbase = row0 + (tid >> 5) * 16;
#pragma unroll
    for (int rr = 0; rr < 16; ++rr) {
        int r = rbase + rr;
        if (r < n) {
            uint2 o;
            o.x = (unsigned)f2bf(acc[rr].x) | ((unsigned)f2bf(acc[rr].y) << 16);
            o.y = (unsigned)f2bf(acc[rr].z) | ((unsigned)f2bf(acc[rr].w) << 16);
            *(uint2*)(out + (size_t)r * 128 + tx * 4) = o;
        }
    }
}

// ---------------------------------------------------------------------------
// gw/sw node pass: 256 threads, 64 rows/block. GEMM X@Wr fused with 8-ILP
// CSR gather of bf16 transformed neighbor rows + scalar head.
// ---------------------------------------------------------------------------
__global__ __launch_bounds__(256, 4) void gemm_gather_scalar_kernel(
    int n, const float* __restrict__ X, const float* __restrict__ Wr,
    const float* __restrict__ bl,
    const unsigned short* __restrict__ bufT16, const int* __restrict__ perm,
    const int* __restrict__ off,
    const float* __restrict__ wout, const float* __restrict__ bout,
    float* __restrict__ out)
{
    __shared__ float sW[32 * 128];
    __shared__ float sX[32 * 64];
    const int tid = threadIdx.x;
    const int row0 = blockIdx.x * 64;
    float4 acc[8];
#pragma unroll
    for (int i = 0; i < 8; ++i) acc[i] = make_float4(0.f, 0.f, 0.f, 0.f);
    tile_gemm<256, 64>(X, Wr, nullptr, n, row0, tid, (float4*)sW, sX, acc);

    const int tx = tid & 31;
    const int rbase = row0 + (tid >> 5) * 8;
    float4 bv = ((const float4*)bl)[tx];
    float4 wo = ((const float4*)wout)[tx];
    float bo = bout[0];

#pragma unroll
    for (int rr = 0; rr < 8; ++rr) {
        int r = rbase + rr;
        int lo = 0, hi = 0;
        if (r < n) { lo = off[r]; hi = off[r + 1]; }
        float4 s0 = make_float4(0.f, 0.f, 0.f, 0.f);
        float4 s1 = make_float4(0.f, 0.f, 0.f, 0.f);
        float4 s2 = make_float4(0.f, 0.f, 0.f, 0.f);
        float4 s3 = make_float4(0.f, 0.f, 0.f, 0.f);
        int i = lo;
        for (; i + 8 <= hi; i += 8) {
            uint2 v0 = *(const uint2*)(bufT16 + (size_t)perm[i + 0] * 128 + tx * 4);
            uint2 v1 = *(const uint2*)(bufT16 + (size_t)perm[i + 1] * 128 + tx * 4);
            uint2 v2 = *(const uint2*)(bufT16 + (size_t)perm[i + 2] * 128 + tx * 4);
            uint2 v3 = *(const uint2*)(bufT16 + (size_t)perm[i + 3] * 128 + tx * 4);
            uint2 v4 = *(const uint2*)(bufT16 + (size_t)perm[i + 4] * 128 + tx * 4);
            uint2 v5 = *(const uint2*)(bufT16 + (size_t)perm[i + 5] * 128 + tx * 4);
            uint2 v6 = *(const uint2*)(bufT16 + (size_t)perm[i + 6] * 128 + tx * 4);
            uint2 v7 = *(const uint2*)(bufT16 + (size_t)perm[i + 7] * 128 + tx * 4);
            s0.x += u2f(v0.x << 16); s0.y += u2f(v0.x & 0xffff0000u);
            s0.z += u2f(v0.y << 16); s0.w += u2f(v0.y & 0xffff0000u);
            s1.x += u2f(v1.x << 16); s1.y += u2f(v1.x & 0xffff0000u);
            s1.z += u2f(v1.y << 16); s1.w += u2f(v1.y & 0xffff0000u);
            s2.x += u2f(v2.x << 16); s2.y += u2f(v2.x & 0xffff0000u);
            s2.z += u2f(v2.y << 16); s2.w += u2f(v2.y & 0xffff0000u);
            s3.x += u2f(v3.x << 16); s3.y += u2f(v3.x & 0xffff0000u);
            s3.z += u2f(v3.y << 16); s3.w += u2f(v3.y & 0xffff0000u);
            s0.x += u2f(v4.x << 16); s0.y += u2f(v4.x & 0xffff0000u);
            s0.z += u2f(v4.y << 16); s0.w += u2f(v4.y & 0xffff0000u);
            s1.x += u2f(v5.x << 16); s1.y += u2f(v5.x & 0xffff0000u);
            s1.z += u2f(v5.y << 16); s1.w += u2f(v5.y & 0xffff0000u);
            s2.x += u2f(v6.x << 16); s2.y += u2f(v6.x & 0xffff0000u);
            s2.z += u2f(v6.y << 16); s2.w += u2f(v6.y & 0xffff0000u);
            s3.x += u2f(v7.x << 16); s3.y += u2f(v7.x & 0xffff0000u);
            s3.z += u2f(v7.y << 16); s3.w += u2f(v7.y & 0xffff0000u);
        }
        for (; i + 2 <= hi; i += 2) {
            uint2 v0 = *(const uint2*)(bufT16 + (size_t)perm[i + 0] * 128 + tx * 4);
            uint2 v1 = *(const uint2*)(bufT16 + (size_t)perm[i + 1] * 128 + tx * 4);
            s0.x += u2f(v0.x << 16); s0.y += u2f(v0.x & 0xffff0000u);
            s0.z += u2f(v0.y << 16); s0.w += u2f(v0.y & 0xffff0000u);
            s1.x += u2f(v1.x << 16); s1.y += u2f(v1.x & 0xffff0000u);
            s1.z += u2f(v1.y << 16); s1.w += u2f(v1.y & 0xffff0000u);
        }
        if (i < hi) {
            uint2 v0 = *(const uint2*)(bufT16 + (size_t)perm[i] * 128 + tx * 4);
            s0.x += u2f(v0.x << 16); s0.y += u2f(v0.x & 0xffff0000u);
            s0.z += u2f(v0.y << 16); s0.w += u2f(v0.y & 0xffff0000u);
        }
        float inv = 1.0f / fmaxf((float)(hi - lo), 1.0f);
        float h0 = fmaxf(acc[rr].x + bv.x + (s0.x + s1.x + s2.x + s3.x) * inv, 0.f);
        float h1 = fmaxf(acc[rr].y + bv.y + (s0.y + s1.y + s2.y + s3.y) * inv, 0.f);
        float h2 = fmaxf(acc[rr].z + bv.z + (s0.z + s1.z + s2.z + s3.z) * inv, 0.f);
        float h3 = fmaxf(acc[rr].w + bv.w + (s0.w + s1.w + s2.w + s3.w) * inv, 0.f);
        float p = h0 * wo.x + h1 * wo.y + h2 * wo.z + h3 * wo.w;
        p += __shfl_xor(p, 1, 32);
        p += __shfl_xor(p, 2, 32);
        p += __shfl_xor(p, 4, 32);
        p += __shfl_xor(p, 8, 32);
        p += __shfl_xor(p, 16, 32);
        if (tx == 0 && r < n) out[r] = p + bo;
    }
}

// ---------------------------------------------------------------------------
// Segment contributions for pfas: contrib[node] = (Σ bufT16[src]) / cnt.
// Half-wave per node, 8 nodes/block, 8-ILP bf16 gather. grid.y = relation.
// ---------------------------------------------------------------------------
__global__ __launch_bounds__(256, 4) void seg_contrib_kernel(
    const unsigned short* __restrict__ bufT_gp,
    const unsigned short* __restrict__ bufT_sp,
    const int* __restrict__ off_all, const int* __restrict__ perm_all,
    float* __restrict__ contrib_gp, float* __restrict__ contrib_sp)
{
    const unsigned short* bufT; const int* off; float* contrib;
    if (blockIdx.y == 0) { bufT = bufT_gp; off = off_all + BASE_GP; contrib = contrib_gp; }
    else                 { bufT = bufT_sp; off = off_all + BASE_SP; contrib = contrib_sp; }

    int node = blockIdx.x * 8 + (threadIdx.x >> 5);
    if (node >= N_PFAS) return;
    int tx = threadIdx.x & 31;
    int lo = off[node], hi = off[node + 1];
    float4 s0 = make_float4(0.f, 0.f, 0.f, 0.f);
    float4 s1 = make_float4(0.f, 0.f, 0.f, 0.f);
    float4 s2 = make_float4(0.f, 0.f, 0.f, 0.f);
    float4 s3 = make_float4(0.f, 0.f, 0.f, 0.f);
    int i = lo;
    for (; i + 8 <= hi; i += 8) {
        uint2 v0 = *(const uint2*)(bufT + (size_t)perm_all[i + 0] * 128 + tx * 4);
        uint2 v1 = *(const uint2*)(bufT + (size_t)perm_all[i + 1] * 128 + tx * 4);
        uint2 v2 = *(const uint2*)(bufT + (size_t)perm_all[i + 2] * 128 + tx * 4);
        uint2 v3 = *(const uint2*)(bufT + (size_t)perm_all[i + 3] * 128 + tx * 4);
        uint2 v4 = *(const uint2*)(bufT + (size_t)perm_all[i + 4] * 128 + tx * 4);
        uint2 v5 = *(const uint2*)(bufT + (size_t)perm_all[i + 5] * 128 + tx * 4);
        uint2 v6 = *(const uint2*)(bufT + (size_t)perm_all[i + 6] * 128 + tx * 4);
        uint2 v7 = *(const uint2*)(bufT + (size_t)perm_all[i + 7] * 128 + tx * 4);
        s0.x += u2f(v0.x << 16); s0.y += u2f(v0.x & 0xffff0000u);
        s0.z += u2f(v0.y << 16); s0.w += u2f(v0.y & 0xffff0000u);
        s1.x += u2f(v1.x << 16); s1.y += u2f(v1.x & 0xffff0000u);
        s1.z += u2f(v1.y << 16); s1.w += u2f(v1.y & 0xffff0000u);
        s2.x += u2f(v2.x << 16); s2.y += u2f(v2.x & 0xffff0000u);
        s2.z += u2f(v2.y << 16); s2.w += u2f(v2.y & 0xffff0000u);
        s3.x += u2f(v3.x << 16); s3.y += u2f(v3.x & 0xffff0000u);
        s3.z += u2f(v3.y << 16); s3.w += u2f(v3.y & 0xffff0000u);
        s0.x += u2f(v4.x << 16); s0.y += u2f(v4.x & 0xffff0000u);
        s0.z += u2f(v4.y << 16); s0.w += u2f(v4.y & 0xffff0000u);
        s1.x += u2f(v5.x << 16); s1.y += u2f(v5.x & 0xffff0000u);
        s1.z += u2f(v5.y << 16); s1.w += u2f(v5.y & 0xffff0000u);
        s2.x += u2f(v6.x << 16); s2.y += u2f(v6.x & 0xffff0000u);
        s2.z += u2f(v6.y << 16); s2.w += u2f(v6.y & 0xffff0000u);
        s3.x += u2f(v7.x << 16); s3.y += u2f(v7.x & 0xffff0000u);
        s3.z += u2f(v7.y << 16); s3.w += u2f(v7.y & 0xffff0000u);
    }
    for (; i + 2 <= hi; i += 2) {
        uint2 v0 = *(const uint2*)(bufT + (size_t)perm_all[i + 0] * 128 + tx * 4);
        uint2 v1 = *(const uint2*)(bufT + (size_t)perm_all[i + 1] * 128 + tx * 4);
        s0.x += u2f(v0.x << 16); s0.y += u2f(v0.x & 0xffff0000u);
        s0.z += u2f(v0.y << 16); s0.w += u2f(v0.y & 0xffff0000u);
        s1.x += u2f(v1.x << 16); s1.y += u2f(v1.x & 0xffff0000u);
        s1.z += u2f(v1.y << 16); s1.w += u2f(v1.y & 0xffff0000u);
    }
    if (i < hi) {
        uint2 v0 = *(const uint2*)(bufT + (size_t)perm_all[i] * 128 + tx * 4);
        s0.x += u2f(v0.x << 16); s0.y += u2f(v0.x & 0xffff0000u);
        s0.z += u2f(v0.y << 16); s0.w += u2f(v0.y & 0xffff0000u);
    }
    float inv = 1.0f / fmaxf((float)(hi - lo), 1.0f);
    float4 o;
    o.x = (s0.x + s1.x + s2.x + s3.x) * inv;
    o.y = (s0.y + s1.y + s2.y + s3.y) * inv;
    o.z = (s0.z + s1.z + s2.z + s3.z) * inv;
    o.w = (s0.w + s1.w + s2.w + s3.w) * inv;
    ((float4*)contrib)[(size_t)node * 32 + tx] = o;
}

// ---------------------------------------------------------------------------
// pfas node pass: h_pf = relu(x@(WrA+WrB) + contrib_gp + contrib_sp + blG+blS)
// ---------------------------------------------------------------------------
__global__ __launch_bounds__(256, 2) void gemm_pf_kernel(
    int n, const float* __restrict__ x,
    const float* __restrict__ WrA, const float* __restrict__ WrB,
    const float* __restrict__ contrib_gp, const float* __restrict__ contrib_sp,
    const float* __restrict__ blG, const float* __restrict__ blS,
    float* __restrict__ out)
{
    __shared__ float sW[32 * 128];
    __shared__ float sX[32 * 128];
    const int tid = threadIdx.x;
    const int row0 = blockIdx.x * 128;
    float4 acc[16];
#pragma unroll
    for (int i = 0; i < 16; ++i) acc[i] = make_float4(0.f, 0.f, 0.f, 0.f);
    tile_gemm<256, 128>(x, WrA, WrB, n, row0, tid, (float4*)sW, sX, acc);

    const int tx = tid & 31;
    const int rbase = row0 + (tid >> 5) * 16;
    float4 b1 = ((const float4*)blG)[tx];
    float4 b2 = ((const float4*)blS)[tx];
#pragma unroll
    for (int rr = 0; rr < 16; ++rr) {
        int r = rbase + rr;
        if (r < n) {
            float4 cg = ((const float4*)contrib_gp)[(size_t)r * 32 + tx];
            float4 cs = ((const float4*)contrib_sp)[(size_t)r * 32 + tx];
            float4 o = acc[rr];
            o.x = fmaxf(o.x + cg.x + cs.x + b1.x + b2.x, 0.f);
            o.y = fmaxf(o.y + cg.y + cs.y + b1.y + b2.y, 0.f);
            o.z = fmaxf(o.z + cg.z + cs.z + b1.z + b2.z, 0.f);
            o.w = fmaxf(o.w + cg.w + cs.w + b1.w + b2.w, 0.f);
            ((float4*)out)[(size_t)r * 32 + tx] = o;
        }
    }
}

// ---------------------------------------------------------------------------
// Bucket-level histogram: LDS-privatized per block (665 counters), then one
// global atomicAdd per nonzero bucket per block. Replaces the per-node global
// histogram (3.04M device atomics -> ~85K) that cost 125 us.
// ---------------------------------------------------------------------------
__global__ __launch_bounds__(1024) void bucket_hist_kernel(
    const int* __restrict__ d_pg, const int* __restrict__ d_ps,
    const int* __restrict__ d_gp, const int* __restrict__ d_sp,
    int* __restrict__ bucketCounts)
{
    __shared__ int hist[NB];
    const int tid = threadIdx.x;
    for (int i = tid; i < NB; i += 1024) hist[i] = 0;
    __syncthreads();
    for (int e = blockIdx.x * 1024 + tid; e < E_TOT; e += H_NBLK * 1024) {
        int idx;
        if (e < E_PG)                    idx = BASE_PG + d_pg[e];
        else if (e < E_PG + E_PS)        idx = BASE_PS + d_ps[e - E_PG];
        else if (e < E_PG + E_PS + E_GP) idx = BASE_GP + d_gp[e - E_PG - E_PS];
        else                             idx = BASE_SP + d_sp[e - E_PG - E_PS - E_GP];
        atomicAdd(&hist[idx >> 8], 1);
    }
    __syncthreads();
    for (int i = tid; i < NB; i += 1024) {
        int c = hist[i];
        if (c) atomicAdd(&bucketCounts[i], c);
    }
}

// ---------------------------------------------------------------------------
// Single-block exclusive scan over the 665 bucket counts. Seeds gcursor with
// bucket start offsets (same semantics scanC produced before).
// ---------------------------------------------------------------------------
__global__ __launch_bounds__(1024) void bucket_scan_kernel(
    const int* __restrict__ bucketCounts, int* __restrict__ bucketOff,
    int* __restrict__ gcursor, int* __restrict__ off_all)
{
    __shared__ int sp[1024];
    const int t = threadIdx.x;
    int v = (t < NB) ? bucketCounts[t] : 0;
    sp[t] = v;
    __syncthreads();
    for (int ofs = 1; ofs < 1024; ofs <<= 1) {
        int add = (t >= ofs) ? sp[t - ofs] : 0;
        __syncthreads();
        sp[t] += add;
        __syncthreads();
    }
    if (t < NB) {
        int excl = sp[t] - v;
        bucketOff[t] = excl;
        gcursor[t] = excl;
    }
    if (t == 0) { bucketOff[NB] = E_TOT; off_all[NTOT] = E_TOT; }
}

// ---------------------------------------------------------------------------
// Pass 1: bin edges into 256-node buckets. Entry packed: (idx&255) | (src<<8).
// ---------------------------------------------------------------------------
__global__ __launch_bounds__(1024) void bin_kernel(
    const int* __restrict__ s_pg, const int* __restrict__ d_pg,
    const int* __restrict__ s_ps, const int* __restrict__ d_ps,
    const int* __restrict__ s_gp, const int* __restrict__ d_gp,
    const int* __restrict__ s_sp, const int* __restrict__ d_sp,
    int* __restrict__ gcursor, unsigned* __restrict__ pairs)
{
    __shared__ int hist[NB];
    __shared__ int chunkBase[NB];
    const int tid = threadIdx.x;
    for (int i = tid; i < NB; i += 1024) hist[i] = 0;
    __syncthreads();

    const int base = blockIdx.x * BIN_EPB;
    int bkt[BIN_EPT], rnk[BIN_EPT];
    unsigned pk[BIN_EPT];
#pragma unroll
    for (int k = 0; k < BIN_EPT; ++k) {
        int e = base + k * 1024 + tid;
        int idx = -1, src = 0;
        if (e < E_PG) { idx = BASE_PG + d_pg[e]; src = s_pg[e]; }
        else if (e < E_PG + E_PS) { int i2 = e - E_PG; idx = BASE_PS + d_ps[i2]; src = s_ps[i2]; }
        else if (e < E_PG + E_PS + E_GP) { int i2 = e - E_PG - E_PS; idx = BASE_GP + d_gp[i2]; src = s_gp[i2]; }
        else if (e < E_TOT) { int i2 = e - E_PG - E_PS - E_GP; idx = BASE_SP + d_sp[i2]; src = s_sp[i2]; }
        if (idx >= 0) {
            int b = idx >> 8;
            bkt[k] = b;
            rnk[k] = atomicAdd(&hist[b], 1);
            pk[k] = (unsigned)(idx & 255) | ((unsigned)src << 8);
        } else bkt[k] = -1;
    }
    __syncthreads();
    for (int i = tid; i < NB; i += 1024) {
        int c = hist[i];
        chunkBase[i] = c ? atomicAdd(&gcursor[i], c) : 0;
    }
    __syncthreads();
#pragma unroll
    for (int k = 0; k < BIN_EPT; ++k)
        if (bkt[k] >= 0) pairs[chunkBase[bkt[k]] + rnk[k]] = pk[k];
}

// ---------------------------------------------------------------------------
// Pass 2: one block per bucket. Per-node counts are recovered HERE from the
// packed pairs with LDS atomics (free vs the old 3.04M global-atomic hist),
// scanned in LDS to produce off_all for this bucket, then scatter into the
// LDS segment and stream out coalesced.
// ---------------------------------------------------------------------------
__global__ __launch_bounds__(1024) void unbin_kernel(
    const unsigned* __restrict__ pairs, const int* __restrict__ bucketOff,
    int* __restrict__ off_all, int* __restrict__ perm_all)
{
    __shared__ int sPerm[SEG_CAP];
    __shared__ int cnt[256];
    __shared__ int sp[256];
    __shared__ int cur[256];
    const int b = blockIdx.x;
    const int nb0 = b << 8;
    const int nb1 = min(nb0 + 256, NTOT);
    const int tid = threadIdx.x;
    const int base = bucketOff[b];
    const int end  = bucketOff[b + 1];
    const int len = end - base;

    if (tid < 256) cnt[tid] = 0;
    __syncthreads();
    // count per-node edges within this bucket
    for (int i = base + tid; i < end; i += 1024)
        atomicAdd(&cnt[pairs[i] & 255u], 1);
    __syncthreads();
    // 256-wide exclusive scan (Hillis-Steele; all 1024 threads hit barriers)
    int v = (tid < 256) ? cnt[tid] : 0;
    if (tid < 256) sp[tid] = v;
    __syncthreads();
    for (int ofs = 1; ofs < 256; ofs <<= 1) {
        int add = (tid < 256 && tid >= ofs) ? sp[tid - ofs] : 0;
        __syncthreads();
        if (tid < 256) sp[tid] += add;
        __syncthreads();
    }
    if (tid < 256) {
        int excl = sp[tid] - v;
        cur[tid] = excl;
        if (nb0 + tid < nb1) off_all[nb0 + tid] = base + excl;
    }
    __syncthreads();

    if (len <= SEG_CAP) {
        for (int i = base + tid; i < end; i += 1024) {
            unsigned p = pairs[i];
            int pos = atomicAdd(&cur[p & 255u], 1);
            sPerm[pos] = (int)(p >> 8);
        }
        __syncthreads();
        for (int i = tid; i < len; i += 1024)
            perm_all[base + i] = sPerm[i];
    } else {
        for (int i = base + tid; i < end; i += 1024) {
            unsigned p = pairs[i];
            int pos = atomicAdd(&cur[p & 255u], 1);
            perm_all[base + pos] = (int)(p >> 8);
        }
    }
}

// ---------------------------------------------------------------------------
// Launch
// ---------------------------------------------------------------------------
extern "C" void kernel_launch(void* const* d_in, const int* in_sizes, int n_in,
                              void* d_out, int out_size, void* d_ws, size_t ws_size,
                              hipStream_t stream)
{
    const float* x_pfas = (const float*)d_in[0];
    const float* x_gw   = (const float*)d_in[1];
    const float* x_sw   = (const float*)d_in[2];
    const int* ei_pg_src = (const int*)d_in[3];
    const int* ei_pg_dst = (const int*)d_in[4];
    const int* ei_gp_src = (const int*)d_in[5];
    const int* ei_gp_dst = (const int*)d_in[6];
    const int* ei_ps_src = (const int*)d_in[7];
    const int* ei_ps_dst = (const int*)d_in[8];
    const int* ei_sp_src = (const int*)d_in[9];
    const int* ei_sp_dst = (const int*)d_in[10];
    const float* Wl_pg = (const float*)d_in[11];
    const float* bl_pg = (const float*)d_in[12];
    const float* Wr_pg = (const float*)d_in[13];
    const float* Wl_gp = (const float*)d_in[14];
    const float* bl_gp = (const float*)d_in[15];
    const float* Wr_gp = (const float*)d_in[16];
    const float* Wl_ps = (const float*)d_in[17];
    const float* bl_ps = (const float*)d_in[18];
    const float* Wr_ps = (const float*)d_in[19];
    const float* Wl_sp = (const float*)d_in[20];
    const float* bl_sp = (const float*)d_in[21];
    const float* Wr_sp = (const float*)d_in[22];
    const float* W_gw = (const float*)d_in[23];
    const float* b_gw = (const float*)d_in[24];
    const float* W_sw = (const float*)d_in[25];
    const float* b_sw = (const float*)d_in[26];

    float* out  = (float*)d_out;
    float* h_pf = out;                         // 20000*128
    float* o_gw = out + (size_t)N_PFAS * 128;  // 100000
    float* o_sw = o_gw + N_GW;                 // 30000

    // ---- workspace layout (~90 MB) ----
    char* p = (char*)d_ws;
    auto alloc = [&](size_t bytes) { char* q = p; p += (bytes + 15) & ~(size_t)15; return q; };
    unsigned short* bufT_pg = (unsigned short*)alloc((size_t)N_PFAS * 128 * 2);
    unsigned short* bufT_ps = (unsigned short*)alloc((size_t)N_PFAS * 128 * 2);
    unsigned short* bufT_gp = (unsigned short*)alloc((size_t)N_GW * 128 * 2);
    unsigned short* bufT_sp = (unsigned short*)alloc((size_t)N_SW * 128 * 2);
    float* contrib_gp = (float*)alloc((size_t)N_PFAS * 128 * 4);
    float* contrib_sp = (float*)alloc((size_t)N_PFAS * 128 * 4);
    int* perm_all   = (int*)alloc((size_t)E_TOT * 4);
    unsigned* pairs = (unsigned*)alloc((size_t)E_TOT * 4);
    int* off_all    = (int*)alloc((size_t)(NTOT + 1) * 4);
    int* bucketCounts = (int*)alloc((size_t)NB * 4);
    int* bucketOff    = (int*)alloc((size_t)(NB + 1) * 4);
    int* gcursor    = (int*)alloc((size_t)NB * 4);

    // ---- 1. unified bf16 transforms (all 4 relations) ----
    gemm_t16_all_kernel<<<TILES_ALL, 256, 0, stream>>>(
        x_pfas, x_gw, x_sw, Wl_pg, Wl_ps, Wl_gp, Wl_sp,
        bufT_pg, bufT_ps, bufT_gp, bufT_sp);

    // ---- 2. CSR build: bucket hist -> bucket scan -> bucketed permute ----
    hipMemsetAsync(bucketCounts, 0, (size_t)NB * 4, stream);
    bucket_hist_kernel<<<H_NBLK, 1024, 0, stream>>>(
        ei_pg_dst, ei_ps_dst, ei_gp_dst, ei_sp_dst, bucketCounts);
    bucket_scan_kernel<<<1, 1024, 0, stream>>>(
        bucketCounts, bucketOff, gcursor, off_all);
    bin_kernel<<<BIN_NBLK, 1024, 0, stream>>>(
        ei_pg_src, ei_pg_dst, ei_ps_src, ei_ps_dst,
        ei_gp_src, ei_gp_dst, ei_sp_src, ei_sp_dst, gcursor, pairs);
    unbin_kernel<<<NB, 1024, 0, stream>>>(pairs, bucketOff, off_all, perm_all);

    // ---- 3. gw / sw fused node passes (64 rows/block) ----
    gemm_gather_scalar_kernel<<<(N_GW + 63) / 64, 256, 0, stream>>>(
        N_GW, x_gw, Wr_pg, bl_pg, bufT_pg, perm_all, off_all + BASE_PG,
        W_gw, b_gw, o_gw);
    gemm_gather_scalar_kernel<<<(N_SW + 63) / 64, 256, 0, stream>>>(
        N_SW, x_sw, Wr_ps, bl_ps, bufT_ps, perm_all, off_all + BASE_PS,
        W_sw, b_sw, o_sw);

    // ---- 4. bf16 segment contributions into pfas ----
    dim3 gS((N_PFAS + 7) / 8, 2);
    seg_contrib_kernel<<<gS, 256, 0, stream>>>(
        bufT_gp, bufT_sp, off_all, perm_all, contrib_gp, contrib_sp);

    // ---- 5. pfas node pass (single GEMM + contrib epilogue) ----
    gemm_pf_kernel<<<(N_PFAS + 127) / 128, 256, 0, stream>>>(
        N_PFAS, x_pfas, Wr_gp, Wr_sp, contrib_gp, contrib_sp,
        bl_gp, bl_sp, h_pf);
}

// Round 2
// 495.568 us; speedup vs baseline: 1.2769x; 1.0568x over previous
//
#include <hip/hip_runtime.h>

// ---------------------------------------------------------------------------
// Problem constants
// ---------------------------------------------------------------------------
#define N_PFAS 20000
#define N_GW   100000
#define N_SW   30000
#define E_PG   1600000
#define E_GP   640000
#define E_PS   480000
#define E_SP   320000
#define E_TOT  (E_PG + E_PS + E_GP + E_SP)
// Concatenated node-count layout: [pg: N_GW][ps: N_SW][gp: N_PFAS][sp: N_PFAS]
#define BASE_PG 0
#define BASE_PS (N_GW)
#define BASE_GP (N_GW + N_SW)
#define BASE_SP (N_GW + N_SW + N_PFAS)
#define NTOT    (N_GW + N_SW + 2 * N_PFAS)
// Bucketed permute: 256 nodes per bucket.
#define NB        ((NTOT + 255) / 256)       // 665
#define BIN_EPT   12
#define BIN_EPB   (1024 * BIN_EPT)
#define BIN_NBLK  ((E_TOT + BIN_EPB - 1) / BIN_EPB)
#define SEG_CAP   15360
#define H_NBLK    128                        // bucket-hist grid
// Unified transform pass tiles (128 rows each)
#define TILES_PF  ((N_PFAS + 127) / 128)     // 157
#define TILES_GW  ((N_GW + 127) / 128)       // 782
#define TILES_SW  ((N_SW + 127) / 128)       // 235
#define TILES_ALL (2 * TILES_PF + TILES_GW + TILES_SW)
// Merged gw/sw node pass (64 rows per block)
#define GW_BLKS   ((N_GW + 63) / 64)         // 1563
#define SW_BLKS   ((N_SW + 63) / 64)         // 469

// ---------------------------------------------------------------------------
// bf16 helpers
// ---------------------------------------------------------------------------
__device__ __forceinline__ unsigned short f2bf(float f) {
    unsigned u = __float_as_uint(f);
    u += 0x7fffu + ((u >> 16) & 1u);
    return (unsigned short)(u >> 16);
}
__device__ __forceinline__ float u2f(unsigned u) { return __uint_as_float(u); }

// ---------------------------------------------------------------------------
// GEMM tile: NT threads, ROWS rows/block, 32-k chunks in LDS.
// acc must be compile-time indexed by callers (dynamic indexing -> scratch!).
// ---------------------------------------------------------------------------
template<int NT, int ROWS>
__device__ __forceinline__ void tile_gemm(
    const float* __restrict__ X, const float* __restrict__ Wa,
    const float* __restrict__ Wb, int n, int row0, int tid,
    float4* sW4, float* sX, float4* acc)
{
    constexpr int TY  = NT / 32;
    constexpr int RPT = ROWS / TY;
    const int tx = tid & 31;
    const int ty = tid >> 5;
    const float4* X4 = (const float4*)X;
    const float4* Wa4 = (const float4*)Wa;
    const float4* Wb4 = (const float4*)Wb;

    for (int kc = 0; kc < 4; ++kc) {
        __syncthreads();
        for (int i = tid; i < 1024; i += NT) {
            float4 w = Wa4[kc * 1024 + i];
            if (Wb) {
                float4 b = Wb4[kc * 1024 + i];
                w.x += b.x; w.y += b.y; w.z += b.z; w.w += b.w;
            }
            sW4[i] = w;
        }
        for (int j = tid; j < ROWS * 8; j += NT) {
            int rr = j >> 3, k4 = j & 7;
            int r = row0 + rr;
            float4 xv = make_float4(0.f, 0.f, 0.f, 0.f);
            if (r < n) xv = X4[(size_t)r * 32 + kc * 8 + k4];
            int kk = k4 * 4;
            sX[(kk + 0) * ROWS + rr] = xv.x;
            sX[(kk + 1) * ROWS + rr] = xv.y;
            sX[(kk + 2) * ROWS + rr] = xv.z;
            sX[(kk + 3) * ROWS + rr] = xv.w;
        }
        __syncthreads();
#pragma unroll 4
        for (int k = 0; k < 32; ++k) {
            float4 w4 = sW4[k * 32 + tx];
            const float4* xr4 = (const float4*)&sX[k * ROWS + ty * RPT];
#pragma unroll
            for (int q = 0; q < RPT / 4; ++q) {
                float4 x4 = xr4[q];
                acc[q * 4 + 0].x += x4.x * w4.x; acc[q * 4 + 0].y += x4.x * w4.y;
                acc[q * 4 + 0].z += x4.x * w4.z; acc[q * 4 + 0].w += x4.x * w4.w;
                acc[q * 4 + 1].x += x4.y * w4.x; acc[q * 4 + 1].y += x4.y * w4.y;
                acc[q * 4 + 1].z += x4.y * w4.z; acc[q * 4 + 1].w += x4.y * w4.w;
                acc[q * 4 + 2].x += x4.z * w4.x; acc[q * 4 + 2].y += x4.z * w4.y;
                acc[q * 4 + 2].z += x4.z * w4.z; acc[q * 4 + 2].w += x4.z * w4.w;
                acc[q * 4 + 3].x += x4.w * w4.x; acc[q * 4 + 3].y += x4.w * w4.y;
                acc[q * 4 + 3].z += x4.w * w4.z; acc[q * 4 + 3].w += x4.w * w4.w;
            }
        }
    }
}

// ---------------------------------------------------------------------------
// Unified transform pass: bufT_* = X @ Wl  (bf16 out) for all 4 relations.
// 1331 blocks of 128 rows.
// ---------------------------------------------------------------------------
__global__ __launch_bounds__(256, 2) void gemm_t16_all_kernel(
    const float* __restrict__ x_pfas, const float* __restrict__ x_gw,
    const float* __restrict__ x_sw,
    const float* __restrict__ Wl_pg, const float* __restrict__ Wl_ps,
    const float* __restrict__ Wl_gp, const float* __restrict__ Wl_sp,
    unsigned short* __restrict__ bufT_pg, unsigned short* __restrict__ bufT_ps,
    unsigned short* __restrict__ bufT_gp, unsigned short* __restrict__ bufT_sp)
{
    __shared__ float sW[32 * 128];
    __shared__ float sX[32 * 128];
    const int b = blockIdx.x;
    const float* X; const float* W; unsigned short* out; int n; int tile;
    if (b < TILES_PF)            { X = x_pfas; W = Wl_pg; out = bufT_pg; n = N_PFAS; tile = b; }
    else if (b < 2 * TILES_PF)   { X = x_pfas; W = Wl_ps; out = bufT_ps; n = N_PFAS; tile = b - TILES_PF; }
    else if (b < 2 * TILES_PF + TILES_GW)
                                 { X = x_gw;   W = Wl_gp; out = bufT_gp; n = N_GW;   tile = b - 2 * TILES_PF; }
    else                         { X = x_sw;   W = Wl_sp; out = bufT_sp; n = N_SW;   tile = b - 2 * TILES_PF - TILES_GW; }
    const int tid = threadIdx.x;
    const int row0 = tile * 128;

    float4 acc[16];
#pragma unroll
    for (int i = 0; i < 16; ++i) acc[i] = make_float4(0.f, 0.f, 0.f, 0.f);
    tile_gemm<256, 128>(X, W, nullptr, n, row0, tid, (float4*)sW, sX, acc);

    const int tx = tid & 31;
    const int rbase = row0 + (tid >> 5) * 16;
#pragma unroll
    for (int rr = 0; rr < 16; ++rr) {
        int r = rbase + rr;
        if (r < n) {
            uint2 o;
            o.x = (unsigned)f2bf(acc[rr].x) | ((unsigned)f2bf(acc[rr].y) << 16);
            o.y = (unsigned)f2bf(acc[rr].z) | ((unsigned)f2bf(acc[rr].w) << 16);
            *(uint2*)(out + (size_t)r * 128 + tx * 4) = o;
        }
    }
}

// ---------------------------------------------------------------------------
// Merged gw+sw node pass: 512 threads, 64 rows/block -> 16 groups x 4 rows.
// GEMM X@Wr fused with 8-ILP CSR gather of bf16 neighbor rows + scalar head.
// 512t/4-rows-per-group triples outstanding loads vs 256t/8-rows (latency-
// bound gather; occupancy cap 4 blocks/CU = 32 waves).
// ---------------------------------------------------------------------------
__global__ __launch_bounds__(512, 4) void gemm_gather_scalar_kernel(
    const float* __restrict__ x_gw, const float* __restrict__ x_sw,
    const float* __restrict__ Wr_pg, const float* __restrict__ Wr_ps,
    const float* __restrict__ bl_pg, const float* __restrict__ bl_ps,
    const unsigned short* __restrict__ bufT_pg,
    const unsigned short* __restrict__ bufT_ps,
    const int* __restrict__ perm, const int* __restrict__ off_all,
    const float* __restrict__ W_gw, const float* __restrict__ b_gw,
    const float* __restrict__ W_sw, const float* __restrict__ b_sw,
    float* __restrict__ o_gw, float* __restrict__ o_sw)
{
    __shared__ float sW[32 * 128];
    __shared__ float sX[32 * 64];
    const int b = blockIdx.x;
    int n; const float* X; const float* Wr; const float* bl;
    const unsigned short* bufT16; const int* off;
    const float* wout; const float* bout; float* out; int tile;
    if (b < GW_BLKS) {
        n = N_GW; X = x_gw; Wr = Wr_pg; bl = bl_pg; bufT16 = bufT_pg;
        off = off_all + BASE_PG; wout = W_gw; bout = b_gw; out = o_gw; tile = b;
    } else {
        n = N_SW; X = x_sw; Wr = Wr_ps; bl = bl_ps; bufT16 = bufT_ps;
        off = off_all + BASE_PS; wout = W_sw; bout = b_sw; out = o_sw; tile = b - GW_BLKS;
    }
    const int tid = threadIdx.x;
    const int row0 = tile * 64;
    float4 acc[4];
#pragma unroll
    for (int i = 0; i < 4; ++i) acc[i] = make_float4(0.f, 0.f, 0.f, 0.f);
    tile_gemm<512, 64>(X, Wr, nullptr, n, row0, tid, (float4*)sW, sX, acc);

    const int tx = tid & 31;
    const int rbase = row0 + (tid >> 5) * 4;
    float4 bv = ((const float4*)bl)[tx];
    float4 wo = ((const float4*)wout)[tx];
    float bo = bout[0];

#pragma unroll
    for (int rr = 0; rr < 4; ++rr) {
        int r = rbase + rr;
        int lo = 0, hi = 0;
        if (r < n) { lo = off[r]; hi = off[r + 1]; }
        float4 s0 = make_float4(0.f, 0.f, 0.f, 0.f);
        float4 s1 = make_float4(0.f, 0.f, 0.f, 0.f);
        float4 s2 = make_float4(0.f, 0.f, 0.f, 0.f);
        float4 s3 = make_float4(0.f, 0.f, 0.f, 0.f);
        int i = lo;
        for (; i + 8 <= hi; i += 8) {
            uint2 v0 = *(const uint2*)(bufT16 + (size_t)perm[i + 0] * 128 + tx * 4);
            uint2 v1 = *(const uint2*)(bufT16 + (size_t)perm[i + 1] * 128 + tx * 4);
            uint2 v2 = *(const uint2*)(bufT16 + (size_t)perm[i + 2] * 128 + tx * 4);
            uint2 v3 = *(const uint2*)(bufT16 + (size_t)perm[i + 3] * 128 + tx * 4);
            uint2 v4 = *(const uint2*)(bufT16 + (size_t)perm[i + 4] * 128 + tx * 4);
            uint2 v5 = *(const uint2*)(bufT16 + (size_t)perm[i + 5] * 128 + tx * 4);
            uint2 v6 = *(const uint2*)(bufT16 + (size_t)perm[i + 6] * 128 + tx * 4);
            uint2 v7 = *(const uint2*)(bufT16 + (size_t)perm[i + 7] * 128 + tx * 4);
            s0.x += u2f(v0.x << 16); s0.y += u2f(v0.x & 0xffff0000u);
            s0.z += u2f(v0.y << 16); s0.w += u2f(v0.y & 0xffff0000u);
            s1.x += u2f(v1.x << 16); s1.y += u2f(v1.x & 0xffff0000u);
            s1.z += u2f(v1.y << 16); s1.w += u2f(v1.y & 0xffff0000u);
            s2.x += u2f(v2.x << 16); s2.y += u2f(v2.x & 0xffff0000u);
            s2.z += u2f(v2.y << 16); s2.w += u2f(v2.y & 0xffff0000u);
            s3.x += u2f(v3.x << 16); s3.y += u2f(v3.x & 0xffff0000u);
            s3.z += u2f(v3.y << 16); s3.w += u2f(v3.y & 0xffff0000u);
            s0.x += u2f(v4.x << 16); s0.y += u2f(v4.x & 0xffff0000u);
            s0.z += u2f(v4.y << 16); s0.w += u2f(v4.y & 0xffff0000u);
            s1.x += u2f(v5.x << 16); s1.y += u2f(v5.x & 0xffff0000u);
            s1.z += u2f(v5.y << 16); s1.w += u2f(v5.y & 0xffff0000u);
            s2.x += u2f(v6.x << 16); s2.y += u2f(v6.x & 0xffff0000u);
            s2.z += u2f(v6.y << 16); s2.w += u2f(v6.y & 0xffff0000u);
            s3.x += u2f(v7.x << 16); s3.y += u2f(v7.x & 0xffff0000u);
            s3.z += u2f(v7.y << 16); s3.w += u2f(v7.y & 0xffff0000u);
        }
        for (; i + 2 <= hi; i += 2) {
            uint2 v0 = *(const uint2*)(bufT16 + (size_t)perm[i + 0] * 128 + tx * 4);
            uint2 v1 = *(const uint2*)(bufT16 + (size_t)perm[i + 1] * 128 + tx * 4);
            s0.x += u2f(v0.x << 16); s0.y += u2f(v0.x & 0xffff0000u);
            s0.z += u2f(v0.y << 16); s0.w += u2f(v0.y & 0xffff0000u);
            s1.x += u2f(v1.x << 16); s1.y += u2f(v1.x & 0xffff0000u);
            s1.z += u2f(v1.y << 16); s1.w += u2f(v1.y & 0xffff0000u);
        }
        if (i < hi) {
            uint2 v0 = *(const uint2*)(bufT16 + (size_t)perm[i] * 128 + tx * 4);
            s0.x += u2f(v0.x << 16); s0.y += u2f(v0.x & 0xffff0000u);
            s0.z += u2f(v0.y << 16); s0.w += u2f(v0.y & 0xffff0000u);
        }
        float inv = 1.0f / fmaxf((float)(hi - lo), 1.0f);
        float h0 = fmaxf(acc[rr].x + bv.x + (s0.x + s1.x + s2.x + s3.x) * inv, 0.f);
        float h1 = fmaxf(acc[rr].y + bv.y + (s0.y + s1.y + s2.y + s3.y) * inv, 0.f);
        float h2 = fmaxf(acc[rr].z + bv.z + (s0.z + s1.z + s2.z + s3.z) * inv, 0.f);
        float h3 = fmaxf(acc[rr].w + bv.w + (s0.w + s1.w + s2.w + s3.w) * inv, 0.f);
        float p = h0 * wo.x + h1 * wo.y + h2 * wo.z + h3 * wo.w;
        p += __shfl_xor(p, 1, 32);
        p += __shfl_xor(p, 2, 32);
        p += __shfl_xor(p, 4, 32);
        p += __shfl_xor(p, 8, 32);
        p += __shfl_xor(p, 16, 32);
        if (tx == 0 && r < n) out[r] = p + bo;
    }
}

// ---------------------------------------------------------------------------
// Segment contributions for pfas: contrib[node] = (Σ bufT16[src]) / cnt.
// Half-wave per node, 8 nodes/block, 8-ILP bf16 gather. grid.y = relation.
// ---------------------------------------------------------------------------
__global__ __launch_bounds__(256, 4) void seg_contrib_kernel(
    const unsigned short* __restrict__ bufT_gp,
    const unsigned short* __restrict__ bufT_sp,
    const int* __restrict__ off_all, const int* __restrict__ perm_all,
    float* __restrict__ contrib_gp, float* __restrict__ contrib_sp)
{
    const unsigned short* bufT; const int* off; float* contrib;
    if (blockIdx.y == 0) { bufT = bufT_gp; off = off_all + BASE_GP; contrib = contrib_gp; }
    else                 { bufT = bufT_sp; off = off_all + BASE_SP; contrib = contrib_sp; }

    int node = blockIdx.x * 8 + (threadIdx.x >> 5);
    if (node >= N_PFAS) return;
    int tx = threadIdx.x & 31;
    int lo = off[node], hi = off[node + 1];
    float4 s0 = make_float4(0.f, 0.f, 0.f, 0.f);
    float4 s1 = make_float4(0.f, 0.f, 0.f, 0.f);
    float4 s2 = make_float4(0.f, 0.f, 0.f, 0.f);
    float4 s3 = make_float4(0.f, 0.f, 0.f, 0.f);
    int i = lo;
    for (; i + 8 <= hi; i += 8) {
        uint2 v0 = *(const uint2*)(bufT + (size_t)perm_all[i + 0] * 128 + tx * 4);
        uint2 v1 = *(const uint2*)(bufT + (size_t)perm_all[i + 1] * 128 + tx * 4);
        uint2 v2 = *(const uint2*)(bufT + (size_t)perm_all[i + 2] * 128 + tx * 4);
        uint2 v3 = *(const uint2*)(bufT + (size_t)perm_all[i + 3] * 128 + tx * 4);
        uint2 v4 = *(const uint2*)(bufT + (size_t)perm_all[i + 4] * 128 + tx * 4);
        uint2 v5 = *(const uint2*)(bufT + (size_t)perm_all[i + 5] * 128 + tx * 4);
        uint2 v6 = *(const uint2*)(bufT + (size_t)perm_all[i + 6] * 128 + tx * 4);
        uint2 v7 = *(const uint2*)(bufT + (size_t)perm_all[i + 7] * 128 + tx * 4);
        s0.x += u2f(v0.x << 16); s0.y += u2f(v0.x & 0xffff0000u);
        s0.z += u2f(v0.y << 16); s0.w += u2f(v0.y & 0xffff0000u);
        s1.x += u2f(v1.x << 16); s1.y += u2f(v1.x & 0xffff0000u);
        s1.z += u2f(v1.y << 16); s1.w += u2f(v1.y & 0xffff0000u);
        s2.x += u2f(v2.x << 16); s2.y += u2f(v2.x & 0xffff0000u);
        s2.z += u2f(v2.y << 16); s2.w += u2f(v2.y & 0xffff0000u);
        s3.x += u2f(v3.x << 16); s3.y += u2f(v3.x & 0xffff0000u);
        s3.z += u2f(v3.y << 16); s3.w += u2f(v3.y & 0xffff0000u);
        s0.x += u2f(v4.x << 16); s0.y += u2f(v4.x & 0xffff0000u);
        s0.z += u2f(v4.y << 16); s0.w += u2f(v4.y & 0xffff0000u);
        s1.x += u2f(v5.x << 16); s1.y += u2f(v5.x & 0xffff0000u);
        s1.z += u2f(v5.y << 16); s1.w += u2f(v5.y & 0xffff0000u);
        s2.x += u2f(v6.x << 16); s2.y += u2f(v6.x & 0xffff0000u);
        s2.z += u2f(v6.y << 16); s2.w += u2f(v6.y & 0xffff0000u);
        s3.x += u2f(v7.x << 16); s3.y += u2f(v7.x & 0xffff0000u);
        s3.z += u2f(v7.y << 16); s3.w += u2f(v7.y & 0xffff0000u);
    }
    for (; i + 2 <= hi; i += 2) {
        uint2 v0 = *(const uint2*)(bufT + (size_t)perm_all[i + 0] * 128 + tx * 4);
        uint2 v1 = *(const uint2*)(bufT + (size_t)perm_all[i + 1] * 128 + tx * 4);
        s0.x += u2f(v0.x << 16); s0.y += u2f(v0.x & 0xffff0000u);
        s0.z += u2f(v0.y << 16); s0.w += u2f(v0.y & 0xffff0000u);
        s1.x += u2f(v1.x << 16); s1.y += u2f(v1.x & 0xffff0000u);
        s1.z += u2f(v1.y << 16); s1.w += u2f(v1.y & 0xffff0000u);
    }
    if (i < hi) {
        uint2 v0 = *(const uint2*)(bufT + (size_t)perm_all[i] * 128 + tx * 4);
        s0.x += u2f(v0.x << 16); s0.y += u2f(v0.x & 0xffff0000u);
        s0.z += u2f(v0.y << 16); s0.w += u2f(v0.y & 0xffff0000u);
    }
    float inv = 1.0f / fmaxf((float)(hi - lo), 1.0f);
    float4 o;
    o.x = (s0.x + s1.x + s2.x + s3.x) * inv;
    o.y = (s0.y + s1.y + s2.y + s3.y) * inv;
    o.z = (s0.z + s1.z + s2.z + s3.z) * inv;
    o.w = (s0.w + s1.w + s2.w + s3.w) * inv;
    ((float4*)contrib)[(size_t)node * 32 + tx] = o;
}

// ---------------------------------------------------------------------------
// pfas node pass: h_pf = relu(x@(WrA+WrB) + contrib_gp + contrib_sp + blG+blS)
// ---------------------------------------------------------------------------
__global__ __launch_bounds__(256, 2) void gemm_pf_kernel(
    int n, const float* __restrict__ x,
    const float* __restrict__ WrA, const float* __restrict__ WrB,
    const float* __restrict__ contrib_gp, const float* __restrict__ contrib_sp,
    const float* __restrict__ blG, const float* __restrict__ blS,
    float* __restrict__ out)
{
    __shared__ float sW[32 * 128];
    __shared__ float sX[32 * 128];
    const int tid = threadIdx.x;
    const int row0 = blockIdx.x * 128;
    float4 acc[16];
#pragma unroll
    for (int i = 0; i < 16; ++i) acc[i] = make_float4(0.f, 0.f, 0.f, 0.f);
    tile_gemm<256, 128>(x, WrA, WrB, n, row0, tid, (float4*)sW, sX, acc);

    const int tx = tid & 31;
    const int rbase = row0 + (tid >> 5) * 16;
    float4 b1 = ((const float4*)blG)[tx];
    float4 b2 = ((const float4*)blS)[tx];
#pragma unroll
    for (int rr = 0; rr < 16; ++rr) {
        int r = rbase + rr;
        if (r < n) {
            float4 cg = ((const float4*)contrib_gp)[(size_t)r * 32 + tx];
            float4 cs = ((const float4*)contrib_sp)[(size_t)r * 32 + tx];
            float4 o = acc[rr];
            o.x = fmaxf(o.x + cg.x + cs.x + b1.x + b2.x, 0.f);
            o.y = fmaxf(o.y + cg.y + cs.y + b1.y + b2.y, 0.f);
            o.z = fmaxf(o.z + cg.z + cs.z + b1.z + b2.z, 0.f);
            o.w = fmaxf(o.w + cg.w + cs.w + b1.w + b2.w, 0.f);
            ((float4*)out)[(size_t)r * 32 + tx] = o;
        }
    }
}

// ---------------------------------------------------------------------------
// Bucket-level histogram: LDS-privatized per block (665 counters), then one
// global atomicAdd per nonzero bucket per block.
// ---------------------------------------------------------------------------
__global__ __launch_bounds__(1024) void bucket_hist_kernel(
    const int* __restrict__ d_pg, const int* __restrict__ d_ps,
    const int* __restrict__ d_gp, const int* __restrict__ d_sp,
    int* __restrict__ bucketCounts)
{
    __shared__ int hist[NB];
    const int tid = threadIdx.x;
    for (int i = tid; i < NB; i += 1024) hist[i] = 0;
    __syncthreads();
    for (int e = blockIdx.x * 1024 + tid; e < E_TOT; e += H_NBLK * 1024) {
        int idx;
        if (e < E_PG)                    idx = BASE_PG + d_pg[e];
        else if (e < E_PG + E_PS)        idx = BASE_PS + d_ps[e - E_PG];
        else if (e < E_PG + E_PS + E_GP) idx = BASE_GP + d_gp[e - E_PG - E_PS];
        else                             idx = BASE_SP + d_sp[e - E_PG - E_PS - E_GP];
        atomicAdd(&hist[idx >> 8], 1);
    }
    __syncthreads();
    for (int i = tid; i < NB; i += 1024) {
        int c = hist[i];
        if (c) atomicAdd(&bucketCounts[i], c);
    }
}

// ---------------------------------------------------------------------------
// Single-block exclusive scan over the 665 bucket counts. Seeds gcursor with
// bucket start offsets.
// ---------------------------------------------------------------------------
__global__ __launch_bounds__(1024) void bucket_scan_kernel(
    const int* __restrict__ bucketCounts, int* __restrict__ bucketOff,
    int* __restrict__ gcursor, int* __restrict__ off_all)
{
    __shared__ int sp[1024];
    const int t = threadIdx.x;
    int v = (t < NB) ? bucketCounts[t] : 0;
    sp[t] = v;
    __syncthreads();
    for (int ofs = 1; ofs < 1024; ofs <<= 1) {
        int add = (t >= ofs) ? sp[t - ofs] : 0;
        __syncthreads();
        sp[t] += add;
        __syncthreads();
    }
    if (t < NB) {
        int excl = sp[t] - v;
        bucketOff[t] = excl;
        gcursor[t] = excl;
    }
    if (t == 0) { bucketOff[NB] = E_TOT; off_all[NTOT] = E_TOT; }
}

// ---------------------------------------------------------------------------
// Pass 1: bin edges into 256-node buckets. Entry packed: (idx&255) | (src<<8).
// ---------------------------------------------------------------------------
__global__ __launch_bounds__(1024) void bin_kernel(
    const int* __restrict__ s_pg, const int* __restrict__ d_pg,
    const int* __restrict__ s_ps, const int* __restrict__ d_ps,
    const int* __restrict__ s_gp, const int* __restrict__ d_gp,
    const int* __restrict__ s_sp, const int* __restrict__ d_sp,
    int* __restrict__ gcursor, unsigned* __restrict__ pairs)
{
    __shared__ int hist[NB];
    __shared__ int chunkBase[NB];
    const int tid = threadIdx.x;
    for (int i = tid; i < NB; i += 1024) hist[i] = 0;
    __syncthreads();

    const int base = blockIdx.x * BIN_EPB;
    int bkt[BIN_EPT], rnk[BIN_EPT];
    unsigned pk[BIN_EPT];
#pragma unroll
    for (int k = 0; k < BIN_EPT; ++k) {
        int e = base + k * 1024 + tid;
        int idx = -1, src = 0;
        if (e < E_PG) { idx = BASE_PG + d_pg[e]; src = s_pg[e]; }
        else if (e < E_PG + E_PS) { int i2 = e - E_PG; idx = BASE_PS + d_ps[i2]; src = s_ps[i2]; }
        else if (e < E_PG + E_PS + E_GP) { int i2 = e - E_PG - E_PS; idx = BASE_GP + d_gp[i2]; src = s_gp[i2]; }
        else if (e < E_TOT) { int i2 = e - E_PG - E_PS - E_GP; idx = BASE_SP + d_sp[i2]; src = s_sp[i2]; }
        if (idx >= 0) {
            int b = idx >> 8;
            bkt[k] = b;
            rnk[k] = atomicAdd(&hist[b], 1);
            pk[k] = (unsigned)(idx & 255) | ((unsigned)src << 8);
        } else bkt[k] = -1;
    }
    __syncthreads();
    for (int i = tid; i < NB; i += 1024) {
        int c = hist[i];
        chunkBase[i] = c ? atomicAdd(&gcursor[i], c) : 0;
    }
    __syncthreads();
#pragma unroll
    for (int k = 0; k < BIN_EPT; ++k)
        if (bkt[k] >= 0) pairs[chunkBase[bkt[k]] + rnk[k]] = pk[k];
}

// ---------------------------------------------------------------------------
// Pass 2: one block per bucket. Per-node counts recovered from the packed
// pairs with LDS atomics, scanned in LDS to produce off_all for this bucket,
// then scatter into the LDS segment and stream out coalesced.
// ---------------------------------------------------------------------------
__global__ __launch_bounds__(1024) void unbin_kernel(
    const unsigned* __restrict__ pairs, const int* __restrict__ bucketOff,
    int* __restrict__ off_all, int* __restrict__ perm_all)
{
    __shared__ int sPerm[SEG_CAP];
    __shared__ int cnt[256];
    __shared__ int sp[256];
    __shared__ int cur[256];
    const int b = blockIdx.x;
    const int nb0 = b << 8;
    const int nb1 = min(nb0 + 256, NTOT);
    const int tid = threadIdx.x;
    const int base = bucketOff[b];
    const int end  = bucketOff[b + 1];
    const int len = end - base;

    if (tid < 256) cnt[tid] = 0;
    __syncthreads();
    for (int i = base + tid; i < end; i += 1024)
        atomicAdd(&cnt[pairs[i] & 255u], 1);
    __syncthreads();
    int v = (tid < 256) ? cnt[tid] : 0;
    if (tid < 256) sp[tid] = v;
    __syncthreads();
    for (int ofs = 1; ofs < 256; ofs <<= 1) {
        int add = (tid < 256 && tid >= ofs) ? sp[tid - ofs] : 0;
        __syncthreads();
        if (tid < 256) sp[tid] += add;
        __syncthreads();
    }
    if (tid < 256) {
        int excl = sp[tid] - v;
        cur[tid] = excl;
        if (nb0 + tid < nb1) off_all[nb0 + tid] = base + excl;
    }
    __syncthreads();

    if (len <= SEG_CAP) {
        for (int i = base + tid; i < end; i += 1024) {
            unsigned p = pairs[i];
            int pos = atomicAdd(&cur[p & 255u], 1);
            sPerm[pos] = (int)(p >> 8);
        }
        __syncthreads();
        for (int i = tid; i < len; i += 1024)
            perm_all[base + i] = sPerm[i];
    } else {
        for (int i = base + tid; i < end; i += 1024) {
            unsigned p = pairs[i];
            int pos = atomicAdd(&cur[p & 255u], 1);
            perm_all[base + pos] = (int)(p >> 8);
        }
    }
}

// ---------------------------------------------------------------------------
// Launch
// ---------------------------------------------------------------------------
extern "C" void kernel_launch(void* const* d_in, const int* in_sizes, int n_in,
                              void* d_out, int out_size, void* d_ws, size_t ws_size,
                              hipStream_t stream)
{
    const float* x_pfas = (const float*)d_in[0];
    const float* x_gw   = (const float*)d_in[1];
    const float* x_sw   = (const float*)d_in[2];
    const int* ei_pg_src = (const int*)d_in[3];
    const int* ei_pg_dst = (const int*)d_in[4];
    const int* ei_gp_src = (const int*)d_in[5];
    const int* ei_gp_dst = (const int*)d_in[6];
    const int* ei_ps_src = (const int*)d_in[7];
    const int* ei_ps_dst = (const int*)d_in[8];
    const int* ei_sp_src = (const int*)d_in[9];
    const int* ei_sp_dst = (const int*)d_in[10];
    const float* Wl_pg = (const float*)d_in[11];
    const float* bl_pg = (const float*)d_in[12];
    const float* Wr_pg = (const float*)d_in[13];
    const float* Wl_gp = (const float*)d_in[14];
    const float* bl_gp = (const float*)d_in[15];
    const float* Wr_gp = (const float*)d_in[16];
    const float* Wl_ps = (const float*)d_in[17];
    const float* bl_ps = (const float*)d_in[18];
    const float* Wr_ps = (const float*)d_in[19];
    const float* Wl_sp = (const float*)d_in[20];
    const float* bl_sp = (const float*)d_in[21];
    const float* Wr_sp = (const float*)d_in[22];
    const float* W_gw = (const float*)d_in[23];
    const float* b_gw = (const float*)d_in[24];
    const float* W_sw = (const float*)d_in[25];
    const float* b_sw = (const float*)d_in[26];

    float* out  = (float*)d_out;
    float* h_pf = out;                         // 20000*128
    float* o_gw = out + (size_t)N_PFAS * 128;  // 100000
    float* o_sw = o_gw + N_GW;                 // 30000

    // ---- workspace layout (~90 MB) ----
    char* p = (char*)d_ws;
    auto alloc = [&](size_t bytes) { char* q = p; p += (bytes + 15) & ~(size_t)15; return q; };
    unsigned short* bufT_pg = (unsigned short*)alloc((size_t)N_PFAS * 128 * 2);
    unsigned short* bufT_ps = (unsigned short*)alloc((size_t)N_PFAS * 128 * 2);
    unsigned short* bufT_gp = (unsigned short*)alloc((size_t)N_GW * 128 * 2);
    unsigned short* bufT_sp = (unsigned short*)alloc((size_t)N_SW * 128 * 2);
    float* contrib_gp = (float*)alloc((size_t)N_PFAS * 128 * 4);
    float* contrib_sp = (float*)alloc((size_t)N_PFAS * 128 * 4);
    int* perm_all   = (int*)alloc((size_t)E_TOT * 4);
    unsigned* pairs = (unsigned*)alloc((size_t)E_TOT * 4);
    int* off_all    = (int*)alloc((size_t)(NTOT + 1) * 4);
    int* bucketCounts = (int*)alloc((size_t)NB * 4);
    int* bucketOff    = (int*)alloc((size_t)(NB + 1) * 4);
    int* gcursor    = (int*)alloc((size_t)NB * 4);

    // ---- 1. unified bf16 transforms (all 4 relations) ----
    gemm_t16_all_kernel<<<TILES_ALL, 256, 0, stream>>>(
        x_pfas, x_gw, x_sw, Wl_pg, Wl_ps, Wl_gp, Wl_sp,
        bufT_pg, bufT_ps, bufT_gp, bufT_sp);

    // ---- 2. CSR build: bucket hist -> bucket scan -> bucketed permute ----
    hipMemsetAsync(bucketCounts, 0, (size_t)NB * 4, stream);
    bucket_hist_kernel<<<H_NBLK, 1024, 0, stream>>>(
        ei_pg_dst, ei_ps_dst, ei_gp_dst, ei_sp_dst, bucketCounts);
    bucket_scan_kernel<<<1, 1024, 0, stream>>>(
        bucketCounts, bucketOff, gcursor, off_all);
    bin_kernel<<<BIN_NBLK, 1024, 0, stream>>>(
        ei_pg_src, ei_pg_dst, ei_ps_src, ei_ps_dst,
        ei_gp_src, ei_gp_dst, ei_sp_src, ei_sp_dst, gcursor, pairs);
    unbin_kernel<<<NB, 1024, 0, stream>>>(pairs, bucketOff, off_all, perm_all);

    // ---- 3. merged gw + sw fused node pass (512 threads, 64 rows/block) ----
    gemm_gather_scalar_kernel<<<GW_BLKS + SW_BLKS, 512, 0, stream>>>(
        x_gw, x_sw, Wr_pg, Wr_ps, bl_pg, bl_ps, bufT_pg, bufT_ps,
        perm_all, off_all, W_gw, b_gw, W_sw, b_sw, o_gw, o_sw);

    // ---- 4. bf16 segment contributions into pfas ----
    dim3 gS((N_PFAS + 7) / 8, 2);
    seg_contrib_kernel<<<gS, 256, 0, stream>>>(
        bufT_gp, bufT_sp, off_all, perm_all, contrib_gp, contrib_sp);

    // ---- 5. pfas node pass (single GEMM + contrib epilogue) ----
    gemm_pf_kernel<<<(N_PFAS + 127) / 128, 256, 0, stream>>>(
        N_PFAS, x_pfas, Wr_gp, Wr_sp, contrib_gp, contrib_sp,
        bl_gp, bl_sp, h_pf);
}

// Round 3
// 463.421 us; speedup vs baseline: 1.3655x; 1.0694x over previous
//
#include <hip/hip_runtime.h>

// ---------------------------------------------------------------------------
// Problem constants
// ---------------------------------------------------------------------------
#define N_PFAS 20000
#define N_GW   100000
#define N_SW   30000
#define E_PG   1600000
#define E_GP   640000
#define E_PS   480000
#define E_SP   320000
#define E_TOT  (E_PG + E_PS + E_GP + E_SP)
// Concatenated node-count layout: [pg: N_GW][ps: N_SW][gp: N_PFAS][sp: N_PFAS]
#define BASE_PG 0
#define BASE_PS (N_GW)
#define BASE_GP (N_GW + N_SW)
#define BASE_SP (N_GW + N_SW + N_PFAS)
#define NTOT    (N_GW + N_SW + 2 * N_PFAS)
// Bucketed permute: 256 nodes per bucket.
#define NB        ((NTOT + 255) / 256)       // 665
#define BIN_EPT   12
#define BIN_EPB   (1024 * BIN_EPT)
#define BIN_NBLK  ((E_TOT + BIN_EPB - 1) / BIN_EPB)
#define SEG_CAP   15360
#define H_NBLK    128                        // bucket-hist grid
// Unified transform pass tiles (128 rows each)
#define TILES_PF  ((N_PFAS + 127) / 128)     // 157
#define TILES_GW  ((N_GW + 127) / 128)       // 782
#define TILES_SW  ((N_SW + 127) / 128)       // 235
#define TILES_ALL (2 * TILES_PF + TILES_GW + TILES_SW)
// Merged gw/sw node pass (64 rows per block)
#define GW_BLKS   ((N_GW + 63) / 64)         // 1563
#define SW_BLKS   ((N_SW + 63) / 64)         // 469

// ---------------------------------------------------------------------------
// f16 helpers: transformed rows stored as f16; aggregation via v_pk_add_f16
// (1 VALU per 2 channels vs 4 for bf16 unpack+add). Values are O(1..50) so
// f16 (10-bit mantissa) is strictly more accurate than bf16 here.
// ---------------------------------------------------------------------------
typedef _Float16 h2_t __attribute__((ext_vector_type(2)));
union HU { unsigned u; h2_t h; };
__device__ __forceinline__ h2_t u2h2(unsigned u) { HU x; x.u = u; return x.h; }
__device__ __forceinline__ unsigned h22u(h2_t h) { HU x; x.h = h; return x.u; }

// ---------------------------------------------------------------------------
// GEMM tile: NT threads, ROWS rows/block, 32-k chunks in LDS.
// acc must be compile-time indexed by callers (dynamic indexing -> scratch!).
// ---------------------------------------------------------------------------
template<int NT, int ROWS>
__device__ __forceinline__ void tile_gemm(
    const float* __restrict__ X, const float* __restrict__ Wa,
    const float* __restrict__ Wb, int n, int row0, int tid,
    float4* sW4, float* sX, float4* acc)
{
    constexpr int TY  = NT / 32;
    constexpr int RPT = ROWS / TY;
    const int tx = tid & 31;
    const int ty = tid >> 5;
    const float4* X4 = (const float4*)X;
    const float4* Wa4 = (const float4*)Wa;
    const float4* Wb4 = (const float4*)Wb;

    for (int kc = 0; kc < 4; ++kc) {
        __syncthreads();
        for (int i = tid; i < 1024; i += NT) {
            float4 w = Wa4[kc * 1024 + i];
            if (Wb) {
                float4 b = Wb4[kc * 1024 + i];
                w.x += b.x; w.y += b.y; w.z += b.z; w.w += b.w;
            }
            sW4[i] = w;
        }
        for (int j = tid; j < ROWS * 8; j += NT) {
            int rr = j >> 3, k4 = j & 7;
            int r = row0 + rr;
            float4 xv = make_float4(0.f, 0.f, 0.f, 0.f);
            if (r < n) xv = X4[(size_t)r * 32 + kc * 8 + k4];
            int kk = k4 * 4;
            sX[(kk + 0) * ROWS + rr] = xv.x;
            sX[(kk + 1) * ROWS + rr] = xv.y;
            sX[(kk + 2) * ROWS + rr] = xv.z;
            sX[(kk + 3) * ROWS + rr] = xv.w;
        }
        __syncthreads();
#pragma unroll 4
        for (int k = 0; k < 32; ++k) {
            float4 w4 = sW4[k * 32 + tx];
            const float4* xr4 = (const float4*)&sX[k * ROWS + ty * RPT];
#pragma unroll
            for (int q = 0; q < RPT / 4; ++q) {
                float4 x4 = xr4[q];
                acc[q * 4 + 0].x += x4.x * w4.x; acc[q * 4 + 0].y += x4.x * w4.y;
                acc[q * 4 + 0].z += x4.x * w4.z; acc[q * 4 + 0].w += x4.x * w4.w;
                acc[q * 4 + 1].x += x4.y * w4.x; acc[q * 4 + 1].y += x4.y * w4.y;
                acc[q * 4 + 1].z += x4.y * w4.z; acc[q * 4 + 1].w += x4.y * w4.w;
                acc[q * 4 + 2].x += x4.z * w4.x; acc[q * 4 + 2].y += x4.z * w4.y;
                acc[q * 4 + 2].z += x4.z * w4.z; acc[q * 4 + 2].w += x4.z * w4.w;
                acc[q * 4 + 3].x += x4.w * w4.x; acc[q * 4 + 3].y += x4.w * w4.y;
                acc[q * 4 + 3].z += x4.w * w4.z; acc[q * 4 + 3].w += x4.w * w4.w;
            }
        }
    }
}

// ---------------------------------------------------------------------------
// Unified transform pass: bufT_* = X @ Wl  (f16 out) for all 4 relations.
// 1331 blocks of 128 rows.
// ---------------------------------------------------------------------------
__global__ __launch_bounds__(256, 2) void gemm_t16_all_kernel(
    const float* __restrict__ x_pfas, const float* __restrict__ x_gw,
    const float* __restrict__ x_sw,
    const float* __restrict__ Wl_pg, const float* __restrict__ Wl_ps,
    const float* __restrict__ Wl_gp, const float* __restrict__ Wl_sp,
    unsigned short* __restrict__ bufT_pg, unsigned short* __restrict__ bufT_ps,
    unsigned short* __restrict__ bufT_gp, unsigned short* __restrict__ bufT_sp)
{
    __shared__ float sW[32 * 128];
    __shared__ float sX[32 * 128];
    const int b = blockIdx.x;
    const float* X; const float* W; unsigned short* out; int n; int tile;
    if (b < TILES_PF)            { X = x_pfas; W = Wl_pg; out = bufT_pg; n = N_PFAS; tile = b; }
    else if (b < 2 * TILES_PF)   { X = x_pfas; W = Wl_ps; out = bufT_ps; n = N_PFAS; tile = b - TILES_PF; }
    else if (b < 2 * TILES_PF + TILES_GW)
                                 { X = x_gw;   W = Wl_gp; out = bufT_gp; n = N_GW;   tile = b - 2 * TILES_PF; }
    else                         { X = x_sw;   W = Wl_sp; out = bufT_sp; n = N_SW;   tile = b - 2 * TILES_PF - TILES_GW; }
    const int tid = threadIdx.x;
    const int row0 = tile * 128;

    float4 acc[16];
#pragma unroll
    for (int i = 0; i < 16; ++i) acc[i] = make_float4(0.f, 0.f, 0.f, 0.f);
    tile_gemm<256, 128>(X, W, nullptr, n, row0, tid, (float4*)sW, sX, acc);

    const int tx = tid & 31;
    const int rbase = row0 + (tid >> 5) * 16;
#pragma unroll
    for (int rr = 0; rr < 16; ++rr) {
        int r = rbase + rr;
        if (r < n) {
            h2_t p01; p01.x = (_Float16)acc[rr].x; p01.y = (_Float16)acc[rr].y;
            h2_t p23; p23.x = (_Float16)acc[rr].z; p23.y = (_Float16)acc[rr].w;
            uint2 o;
            o.x = h22u(p01);
            o.y = h22u(p23);
            *(uint2*)(out + (size_t)r * 128 + tx * 4) = o;
        }
    }
}

// ---------------------------------------------------------------------------
// Merged gw+sw node pass: 512 threads, 64 rows/block -> 16 groups x 4 rows.
// GEMM X@Wr fused with 8-ILP CSR gather of f16 neighbor rows (pk_add_f16
// accumulate) + scalar head.
// ---------------------------------------------------------------------------
__global__ __launch_bounds__(512, 4) void gemm_gather_scalar_kernel(
    const float* __restrict__ x_gw, const float* __restrict__ x_sw,
    const float* __restrict__ Wr_pg, const float* __restrict__ Wr_ps,
    const float* __restrict__ bl_pg, const float* __restrict__ bl_ps,
    const unsigned short* __restrict__ bufT_pg,
    const unsigned short* __restrict__ bufT_ps,
    const int* __restrict__ perm, const int* __restrict__ off_all,
    const float* __restrict__ W_gw, const float* __restrict__ b_gw,
    const float* __restrict__ W_sw, const float* __restrict__ b_sw,
    float* __restrict__ o_gw, float* __restrict__ o_sw)
{
    __shared__ float sW[32 * 128];
    __shared__ float sX[32 * 64];
    const int b = blockIdx.x;
    int n; const float* X; const float* Wr; const float* bl;
    const unsigned short* bufT16; const int* off;
    const float* wout; const float* bout; float* out; int tile;
    if (b < GW_BLKS) {
        n = N_GW; X = x_gw; Wr = Wr_pg; bl = bl_pg; bufT16 = bufT_pg;
        off = off_all + BASE_PG; wout = W_gw; bout = b_gw; out = o_gw; tile = b;
    } else {
        n = N_SW; X = x_sw; Wr = Wr_ps; bl = bl_ps; bufT16 = bufT_ps;
        off = off_all + BASE_PS; wout = W_sw; bout = b_sw; out = o_sw; tile = b - GW_BLKS;
    }
    const int tid = threadIdx.x;
    const int row0 = tile * 64;
    float4 acc[4];
#pragma unroll
    for (int i = 0; i < 4; ++i) acc[i] = make_float4(0.f, 0.f, 0.f, 0.f);
    tile_gemm<512, 64>(X, Wr, nullptr, n, row0, tid, (float4*)sW, sX, acc);

    const int tx = tid & 31;
    const int rbase = row0 + (tid >> 5) * 4;
    float4 bv = ((const float4*)bl)[tx];
    float4 wo = ((const float4*)wout)[tx];
    float bo = bout[0];

    h2_t hz; hz.x = (_Float16)0.f; hz.y = (_Float16)0.f;

#pragma unroll
    for (int rr = 0; rr < 4; ++rr) {
        int r = rbase + rr;
        int lo = 0, hi = 0;
        if (r < n) { lo = off[r]; hi = off[r + 1]; }
        h2_t a0 = hz, a1 = hz, a2 = hz, a3 = hz, a4 = hz, a5 = hz, a6 = hz, a7 = hz;
        int i = lo;
        for (; i + 8 <= hi; i += 8) {
            uint2 v0 = *(const uint2*)(bufT16 + (size_t)perm[i + 0] * 128 + tx * 4);
            uint2 v1 = *(const uint2*)(bufT16 + (size_t)perm[i + 1] * 128 + tx * 4);
            uint2 v2 = *(const uint2*)(bufT16 + (size_t)perm[i + 2] * 128 + tx * 4);
            uint2 v3 = *(const uint2*)(bufT16 + (size_t)perm[i + 3] * 128 + tx * 4);
            uint2 v4 = *(const uint2*)(bufT16 + (size_t)perm[i + 4] * 128 + tx * 4);
            uint2 v5 = *(const uint2*)(bufT16 + (size_t)perm[i + 5] * 128 + tx * 4);
            uint2 v6 = *(const uint2*)(bufT16 + (size_t)perm[i + 6] * 128 + tx * 4);
            uint2 v7 = *(const uint2*)(bufT16 + (size_t)perm[i + 7] * 128 + tx * 4);
            a0 += u2h2(v0.x); a1 += u2h2(v0.y);
            a2 += u2h2(v1.x); a3 += u2h2(v1.y);
            a4 += u2h2(v2.x); a5 += u2h2(v2.y);
            a6 += u2h2(v3.x); a7 += u2h2(v3.y);
            a0 += u2h2(v4.x); a1 += u2h2(v4.y);
            a2 += u2h2(v5.x); a3 += u2h2(v5.y);
            a4 += u2h2(v6.x); a5 += u2h2(v6.y);
            a6 += u2h2(v7.x); a7 += u2h2(v7.y);
        }
        for (; i + 2 <= hi; i += 2) {
            uint2 v0 = *(const uint2*)(bufT16 + (size_t)perm[i + 0] * 128 + tx * 4);
            uint2 v1 = *(const uint2*)(bufT16 + (size_t)perm[i + 1] * 128 + tx * 4);
            a0 += u2h2(v0.x); a1 += u2h2(v0.y);
            a2 += u2h2(v1.x); a3 += u2h2(v1.y);
        }
        if (i < hi) {
            uint2 v0 = *(const uint2*)(bufT16 + (size_t)perm[i] * 128 + tx * 4);
            a0 += u2h2(v0.x); a1 += u2h2(v0.y);
        }
        h2_t tl = (a0 + a2) + (a4 + a6);
        h2_t th = (a1 + a3) + (a5 + a7);
        float inv = 1.0f / fmaxf((float)(hi - lo), 1.0f);
        float h0 = fmaxf(acc[rr].x + bv.x + (float)tl.x * inv, 0.f);
        float h1 = fmaxf(acc[rr].y + bv.y + (float)tl.y * inv, 0.f);
        float h2v = fmaxf(acc[rr].z + bv.z + (float)th.x * inv, 0.f);
        float h3 = fmaxf(acc[rr].w + bv.w + (float)th.y * inv, 0.f);
        float p = h0 * wo.x + h1 * wo.y + h2v * wo.z + h3 * wo.w;
        p += __shfl_xor(p, 1, 32);
        p += __shfl_xor(p, 2, 32);
        p += __shfl_xor(p, 4, 32);
        p += __shfl_xor(p, 8, 32);
        p += __shfl_xor(p, 16, 32);
        if (tx == 0 && r < n) out[r] = p + bo;
    }
}

// ---------------------------------------------------------------------------
// Segment contributions for pfas: contrib[node] = (Σ bufT16[src]) / cnt.
// Half-wave per node, 8 nodes/block, 8-ILP f16 pk_add gather. grid.y = rel.
// ---------------------------------------------------------------------------
__global__ __launch_bounds__(256, 4) void seg_contrib_kernel(
    const unsigned short* __restrict__ bufT_gp,
    const unsigned short* __restrict__ bufT_sp,
    const int* __restrict__ off_all, const int* __restrict__ perm_all,
    float* __restrict__ contrib_gp, float* __restrict__ contrib_sp)
{
    const unsigned short* bufT; const int* off; float* contrib;
    if (blockIdx.y == 0) { bufT = bufT_gp; off = off_all + BASE_GP; contrib = contrib_gp; }
    else                 { bufT = bufT_sp; off = off_all + BASE_SP; contrib = contrib_sp; }

    int node = blockIdx.x * 8 + (threadIdx.x >> 5);
    if (node >= N_PFAS) return;
    int tx = threadIdx.x & 31;
    int lo = off[node], hi = off[node + 1];
    h2_t hz; hz.x = (_Float16)0.f; hz.y = (_Float16)0.f;
    h2_t a0 = hz, a1 = hz, a2 = hz, a3 = hz, a4 = hz, a5 = hz, a6 = hz, a7 = hz;
    int i = lo;
    for (; i + 8 <= hi; i += 8) {
        uint2 v0 = *(const uint2*)(bufT + (size_t)perm_all[i + 0] * 128 + tx * 4);
        uint2 v1 = *(const uint2*)(bufT + (size_t)perm_all[i + 1] * 128 + tx * 4);
        uint2 v2 = *(const uint2*)(bufT + (size_t)perm_all[i + 2] * 128 + tx * 4);
        uint2 v3 = *(const uint2*)(bufT + (size_t)perm_all[i + 3] * 128 + tx * 4);
        uint2 v4 = *(const uint2*)(bufT + (size_t)perm_all[i + 4] * 128 + tx * 4);
        uint2 v5 = *(const uint2*)(bufT + (size_t)perm_all[i + 5] * 128 + tx * 4);
        uint2 v6 = *(const uint2*)(bufT + (size_t)perm_all[i + 6] * 128 + tx * 4);
        uint2 v7 = *(const uint2*)(bufT + (size_t)perm_all[i + 7] * 128 + tx * 4);
        a0 += u2h2(v0.x); a1 += u2h2(v0.y);
        a2 += u2h2(v1.x); a3 += u2h2(v1.y);
        a4 += u2h2(v2.x); a5 += u2h2(v2.y);
        a6 += u2h2(v3.x); a7 += u2h2(v3.y);
        a0 += u2h2(v4.x); a1 += u2h2(v4.y);
        a2 += u2h2(v5.x); a3 += u2h2(v5.y);
        a4 += u2h2(v6.x); a5 += u2h2(v6.y);
        a6 += u2h2(v7.x); a7 += u2h2(v7.y);
    }
    for (; i + 2 <= hi; i += 2) {
        uint2 v0 = *(const uint2*)(bufT + (size_t)perm_all[i + 0] * 128 + tx * 4);
        uint2 v1 = *(const uint2*)(bufT + (size_t)perm_all[i + 1] * 128 + tx * 4);
        a0 += u2h2(v0.x); a1 += u2h2(v0.y);
        a2 += u2h2(v1.x); a3 += u2h2(v1.y);
    }
    if (i < hi) {
        uint2 v0 = *(const uint2*)(bufT + (size_t)perm_all[i] * 128 + tx * 4);
        a0 += u2h2(v0.x); a1 += u2h2(v0.y);
    }
    h2_t tl = (a0 + a2) + (a4 + a6);
    h2_t th = (a1 + a3) + (a5 + a7);
    float inv = 1.0f / fmaxf((float)(hi - lo), 1.0f);
    float4 o;
    o.x = (float)tl.x * inv;
    o.y = (float)tl.y * inv;
    o.z = (float)th.x * inv;
    o.w = (float)th.y * inv;
    ((float4*)contrib)[(size_t)node * 32 + tx] = o;
}

// ---------------------------------------------------------------------------
// pfas node pass: h_pf = relu(x@(WrA+WrB) + contrib_gp + contrib_sp + blG+blS)
// ---------------------------------------------------------------------------
__global__ __launch_bounds__(256, 2) void gemm_pf_kernel(
    int n, const float* __restrict__ x,
    const float* __restrict__ WrA, const float* __restrict__ WrB,
    const float* __restrict__ contrib_gp, const float* __restrict__ contrib_sp,
    const float* __restrict__ blG, const float* __restrict__ blS,
    float* __restrict__ out)
{
    __shared__ float sW[32 * 128];
    __shared__ float sX[32 * 128];
    const int tid = threadIdx.x;
    const int row0 = blockIdx.x * 128;
    float4 acc[16];
#pragma unroll
    for (int i = 0; i < 16; ++i) acc[i] = make_float4(0.f, 0.f, 0.f, 0.f);
    tile_gemm<256, 128>(x, WrA, WrB, n, row0, tid, (float4*)sW, sX, acc);

    const int tx = tid & 31;
    const int rbase = row0 + (tid >> 5) * 16;
    float4 b1 = ((const float4*)blG)[tx];
    float4 b2 = ((const float4*)blS)[tx];
#pragma unroll
    for (int rr = 0; rr < 16; ++rr) {
        int r = rbase + rr;
        if (r < n) {
            float4 cg = ((const float4*)contrib_gp)[(size_t)r * 32 + tx];
            float4 cs = ((const float4*)contrib_sp)[(size_t)r * 32 + tx];
            float4 o = acc[rr];
            o.x = fmaxf(o.x + cg.x + cs.x + b1.x + b2.x, 0.f);
            o.y = fmaxf(o.y + cg.y + cs.y + b1.y + b2.y, 0.f);
            o.z = fmaxf(o.z + cg.z + cs.z + b1.z + b2.z, 0.f);
            o.w = fmaxf(o.w + cg.w + cs.w + b1.w + b2.w, 0.f);
            ((float4*)out)[(size_t)r * 32 + tx] = o;
        }
    }
}

// ---------------------------------------------------------------------------
// Bucket-level histogram: LDS-privatized per block (665 counters), then one
// global atomicAdd per nonzero bucket per block.
// ---------------------------------------------------------------------------
__global__ __launch_bounds__(1024) void bucket_hist_kernel(
    const int* __restrict__ d_pg, const int* __restrict__ d_ps,
    const int* __restrict__ d_gp, const int* __restrict__ d_sp,
    int* __restrict__ bucketCounts)
{
    __shared__ int hist[NB];
    const int tid = threadIdx.x;
    for (int i = tid; i < NB; i += 1024) hist[i] = 0;
    __syncthreads();
    for (int e = blockIdx.x * 1024 + tid; e < E_TOT; e += H_NBLK * 1024) {
        int idx;
        if (e < E_PG)                    idx = BASE_PG + d_pg[e];
        else if (e < E_PG + E_PS)        idx = BASE_PS + d_ps[e - E_PG];
        else if (e < E_PG + E_PS + E_GP) idx = BASE_GP + d_gp[e - E_PG - E_PS];
        else                             idx = BASE_SP + d_sp[e - E_PG - E_PS - E_GP];
        atomicAdd(&hist[idx >> 8], 1);
    }
    __syncthreads();
    for (int i = tid; i < NB; i += 1024) {
        int c = hist[i];
        if (c) atomicAdd(&bucketCounts[i], c);
    }
}

// ---------------------------------------------------------------------------
// Single-block exclusive scan over the 665 bucket counts. Seeds gcursor with
// bucket start offsets.
// ---------------------------------------------------------------------------
__global__ __launch_bounds__(1024) void bucket_scan_kernel(
    const int* __restrict__ bucketCounts, int* __restrict__ bucketOff,
    int* __restrict__ gcursor, int* __restrict__ off_all)
{
    __shared__ int sp[1024];
    const int t = threadIdx.x;
    int v = (t < NB) ? bucketCounts[t] : 0;
    sp[t] = v;
    __syncthreads();
    for (int ofs = 1; ofs < 1024; ofs <<= 1) {
        int add = (t >= ofs) ? sp[t - ofs] : 0;
        __syncthreads();
        sp[t] += add;
        __syncthreads();
    }
    if (t < NB) {
        int excl = sp[t] - v;
        bucketOff[t] = excl;
        gcursor[t] = excl;
    }
    if (t == 0) { bucketOff[NB] = E_TOT; off_all[NTOT] = E_TOT; }
}

// ---------------------------------------------------------------------------
// Pass 1: bin edges into 256-node buckets. Entry packed: (idx&255) | (src<<8).
// ---------------------------------------------------------------------------
__global__ __launch_bounds__(1024) void bin_kernel(
    const int* __restrict__ s_pg, const int* __restrict__ d_pg,
    const int* __restrict__ s_ps, const int* __restrict__ d_ps,
    const int* __restrict__ s_gp, const int* __restrict__ d_gp,
    const int* __restrict__ s_sp, const int* __restrict__ d_sp,
    int* __restrict__ gcursor, unsigned* __restrict__ pairs)
{
    __shared__ int hist[NB];
    __shared__ int chunkBase[NB];
    const int tid = threadIdx.x;
    for (int i = tid; i < NB; i += 1024) hist[i] = 0;
    __syncthreads();

    const int base = blockIdx.x * BIN_EPB;
    int bkt[BIN_EPT], rnk[BIN_EPT];
    unsigned pk[BIN_EPT];
#pragma unroll
    for (int k = 0; k < BIN_EPT; ++k) {
        int e = base + k * 1024 + tid;
        int idx = -1, src = 0;
        if (e < E_PG) { idx = BASE_PG + d_pg[e]; src = s_pg[e]; }
        else if (e < E_PG + E_PS) { int i2 = e - E_PG; idx = BASE_PS + d_ps[i2]; src = s_ps[i2]; }
        else if (e < E_PG + E_PS + E_GP) { int i2 = e - E_PG - E_PS; idx = BASE_GP + d_gp[i2]; src = s_gp[i2]; }
        else if (e < E_TOT) { int i2 = e - E_PG - E_PS - E_GP; idx = BASE_SP + d_sp[i2]; src = s_sp[i2]; }
        if (idx >= 0) {
            int b = idx >> 8;
            bkt[k] = b;
            rnk[k] = atomicAdd(&hist[b], 1);
            pk[k] = (unsigned)(idx & 255) | ((unsigned)src << 8);
        } else bkt[k] = -1;
    }
    __syncthreads();
    for (int i = tid; i < NB; i += 1024) {
        int c = hist[i];
        chunkBase[i] = c ? atomicAdd(&gcursor[i], c) : 0;
    }
    __syncthreads();
#pragma unroll
    for (int k = 0; k < BIN_EPT; ++k)
        if (bkt[k] >= 0) pairs[chunkBase[bkt[k]] + rnk[k]] = pk[k];
}

// ---------------------------------------------------------------------------
// Pass 2: one block per bucket. Per-node counts recovered from the packed
// pairs with LDS atomics, scanned in LDS to produce off_all for this bucket,
// then scatter into the LDS segment and stream out coalesced.
// ---------------------------------------------------------------------------
__global__ __launch_bounds__(1024) void unbin_kernel(
    const unsigned* __restrict__ pairs, const int* __restrict__ bucketOff,
    int* __restrict__ off_all, int* __restrict__ perm_all)
{
    __shared__ int sPerm[SEG_CAP];
    __shared__ int cnt[256];
    __shared__ int sp[256];
    __shared__ int cur[256];
    const int b = blockIdx.x;
    const int nb0 = b << 8;
    const int nb1 = min(nb0 + 256, NTOT);
    const int tid = threadIdx.x;
    const int base = bucketOff[b];
    const int end  = bucketOff[b + 1];
    const int len = end - base;

    if (tid < 256) cnt[tid] = 0;
    __syncthreads();
    for (int i = base + tid; i < end; i += 1024)
        atomicAdd(&cnt[pairs[i] & 255u], 1);
    __syncthreads();
    int v = (tid < 256) ? cnt[tid] : 0;
    if (tid < 256) sp[tid] = v;
    __syncthreads();
    for (int ofs = 1; ofs < 256; ofs <<= 1) {
        int add = (tid < 256 && tid >= ofs) ? sp[tid - ofs] : 0;
        __syncthreads();
        if (tid < 256) sp[tid] += add;
        __syncthreads();
    }
    if (tid < 256) {
        int excl = sp[tid] - v;
        cur[tid] = excl;
        if (nb0 + tid < nb1) off_all[nb0 + tid] = base + excl;
    }
    __syncthreads();

    if (len <= SEG_CAP) {
        for (int i = base + tid; i < end; i += 1024) {
            unsigned p = pairs[i];
            int pos = atomicAdd(&cur[p & 255u], 1);
            sPerm[pos] = (int)(p >> 8);
        }
        __syncthreads();
        for (int i = tid; i < len; i += 1024)
            perm_all[base + i] = sPerm[i];
    } else {
        for (int i = base + tid; i < end; i += 1024) {
            unsigned p = pairs[i];
            int pos = atomicAdd(&cur[p & 255u], 1);
            perm_all[base + pos] = (int)(p >> 8);
        }
    }
}

// ---------------------------------------------------------------------------
// Launch
// ---------------------------------------------------------------------------
extern "C" void kernel_launch(void* const* d_in, const int* in_sizes, int n_in,
                              void* d_out, int out_size, void* d_ws, size_t ws_size,
                              hipStream_t stream)
{
    const float* x_pfas = (const float*)d_in[0];
    const float* x_gw   = (const float*)d_in[1];
    const float* x_sw   = (const float*)d_in[2];
    const int* ei_pg_src = (const int*)d_in[3];
    const int* ei_pg_dst = (const int*)d_in[4];
    const int* ei_gp_src = (const int*)d_in[5];
    const int* ei_gp_dst = (const int*)d_in[6];
    const int* ei_ps_src = (const int*)d_in[7];
    const int* ei_ps_dst = (const int*)d_in[8];
    const int* ei_sp_src = (const int*)d_in[9];
    const int* ei_sp_dst = (const int*)d_in[10];
    const float* Wl_pg = (const float*)d_in[11];
    const float* bl_pg = (const float*)d_in[12];
    const float* Wr_pg = (const float*)d_in[13];
    const float* Wl_gp = (const float*)d_in[14];
    const float* bl_gp = (const float*)d_in[15];
    const float* Wr_gp = (const float*)d_in[16];
    const float* Wl_ps = (const float*)d_in[17];
    const float* bl_ps = (const float*)d_in[18];
    const float* Wr_ps = (const float*)d_in[19];
    const float* Wl_sp = (const float*)d_in[20];
    const float* bl_sp = (const float*)d_in[21];
    const float* Wr_sp = (const float*)d_in[22];
    const float* W_gw = (const float*)d_in[23];
    const float* b_gw = (const float*)d_in[24];
    const float* W_sw = (const float*)d_in[25];
    const float* b_sw = (const float*)d_in[26];

    float* out  = (float*)d_out;
    float* h_pf = out;                         // 20000*128
    float* o_gw = out + (size_t)N_PFAS * 128;  // 100000
    float* o_sw = o_gw + N_GW;                 // 30000

    // ---- workspace layout (~90 MB) ----
    char* p = (char*)d_ws;
    auto alloc = [&](size_t bytes) { char* q = p; p += (bytes + 15) & ~(size_t)15; return q; };
    unsigned short* bufT_pg = (unsigned short*)alloc((size_t)N_PFAS * 128 * 2);
    unsigned short* bufT_ps = (unsigned short*)alloc((size_t)N_PFAS * 128 * 2);
    unsigned short* bufT_gp = (unsigned short*)alloc((size_t)N_GW * 128 * 2);
    unsigned short* bufT_sp = (unsigned short*)alloc((size_t)N_SW * 128 * 2);
    float* contrib_gp = (float*)alloc((size_t)N_PFAS * 128 * 4);
    float* contrib_sp = (float*)alloc((size_t)N_PFAS * 128 * 4);
    int* perm_all   = (int*)alloc((size_t)E_TOT * 4);
    unsigned* pairs = (unsigned*)alloc((size_t)E_TOT * 4);
    int* off_all    = (int*)alloc((size_t)(NTOT + 1) * 4);
    int* bucketCounts = (int*)alloc((size_t)NB * 4);
    int* bucketOff    = (int*)alloc((size_t)(NB + 1) * 4);
    int* gcursor    = (int*)alloc((size_t)NB * 4);

    // ---- 1. unified f16 transforms (all 4 relations) ----
    gemm_t16_all_kernel<<<TILES_ALL, 256, 0, stream>>>(
        x_pfas, x_gw, x_sw, Wl_pg, Wl_ps, Wl_gp, Wl_sp,
        bufT_pg, bufT_ps, bufT_gp, bufT_sp);

    // ---- 2. CSR build: bucket hist -> bucket scan -> bucketed permute ----
    hipMemsetAsync(bucketCounts, 0, (size_t)NB * 4, stream);
    bucket_hist_kernel<<<H_NBLK, 1024, 0, stream>>>(
        ei_pg_dst, ei_ps_dst, ei_gp_dst, ei_sp_dst, bucketCounts);
    bucket_scan_kernel<<<1, 1024, 0, stream>>>(
        bucketCounts, bucketOff, gcursor, off_all);
    bin_kernel<<<BIN_NBLK, 1024, 0, stream>>>(
        ei_pg_src, ei_pg_dst, ei_ps_src, ei_ps_dst,
        ei_gp_src, ei_gp_dst, ei_sp_src, ei_sp_dst, gcursor, pairs);
    unbin_kernel<<<NB, 1024, 0, stream>>>(pairs, bucketOff, off_all, perm_all);

    // ---- 3. merged gw + sw fused node pass (512 threads, 64 rows/block) ----
    gemm_gather_scalar_kernel<<<GW_BLKS + SW_BLKS, 512, 0, stream>>>(
        x_gw, x_sw, Wr_pg, Wr_ps, bl_pg, bl_ps, bufT_pg, bufT_ps,
        perm_all, off_all, W_gw, b_gw, W_sw, b_sw, o_gw, o_sw);

    // ---- 4. f16 segment contributions into pfas ----
    dim3 gS((N_PFAS + 7) / 8, 2);
    seg_contrib_kernel<<<gS, 256, 0, stream>>>(
        bufT_gp, bufT_sp, off_all, perm_all, contrib_gp, contrib_sp);

    // ---- 5. pfas node pass (single GEMM + contrib epilogue) ----
    gemm_pf_kernel<<<(N_PFAS + 127) / 128, 256, 0, stream>>>(
        N_PFAS, x_pfas, Wr_gp, Wr_sp, contrib_gp, contrib_sp,
        bl_gp, bl_sp, h_pf);
}

// Round 4
// 449.939 us; speedup vs baseline: 1.4064x; 1.0300x over previous
//
#include <hip/hip_runtime.h>

// ---------------------------------------------------------------------------
// Problem constants
// ---------------------------------------------------------------------------
#define N_PFAS 20000
#define N_GW   100000
#define N_SW   30000
#define E_PG   1600000
#define E_GP   640000
#define E_PS   480000
#define E_SP   320000
#define E_TOT  (E_PG + E_PS + E_GP + E_SP)
// Concatenated node-count layout: [pg: N_GW][ps: N_SW][gp: N_PFAS][sp: N_PFAS]
#define BASE_PG 0
#define BASE_PS (N_GW)
#define BASE_GP (N_GW + N_SW)
#define BASE_SP (N_GW + N_SW + N_PFAS)
#define NTOT    (N_GW + N_SW + 2 * N_PFAS)
// Bucketed permute: 256 nodes per bucket.
#define NB        ((NTOT + 255) / 256)       // 665
#define BIN_EPT   12
#define BIN_EPB   (1024 * BIN_EPT)
#define BIN_NBLK  ((E_TOT + BIN_EPB - 1) / BIN_EPB)
#define SEG_CAP   15360
#define H_NBLK    128                        // bucket-hist grid
// MFMA transform tiles (64 rows each)
#define T64_PF ((N_PFAS + 63) / 64)          // 313
#define T64_GW ((N_GW + 63) / 64)            // 1563
#define T64_SW ((N_SW + 63) / 64)            // 469
#define T64_ALL (T64_PF + T64_GW + T64_SW)
// Merged gather dispatch
#define GW_BLKS   ((N_GW + 63) / 64)         // 1563  (64 nodes/block)
#define SW_BLKS   ((N_SW + 63) / 64)         // 469
#define SEGP_BLKS (N_PFAS / 16)              // 1250  (16 nodes/block, exact)

// ---------------------------------------------------------------------------
// f16 helpers: transformed rows stored f16; aggregation via v_pk_add_f16.
// ---------------------------------------------------------------------------
typedef _Float16 h2_t  __attribute__((ext_vector_type(2)));
typedef _Float16 f16x8 __attribute__((ext_vector_type(8)));
typedef float    f32x4 __attribute__((ext_vector_type(4)));
union HU { unsigned u; h2_t h; };
__device__ __forceinline__ h2_t u2h2(unsigned u) { HU x; x.u = u; return x.h; }

// ---------------------------------------------------------------------------
// 8-ILP f16 gather-sum over a CSR segment: tl = sum of channels (4tx,4tx+1),
// th = (4tx+2, 4tx+3).
// ---------------------------------------------------------------------------
__device__ __forceinline__ void gather_sum_f16(
    const unsigned short* __restrict__ bufT16, const int* __restrict__ perm,
    int lo, int hi, int tx, h2_t& tl, h2_t& th)
{
    h2_t hz; hz.x = (_Float16)0.f; hz.y = (_Float16)0.f;
    h2_t a0 = hz, a1 = hz, a2 = hz, a3 = hz, a4 = hz, a5 = hz, a6 = hz, a7 = hz;
    int i = lo;
    for (; i + 8 <= hi; i += 8) {
        uint2 v0 = *(const uint2*)(bufT16 + (size_t)perm[i + 0] * 128 + tx * 4);
        uint2 v1 = *(const uint2*)(bufT16 + (size_t)perm[i + 1] * 128 + tx * 4);
        uint2 v2 = *(const uint2*)(bufT16 + (size_t)perm[i + 2] * 128 + tx * 4);
        uint2 v3 = *(const uint2*)(bufT16 + (size_t)perm[i + 3] * 128 + tx * 4);
        uint2 v4 = *(const uint2*)(bufT16 + (size_t)perm[i + 4] * 128 + tx * 4);
        uint2 v5 = *(const uint2*)(bufT16 + (size_t)perm[i + 5] * 128 + tx * 4);
        uint2 v6 = *(const uint2*)(bufT16 + (size_t)perm[i + 6] * 128 + tx * 4);
        uint2 v7 = *(const uint2*)(bufT16 + (size_t)perm[i + 7] * 128 + tx * 4);
        a0 += u2h2(v0.x); a1 += u2h2(v0.y);
        a2 += u2h2(v1.x); a3 += u2h2(v1.y);
        a4 += u2h2(v2.x); a5 += u2h2(v2.y);
        a6 += u2h2(v3.x); a7 += u2h2(v3.y);
        a0 += u2h2(v4.x); a1 += u2h2(v4.y);
        a2 += u2h2(v5.x); a3 += u2h2(v5.y);
        a4 += u2h2(v6.x); a5 += u2h2(v6.y);
        a6 += u2h2(v7.x); a7 += u2h2(v7.y);
    }
    for (; i + 2 <= hi; i += 2) {
        uint2 v0 = *(const uint2*)(bufT16 + (size_t)perm[i + 0] * 128 + tx * 4);
        uint2 v1 = *(const uint2*)(bufT16 + (size_t)perm[i + 1] * 128 + tx * 4);
        a0 += u2h2(v0.x); a1 += u2h2(v0.y);
        a2 += u2h2(v1.x); a3 += u2h2(v1.y);
    }
    if (i < hi) {
        uint2 v0 = *(const uint2*)(bufT16 + (size_t)perm[i] * 128 + tx * 4);
        a0 += u2h2(v0.x); a1 += u2h2(v0.y);
    }
    tl = (a0 + a2) + (a4 + a6);
    th = (a1 + a3) + (a5 + a7);
}

// ---------------------------------------------------------------------------
// Weight prep: f16 transposes Wt[n][k] = (f16)W[k][n] for all 7 products.
// Block m handles one matrix; m==2 sums Wr_gp+Wr_sp (pfas HeteroConv fusion).
// ---------------------------------------------------------------------------
__global__ __launch_bounds__(256) void prep_wt_kernel(
    const float* __restrict__ Wl_pg, const float* __restrict__ Wl_ps,
    const float* __restrict__ Wr_gp, const float* __restrict__ Wr_sp,
    const float* __restrict__ Wl_gp, const float* __restrict__ Wr_pg,
    const float* __restrict__ Wl_sp, const float* __restrict__ Wr_ps,
    _Float16* __restrict__ Wt_pg, _Float16* __restrict__ Wt_ps,
    _Float16* __restrict__ WtR_pf,
    _Float16* __restrict__ Wt_gp, _Float16* __restrict__ WtR_gw,
    _Float16* __restrict__ Wt_sp, _Float16* __restrict__ WtR_sw)
{
    const int m = blockIdx.x;
    const float* A = nullptr; const float* B = nullptr; _Float16* O = nullptr;
    switch (m) {
        case 0: A = Wl_pg; O = Wt_pg;  break;
        case 1: A = Wl_ps; O = Wt_ps;  break;
        case 2: A = Wr_gp; B = Wr_sp; O = WtR_pf; break;
        case 3: A = Wl_gp; O = Wt_gp;  break;
        case 4: A = Wr_pg; O = WtR_gw; break;
        case 5: A = Wl_sp; O = Wt_sp;  break;
        default: A = Wr_ps; O = WtR_sw; break;
    }
    for (int i = threadIdx.x; i < 16384; i += 256) {
        int k = i >> 7, n = i & 127;
        float v = A[i];
        if (B) v += B[i];
        O[n * 128 + k] = (_Float16)v;
    }
}

// ---------------------------------------------------------------------------
// One B-matrix MFMA pass: OUT[64 rows x 128] = X_tile @ W using
// mfma_f32_16x16x32_f16. A-frags in regs; B-frags straight from L2-hot Wt.
// C layout (verified): col = lane&15, row = (lane>>4)*4 + reg.
// ---------------------------------------------------------------------------
template<bool F16OUT>
__device__ __forceinline__ void mfma_one_B(
    const _Float16* __restrict__ Wt, const f16x8* a,
    int rbase, int n, int lane,
    _Float16* __restrict__ o16, float* __restrict__ o32)
{
    f32x4 acc[8];
#pragma unroll
    for (int ct = 0; ct < 8; ++ct) acc[ct] = (f32x4){0.f, 0.f, 0.f, 0.f};
    const int bcol = lane & 15;
    const int bko  = (lane >> 4) * 8;
#pragma unroll
    for (int ct = 0; ct < 8; ++ct) {
#pragma unroll
        for (int ks = 0; ks < 4; ++ks) {
            f16x8 bfrag = *(const f16x8*)(Wt + ((size_t)(ct * 16 + bcol) << 7) + ks * 32 + bko);
            acc[ct] = __builtin_amdgcn_mfma_f32_16x16x32_f16(a[ks], bfrag, acc[ct], 0, 0, 0);
        }
    }
    const int rowb = rbase + (lane >> 4) * 4;
#pragma unroll
    for (int ct = 0; ct < 8; ++ct) {
        const int col = ct * 16 + (lane & 15);
#pragma unroll
        for (int e = 0; e < 4; ++e) {
            int r = rowb + e;
            if (r < n) {
                if (F16OUT) o16[((size_t)r << 7) + col] = (_Float16)acc[ct][e];
                else        o32[((size_t)r << 7) + col] = acc[ct][e];
            }
        }
    }
}

// ---------------------------------------------------------------------------
// Unified MFMA transform: per 64-row X tile, load A-frags once (f32->f16 in
// regs, no LDS) and emit every needed product:
//   pfas: X@Wl_pg (f16), X@Wl_ps (f16), X@(Wr_gp+Wr_sp) (f32 R_pf)
//   gw:   X@Wl_gp (f16), X@Wr_pg (f16 R_gw)
//   sw:   X@Wl_sp (f16), X@Wr_ps (f16 R_sw)
// ---------------------------------------------------------------------------
__global__ __launch_bounds__(256, 4) void mfma_trans_kernel(
    const float* __restrict__ x_pfas, const float* __restrict__ x_gw,
    const float* __restrict__ x_sw,
    const _Float16* __restrict__ Wt_pg, const _Float16* __restrict__ Wt_ps,
    const _Float16* __restrict__ WtR_pf,
    const _Float16* __restrict__ Wt_gp, const _Float16* __restrict__ WtR_gw,
    const _Float16* __restrict__ Wt_sp, const _Float16* __restrict__ WtR_sw,
    _Float16* __restrict__ bufT_pg, _Float16* __restrict__ bufT_ps,
    float* __restrict__ R_pf,
    _Float16* __restrict__ bufT_gp, _Float16* __restrict__ R_gw,
    _Float16* __restrict__ bufT_sp, _Float16* __restrict__ R_sw)
{
    const int b = blockIdx.x;
    int mode, tile, n; const float* X;
    if (b < T64_PF)               { mode = 0; tile = b;                    X = x_pfas; n = N_PFAS; }
    else if (b < T64_PF + T64_GW) { mode = 1; tile = b - T64_PF;           X = x_gw;   n = N_GW; }
    else                          { mode = 2; tile = b - T64_PF - T64_GW;  X = x_sw;   n = N_SW; }
    const int lane = threadIdx.x & 63;
    const int w    = threadIdx.x >> 6;
    const int rbase = tile * 64 + w * 16;
    const int rA = rbase + (lane & 15);
    const int ko = (lane >> 4) * 8;

    f16x8 a[4];
#pragma unroll
    for (int ks = 0; ks < 4; ++ks) {
        float4 x0 = make_float4(0.f, 0.f, 0.f, 0.f), x1 = x0;
        if (rA < n) {
            const float* xp = X + ((size_t)rA << 7) + ks * 32 + ko;
            x0 = *(const float4*)xp;
            x1 = *(const float4*)(xp + 4);
        }
        f16x8 v;
        v[0] = (_Float16)x0.x; v[1] = (_Float16)x0.y; v[2] = (_Float16)x0.z; v[3] = (_Float16)x0.w;
        v[4] = (_Float16)x1.x; v[5] = (_Float16)x1.y; v[6] = (_Float16)x1.z; v[7] = (_Float16)x1.w;
        a[ks] = v;
    }
    if (mode == 0) {
        mfma_one_B<true >(Wt_pg,  a, rbase, n, lane, bufT_pg, nullptr);
        mfma_one_B<true >(Wt_ps,  a, rbase, n, lane, bufT_ps, nullptr);
        mfma_one_B<false>(WtR_pf, a, rbase, n, lane, nullptr, R_pf);
    } else if (mode == 1) {
        mfma_one_B<true>(Wt_gp,  a, rbase, n, lane, bufT_gp, nullptr);
        mfma_one_B<true>(WtR_gw, a, rbase, n, lane, R_gw,    nullptr);
    } else {
        mfma_one_B<true>(Wt_sp,  a, rbase, n, lane, bufT_sp, nullptr);
        mfma_one_B<true>(WtR_sw, a, rbase, n, lane, R_sw,    nullptr);
    }
}

// ---------------------------------------------------------------------------
// Merged gather dispatch: GEMM-free, LDS-free, barrier-free.
//  blocks [0, GW+SW): gw/sw node pass — gather-mean + R row + relu + head
//  blocks [GW+SW, +2*SEGP): pfas seg contributions (gp then sp), 1 node/group
// ---------------------------------------------------------------------------
__global__ __launch_bounds__(512, 8) void gather_all_kernel(
    const _Float16* __restrict__ R_gw, const _Float16* __restrict__ R_sw,
    const float* __restrict__ bl_pg, const float* __restrict__ bl_ps,
    const unsigned short* __restrict__ bufT_pg,
    const unsigned short* __restrict__ bufT_ps,
    const unsigned short* __restrict__ bufT_gp,
    const unsigned short* __restrict__ bufT_sp,
    const int* __restrict__ perm, const int* __restrict__ off_all,
    const float* __restrict__ W_gw, const float* __restrict__ b_gw,
    const float* __restrict__ W_sw, const float* __restrict__ b_sw,
    float* __restrict__ o_gw, float* __restrict__ o_sw,
    float* __restrict__ contrib_gp, float* __restrict__ contrib_sp)
{
    const int b = blockIdx.x;
    const int tid = threadIdx.x;
    const int tx = tid & 31;
    const int g = tid >> 5;

    if (b < GW_BLKS + SW_BLKS) {
        int n; const _Float16* R; const float* bl; const unsigned short* bufT16;
        const int* off; const float* wout; const float* bout; float* out; int tile;
        if (b < GW_BLKS) {
            n = N_GW; R = R_gw; bl = bl_pg; bufT16 = bufT_pg; off = off_all + BASE_PG;
            wout = W_gw; bout = b_gw; out = o_gw; tile = b;
        } else {
            n = N_SW; R = R_sw; bl = bl_ps; bufT16 = bufT_ps; off = off_all + BASE_PS;
            wout = W_sw; bout = b_sw; out = o_sw; tile = b - GW_BLKS;
        }
        const int rbase = tile * 64 + g * 4;
        float4 bv = ((const float4*)bl)[tx];
        float4 wo = ((const float4*)wout)[tx];
        float bo = bout[0];
#pragma unroll
        for (int rr = 0; rr < 4; ++rr) {
            int r = rbase + rr;
            int lo = 0, hi = 0;
            if (r < n) { lo = off[r]; hi = off[r + 1]; }
            h2_t tl, th;
            gather_sum_f16(bufT16, perm, lo, hi, tx, tl, th);
            float4 rf = make_float4(0.f, 0.f, 0.f, 0.f);
            if (r < n) {
                uint2 rv = *(const uint2*)((const unsigned short*)R + ((size_t)r << 7) + tx * 4);
                h2_t r01 = u2h2(rv.x), r23 = u2h2(rv.y);
                rf = make_float4((float)r01.x, (float)r01.y, (float)r23.x, (float)r23.y);
            }
            float inv = 1.0f / fmaxf((float)(hi - lo), 1.0f);
            float h0  = fmaxf(rf.x + bv.x + (float)tl.x * inv, 0.f);
            float h1  = fmaxf(rf.y + bv.y + (float)tl.y * inv, 0.f);
            float h2v = fmaxf(rf.z + bv.z + (float)th.x * inv, 0.f);
            float h3  = fmaxf(rf.w + bv.w + (float)th.y * inv, 0.f);
            float pv = h0 * wo.x + h1 * wo.y + h2v * wo.z + h3 * wo.w;
            pv += __shfl_xor(pv, 1, 32);
            pv += __shfl_xor(pv, 2, 32);
            pv += __shfl_xor(pv, 4, 32);
            pv += __shfl_xor(pv, 8, 32);
            pv += __shfl_xor(pv, 16, 32);
            if (tx == 0 && r < n) out[r] = pv + bo;
        }
    } else {
        const int b2 = b - (GW_BLKS + SW_BLKS);
        const unsigned short* bufT; const int* off; float* contrib; int node;
        if (b2 < SEGP_BLKS) {
            bufT = bufT_gp; off = off_all + BASE_GP; contrib = contrib_gp; node = b2 * 16 + g;
        } else {
            bufT = bufT_sp; off = off_all + BASE_SP; contrib = contrib_sp; node = (b2 - SEGP_BLKS) * 16 + g;
        }
        int lo = off[node], hi = off[node + 1];
        h2_t tl, th;
        gather_sum_f16(bufT, perm, lo, hi, tx, tl, th);
        float inv = 1.0f / fmaxf((float)(hi - lo), 1.0f);
        float4 o;
        o.x = (float)tl.x * inv; o.y = (float)tl.y * inv;
        o.z = (float)th.x * inv; o.w = (float)th.y * inv;
        ((float4*)contrib)[(size_t)node * 32 + tx] = o;
    }
}

// ---------------------------------------------------------------------------
// pfas finalize: h_pf = relu(R_pf + contrib_gp + contrib_sp + bl_gp + bl_sp)
// ---------------------------------------------------------------------------
__global__ __launch_bounds__(256) void pf_final_kernel(
    const float* __restrict__ R_pf,
    const float* __restrict__ contrib_gp, const float* __restrict__ contrib_sp,
    const float* __restrict__ blG, const float* __restrict__ blS,
    float* __restrict__ out)
{
    int t = blockIdx.x * 256 + threadIdx.x;   // over N_PFAS*32 float4 lanes
    if (t >= N_PFAS * 32) return;
    int c4 = t & 31;
    float4 b1 = ((const float4*)blG)[c4];
    float4 b2 = ((const float4*)blS)[c4];
    float4 rv = ((const float4*)R_pf)[t];
    float4 cg = ((const float4*)contrib_gp)[t];
    float4 cs = ((const float4*)contrib_sp)[t];
    float4 o;
    o.x = fmaxf(rv.x + cg.x + cs.x + b1.x + b2.x, 0.f);
    o.y = fmaxf(rv.y + cg.y + cs.y + b1.y + b2.y, 0.f);
    o.z = fmaxf(rv.z + cg.z + cs.z + b1.z + b2.z, 0.f);
    o.w = fmaxf(rv.w + cg.w + cs.w + b1.w + b2.w, 0.f);
    ((float4*)out)[t] = o;
}

// ---------------------------------------------------------------------------
// Bucket-level histogram: LDS-privatized per block (665 counters), then one
// global atomicAdd per nonzero bucket per block.
// ---------------------------------------------------------------------------
__global__ __launch_bounds__(1024) void bucket_hist_kernel(
    const int* __restrict__ d_pg, const int* __restrict__ d_ps,
    const int* __restrict__ d_gp, const int* __restrict__ d_sp,
    int* __restrict__ bucketCounts)
{
    __shared__ int hist[NB];
    const int tid = threadIdx.x;
    for (int i = tid; i < NB; i += 1024) hist[i] = 0;
    __syncthreads();
    for (int e = blockIdx.x * 1024 + tid; e < E_TOT; e += H_NBLK * 1024) {
        int idx;
        if (e < E_PG)                    idx = BASE_PG + d_pg[e];
        else if (e < E_PG + E_PS)        idx = BASE_PS + d_ps[e - E_PG];
        else if (e < E_PG + E_PS + E_GP) idx = BASE_GP + d_gp[e - E_PG - E_PS];
        else                             idx = BASE_SP + d_sp[e - E_PG - E_PS - E_GP];
        atomicAdd(&hist[idx >> 8], 1);
    }
    __syncthreads();
    for (int i = tid; i < NB; i += 1024) {
        int c = hist[i];
        if (c) atomicAdd(&bucketCounts[i], c);
    }
}

// ---------------------------------------------------------------------------
// Single-block exclusive scan over the 665 bucket counts. Seeds gcursor with
// bucket start offsets.
// ---------------------------------------------------------------------------
__global__ __launch_bounds__(1024) void bucket_scan_kernel(
    const int* __restrict__ bucketCounts, int* __restrict__ bucketOff,
    int* __restrict__ gcursor, int* __restrict__ off_all)
{
    __shared__ int sp[1024];
    const int t = threadIdx.x;
    int v = (t < NB) ? bucketCounts[t] : 0;
    sp[t] = v;
    __syncthreads();
    for (int ofs = 1; ofs < 1024; ofs <<= 1) {
        int add = (t >= ofs) ? sp[t - ofs] : 0;
        __syncthreads();
        sp[t] += add;
        __syncthreads();
    }
    if (t < NB) {
        int excl = sp[t] - v;
        bucketOff[t] = excl;
        gcursor[t] = excl;
    }
    if (t == 0) { bucketOff[NB] = E_TOT; off_all[NTOT] = E_TOT; }
}

// ---------------------------------------------------------------------------
// Pass 1: bin edges into 256-node buckets. Entry packed: (idx&255) | (src<<8).
// ---------------------------------------------------------------------------
__global__ __launch_bounds__(1024) void bin_kernel(
    const int* __restrict__ s_pg, const int* __restrict__ d_pg,
    const int* __restrict__ s_ps, const int* __restrict__ d_ps,
    const int* __restrict__ s_gp, const int* __restrict__ d_gp,
    const int* __restrict__ s_sp, const int* __restrict__ d_sp,
    int* __restrict__ gcursor, unsigned* __restrict__ pairs)
{
    __shared__ int hist[NB];
    __shared__ int chunkBase[NB];
    const int tid = threadIdx.x;
    for (int i = tid; i < NB; i += 1024) hist[i] = 0;
    __syncthreads();

    const int base = blockIdx.x * BIN_EPB;
    int bkt[BIN_EPT], rnk[BIN_EPT];
    unsigned pk[BIN_EPT];
#pragma unroll
    for (int k = 0; k < BIN_EPT; ++k) {
        int e = base + k * 1024 + tid;
        int idx = -1, src = 0;
        if (e < E_PG) { idx = BASE_PG + d_pg[e]; src = s_pg[e]; }
        else if (e < E_PG + E_PS) { int i2 = e - E_PG; idx = BASE_PS + d_ps[i2]; src = s_ps[i2]; }
        else if (e < E_PG + E_PS + E_GP) { int i2 = e - E_PG - E_PS; idx = BASE_GP + d_gp[i2]; src = s_gp[i2]; }
        else if (e < E_TOT) { int i2 = e - E_PG - E_PS - E_GP; idx = BASE_SP + d_sp[i2]; src = s_sp[i2]; }
        if (idx >= 0) {
            int b = idx >> 8;
            bkt[k] = b;
            rnk[k] = atomicAdd(&hist[b], 1);
            pk[k] = (unsigned)(idx & 255) | ((unsigned)src << 8);
        } else bkt[k] = -1;
    }
    __syncthreads();
    for (int i = tid; i < NB; i += 1024) {
        int c = hist[i];
        chunkBase[i] = c ? atomicAdd(&gcursor[i], c) : 0;
    }
    __syncthreads();
#pragma unroll
    for (int k = 0; k < BIN_EPT; ++k)
        if (bkt[k] >= 0) pairs[chunkBase[bkt[k]] + rnk[k]] = pk[k];
}

// ---------------------------------------------------------------------------
// Pass 2: one block per bucket. Per-node counts recovered from the packed
// pairs with LDS atomics, scanned in LDS to produce off_all for this bucket,
// then scatter into the LDS segment and stream out coalesced.
// ---------------------------------------------------------------------------
__global__ __launch_bounds__(1024) void unbin_kernel(
    const unsigned* __restrict__ pairs, const int* __restrict__ bucketOff,
    int* __restrict__ off_all, int* __restrict__ perm_all)
{
    __shared__ int sPerm[SEG_CAP];
    __shared__ int cnt[256];
    __shared__ int sp[256];
    __shared__ int cur[256];
    const int b = blockIdx.x;
    const int nb0 = b << 8;
    const int nb1 = min(nb0 + 256, NTOT);
    const int tid = threadIdx.x;
    const int base = bucketOff[b];
    const int end  = bucketOff[b + 1];
    const int len = end - base;

    if (tid < 256) cnt[tid] = 0;
    __syncthreads();
    for (int i = base + tid; i < end; i += 1024)
        atomicAdd(&cnt[pairs[i] & 255u], 1);
    __syncthreads();
    int v = (tid < 256) ? cnt[tid] : 0;
    if (tid < 256) sp[tid] = v;
    __syncthreads();
    for (int ofs = 1; ofs < 256; ofs <<= 1) {
        int add = (tid < 256 && tid >= ofs) ? sp[tid - ofs] : 0;
        __syncthreads();
        if (tid < 256) sp[tid] += add;
        __syncthreads();
    }
    if (tid < 256) {
        int excl = sp[tid] - v;
        cur[tid] = excl;
        if (nb0 + tid < nb1) off_all[nb0 + tid] = base + excl;
    }
    __syncthreads();

    if (len <= SEG_CAP) {
        for (int i = base + tid; i < end; i += 1024) {
            unsigned p = pairs[i];
            int pos = atomicAdd(&cur[p & 255u], 1);
            sPerm[pos] = (int)(p >> 8);
        }
        __syncthreads();
        for (int i = tid; i < len; i += 1024)
            perm_all[base + i] = sPerm[i];
    } else {
        for (int i = base + tid; i < end; i += 1024) {
            unsigned p = pairs[i];
            int pos = atomicAdd(&cur[p & 255u], 1);
            perm_all[base + pos] = (int)(p >> 8);
        }
    }
}

// ---------------------------------------------------------------------------
// Launch
// ---------------------------------------------------------------------------
extern "C" void kernel_launch(void* const* d_in, const int* in_sizes, int n_in,
                              void* d_out, int out_size, void* d_ws, size_t ws_size,
                              hipStream_t stream)
{
    const float* x_pfas = (const float*)d_in[0];
    const float* x_gw   = (const float*)d_in[1];
    const float* x_sw   = (const float*)d_in[2];
    const int* ei_pg_src = (const int*)d_in[3];
    const int* ei_pg_dst = (const int*)d_in[4];
    const int* ei_gp_src = (const int*)d_in[5];
    const int* ei_gp_dst = (const int*)d_in[6];
    const int* ei_ps_src = (const int*)d_in[7];
    const int* ei_ps_dst = (const int*)d_in[8];
    const int* ei_sp_src = (const int*)d_in[9];
    const int* ei_sp_dst = (const int*)d_in[10];
    const float* Wl_pg = (const float*)d_in[11];
    const float* bl_pg = (const float*)d_in[12];
    const float* Wr_pg = (const float*)d_in[13];
    const float* Wl_gp = (const float*)d_in[14];
    const float* bl_gp = (const float*)d_in[15];
    const float* Wr_gp = (const float*)d_in[16];
    const float* Wl_ps = (const float*)d_in[17];
    const float* bl_ps = (const float*)d_in[18];
    const float* Wr_ps = (const float*)d_in[19];
    const float* Wl_sp = (const float*)d_in[20];
    const float* bl_sp = (const float*)d_in[21];
    const float* Wr_sp = (const float*)d_in[22];
    const float* W_gw = (const float*)d_in[23];
    const float* b_gw = (const float*)d_in[24];
    const float* W_sw = (const float*)d_in[25];
    const float* b_sw = (const float*)d_in[26];

    float* out  = (float*)d_out;
    float* h_pf = out;                         // 20000*128
    float* o_gw = out + (size_t)N_PFAS * 128;  // 100000
    float* o_sw = o_gw + N_GW;                 // 30000

    // ---- workspace layout (~130 MB) ----
    char* p = (char*)d_ws;
    auto alloc = [&](size_t bytes) { char* q = p; p += (bytes + 15) & ~(size_t)15; return q; };
    unsigned short* bufT_pg = (unsigned short*)alloc((size_t)N_PFAS * 128 * 2);
    unsigned short* bufT_ps = (unsigned short*)alloc((size_t)N_PFAS * 128 * 2);
    unsigned short* bufT_gp = (unsigned short*)alloc((size_t)N_GW * 128 * 2);
    unsigned short* bufT_sp = (unsigned short*)alloc((size_t)N_SW * 128 * 2);
    _Float16* R_gw = (_Float16*)alloc((size_t)N_GW * 128 * 2);
    _Float16* R_sw = (_Float16*)alloc((size_t)N_SW * 128 * 2);
    float* R_pf = (float*)alloc((size_t)N_PFAS * 128 * 4);
    float* contrib_gp = (float*)alloc((size_t)N_PFAS * 128 * 4);
    float* contrib_sp = (float*)alloc((size_t)N_PFAS * 128 * 4);
    int* perm_all   = (int*)alloc((size_t)E_TOT * 4);
    unsigned* pairs = (unsigned*)alloc((size_t)E_TOT * 4);
    int* off_all    = (int*)alloc((size_t)(NTOT + 1) * 4);
    int* bucketCounts = (int*)alloc((size_t)NB * 4);
    int* bucketOff    = (int*)alloc((size_t)(NB + 1) * 4);
    int* gcursor    = (int*)alloc((size_t)NB * 4);
    _Float16* Wt_pg  = (_Float16*)alloc(16384 * 2);
    _Float16* Wt_ps  = (_Float16*)alloc(16384 * 2);
    _Float16* WtR_pf = (_Float16*)alloc(16384 * 2);
    _Float16* Wt_gp  = (_Float16*)alloc(16384 * 2);
    _Float16* WtR_gw = (_Float16*)alloc(16384 * 2);
    _Float16* Wt_sp  = (_Float16*)alloc(16384 * 2);
    _Float16* WtR_sw = (_Float16*)alloc(16384 * 2);

    // ---- 1. weight transposes + unified MFMA transforms ----
    prep_wt_kernel<<<7, 256, 0, stream>>>(
        Wl_pg, Wl_ps, Wr_gp, Wr_sp, Wl_gp, Wr_pg, Wl_sp, Wr_ps,
        Wt_pg, Wt_ps, WtR_pf, Wt_gp, WtR_gw, Wt_sp, WtR_sw);
    mfma_trans_kernel<<<T64_ALL, 256, 0, stream>>>(
        x_pfas, x_gw, x_sw,
        Wt_pg, Wt_ps, WtR_pf, Wt_gp, WtR_gw, Wt_sp, WtR_sw,
        (_Float16*)bufT_pg, (_Float16*)bufT_ps, R_pf,
        (_Float16*)bufT_gp, R_gw, (_Float16*)bufT_sp, R_sw);

    // ---- 2. CSR build: bucket hist -> bucket scan -> bucketed permute ----
    hipMemsetAsync(bucketCounts, 0, (size_t)NB * 4, stream);
    bucket_hist_kernel<<<H_NBLK, 1024, 0, stream>>>(
        ei_pg_dst, ei_ps_dst, ei_gp_dst, ei_sp_dst, bucketCounts);
    bucket_scan_kernel<<<1, 1024, 0, stream>>>(
        bucketCounts, bucketOff, gcursor, off_all);
    bin_kernel<<<BIN_NBLK, 1024, 0, stream>>>(
        ei_pg_src, ei_pg_dst, ei_ps_src, ei_ps_dst,
        ei_gp_src, ei_gp_dst, ei_sp_src, ei_sp_dst, gcursor, pairs);
    unbin_kernel<<<NB, 1024, 0, stream>>>(pairs, bucketOff, off_all, perm_all);

    // ---- 3. merged gather dispatch: gw/sw node passes + pfas seg contribs ----
    gather_all_kernel<<<GW_BLKS + SW_BLKS + 2 * SEGP_BLKS, 512, 0, stream>>>(
        R_gw, R_sw, bl_pg, bl_ps, bufT_pg, bufT_ps, bufT_gp, bufT_sp,
        perm_all, off_all, W_gw, b_gw, W_sw, b_sw, o_gw, o_sw,
        contrib_gp, contrib_sp);

    // ---- 4. pfas finalize ----
    pf_final_kernel<<<(N_PFAS * 32 + 255) / 256, 256, 0, stream>>>(
        R_pf, contrib_gp, contrib_sp, bl_gp, bl_sp, h_pf);
}

// Round 5
// 383.590 us; speedup vs baseline: 1.6496x; 1.1730x over previous
//
#include <hip/hip_runtime.h>

// ---------------------------------------------------------------------------
// Problem constants
// ---------------------------------------------------------------------------
#define N_PFAS 20000
#define N_GW   100000
#define N_SW   30000
#define E_PG   1600000
#define E_GP   640000
#define E_PS   480000
#define E_SP   320000
#define E_TOT  (E_PG + E_PS + E_GP + E_SP)
// Concatenated node-count layout: [pg: N_GW][ps: N_SW][gp: N_PFAS][sp: N_PFAS]
#define BASE_PG 0
#define BASE_PS (N_GW)
#define BASE_GP (N_GW + N_SW)
#define BASE_SP (N_GW + N_SW + N_PFAS)
#define NTOT    (N_GW + N_SW + 2 * N_PFAS)
// Bucketed permute: 256 nodes per bucket.
#define NB        ((NTOT + 255) / 256)       // 665
#define BIN_EPT   12
#define BIN_EPB   (1024 * BIN_EPT)
#define BIN_NBLK  ((E_TOT + BIN_EPB - 1) / BIN_EPB)
#define SEG_CAP   15360
#define H_NBLK    128                        // bucket-hist grid
// MFMA transform tiles (64 rows each)
#define T64_PF ((N_PFAS + 63) / 64)          // 313
#define T64_GW ((N_GW + 63) / 64)            // 1563
#define T64_SW ((N_SW + 63) / 64)            // 469
#define T64_ALL (T64_PF + T64_GW + T64_SW)
// Merged gather dispatch
#define GW_BLKS   ((N_GW + 63) / 64)         // 1563  (64 nodes/block)
#define SW_BLKS   ((N_SW + 63) / 64)         // 469
#define SEGP_BLKS (N_PFAS / 16)              // 1250  (16 nodes/block, exact)

// ---------------------------------------------------------------------------
// f16 helpers: transformed rows stored f16; aggregation via v_pk_add_f16.
// ---------------------------------------------------------------------------
typedef _Float16 h2_t  __attribute__((ext_vector_type(2)));
typedef _Float16 f16x8 __attribute__((ext_vector_type(8)));
typedef float    f32x4 __attribute__((ext_vector_type(4)));
union HU { unsigned u; h2_t h; };
__device__ __forceinline__ h2_t u2h2(unsigned u) { HU x; x.u = u; return x.h; }

// ---------------------------------------------------------------------------
// 8-ILP f16 gather-sum over a CSR segment: tl = sum of channels (4tx,4tx+1),
// th = (4tx+2, 4tx+3).
// ---------------------------------------------------------------------------
__device__ __forceinline__ void gather_sum_f16(
    const unsigned short* __restrict__ bufT16, const int* __restrict__ perm,
    int lo, int hi, int tx, h2_t& tl, h2_t& th)
{
    h2_t hz; hz.x = (_Float16)0.f; hz.y = (_Float16)0.f;
    h2_t a0 = hz, a1 = hz, a2 = hz, a3 = hz, a4 = hz, a5 = hz, a6 = hz, a7 = hz;
    int i = lo;
    for (; i + 8 <= hi; i += 8) {
        uint2 v0 = *(const uint2*)(bufT16 + (size_t)perm[i + 0] * 128 + tx * 4);
        uint2 v1 = *(const uint2*)(bufT16 + (size_t)perm[i + 1] * 128 + tx * 4);
        uint2 v2 = *(const uint2*)(bufT16 + (size_t)perm[i + 2] * 128 + tx * 4);
        uint2 v3 = *(const uint2*)(bufT16 + (size_t)perm[i + 3] * 128 + tx * 4);
        uint2 v4 = *(const uint2*)(bufT16 + (size_t)perm[i + 4] * 128 + tx * 4);
        uint2 v5 = *(const uint2*)(bufT16 + (size_t)perm[i + 5] * 128 + tx * 4);
        uint2 v6 = *(const uint2*)(bufT16 + (size_t)perm[i + 6] * 128 + tx * 4);
        uint2 v7 = *(const uint2*)(bufT16 + (size_t)perm[i + 7] * 128 + tx * 4);
        a0 += u2h2(v0.x); a1 += u2h2(v0.y);
        a2 += u2h2(v1.x); a3 += u2h2(v1.y);
        a4 += u2h2(v2.x); a5 += u2h2(v2.y);
        a6 += u2h2(v3.x); a7 += u2h2(v3.y);
        a0 += u2h2(v4.x); a1 += u2h2(v4.y);
        a2 += u2h2(v5.x); a3 += u2h2(v5.y);
        a4 += u2h2(v6.x); a5 += u2h2(v6.y);
        a6 += u2h2(v7.x); a7 += u2h2(v7.y);
    }
    for (; i + 2 <= hi; i += 2) {
        uint2 v0 = *(const uint2*)(bufT16 + (size_t)perm[i + 0] * 128 + tx * 4);
        uint2 v1 = *(const uint2*)(bufT16 + (size_t)perm[i + 1] * 128 + tx * 4);
        a0 += u2h2(v0.x); a1 += u2h2(v0.y);
        a2 += u2h2(v1.x); a3 += u2h2(v1.y);
    }
    if (i < hi) {
        uint2 v0 = *(const uint2*)(bufT16 + (size_t)perm[i] * 128 + tx * 4);
        a0 += u2h2(v0.x); a1 += u2h2(v0.y);
    }
    tl = (a0 + a2) + (a4 + a6);
    th = (a1 + a3) + (a5 + a7);
}

// ---------------------------------------------------------------------------
// Weight prep: write each W (f32 [k][n]) as FRAGMENT-LINEAR f16 WtF:
//   WtF[((ct*4+ks)*64 + lane)*8 + j] = W[ks*32 + (lane>>4)*8 + j][ct*16 + (lane&15)]
// so the MFMA kernel's B-frag load is one contiguous 1KB block per (ct,ks)
// (coalesced; kills the 16-line address divergence that made round-4 slow).
// m==2 sums Wr_gp+Wr_sp (pfas HeteroConv fusion).
// ---------------------------------------------------------------------------
__global__ __launch_bounds__(256) void prep_wt_kernel(
    const float* __restrict__ Wl_pg, const float* __restrict__ Wl_ps,
    const float* __restrict__ Wr_gp, const float* __restrict__ Wr_sp,
    const float* __restrict__ Wl_gp, const float* __restrict__ Wr_pg,
    const float* __restrict__ Wl_sp, const float* __restrict__ Wr_ps,
    _Float16* __restrict__ WtF_pg, _Float16* __restrict__ WtF_ps,
    _Float16* __restrict__ WtFR_pf,
    _Float16* __restrict__ WtF_gp, _Float16* __restrict__ WtFR_gw,
    _Float16* __restrict__ WtF_sp, _Float16* __restrict__ WtFR_sw)
{
    const int m = blockIdx.x;
    const float* A = nullptr; const float* B = nullptr; _Float16* O = nullptr;
    switch (m) {
        case 0: A = Wl_pg; O = WtF_pg;  break;
        case 1: A = Wl_ps; O = WtF_ps;  break;
        case 2: A = Wr_gp; B = Wr_sp; O = WtFR_pf; break;
        case 3: A = Wl_gp; O = WtF_gp;  break;
        case 4: A = Wr_pg; O = WtFR_gw; break;
        case 5: A = Wl_sp; O = WtF_sp;  break;
        default: A = Wr_ps; O = WtFR_sw; break;
    }
    for (int t = threadIdx.x; t < 2048; t += 256) {
        int lane = t & 63, g = t >> 6;      // g = ct*4+ks
        int ks = g & 3, ct = g >> 2;
        int nn = ct * 16 + (lane & 15);
        int k0 = ks * 32 + (lane >> 4) * 8;
        f16x8 v;
#pragma unroll
        for (int j = 0; j < 8; ++j) {
            float x = A[(k0 + j) * 128 + nn];
            if (B) x += B[(k0 + j) * 128 + nn];
            v[j] = (_Float16)x;
        }
        *(f16x8*)(O + (size_t)t * 8) = v;
    }
}

// ---------------------------------------------------------------------------
// One B-matrix MFMA pass: OUT[64 rows x 128] = X_tile @ W using
// mfma_f32_16x16x32_f16. All 32 B-frags preloaded (coalesced, from WtF) to
// overlap their latency; then 32 MFMAs; then standard row-major stores.
// C layout (verified): col = lane&15, row = (lane>>4)*4 + reg.
// ---------------------------------------------------------------------------
template<bool F16OUT>
__device__ __forceinline__ void mfma_one_B(
    const _Float16* __restrict__ WtF, const f16x8* a,
    int rbase, int n, int lane,
    _Float16* __restrict__ o16, float* __restrict__ o32)
{
    f16x8 bf[8][4];
#pragma unroll
    for (int ct = 0; ct < 8; ++ct)
#pragma unroll
        for (int ks = 0; ks < 4; ++ks)
            bf[ct][ks] = *(const f16x8*)(WtF + (size_t)((ct * 4 + ks) * 64 + lane) * 8);

    f32x4 acc[8];
#pragma unroll
    for (int ct = 0; ct < 8; ++ct) acc[ct] = (f32x4){0.f, 0.f, 0.f, 0.f};
#pragma unroll
    for (int ct = 0; ct < 8; ++ct)
#pragma unroll
        for (int ks = 0; ks < 4; ++ks)
            acc[ct] = __builtin_amdgcn_mfma_f32_16x16x32_f16(a[ks], bf[ct][ks], acc[ct], 0, 0, 0);

    const int rowb = rbase + (lane >> 4) * 4;
    const int bcol = lane & 15;
#pragma unroll
    for (int ct = 0; ct < 8; ++ct) {
        const int col = ct * 16 + bcol;
#pragma unroll
        for (int e = 0; e < 4; ++e) {
            int r = rowb + e;
            if (r < n) {
                if (F16OUT) o16[((size_t)r << 7) + col] = (_Float16)acc[ct][e];
                else        o32[((size_t)r << 7) + col] = acc[ct][e];
            }
        }
    }
}

// ---------------------------------------------------------------------------
// Unified MFMA transform: per 64-row X tile, load A-frags once (f32->f16 in
// regs, no LDS) and emit every needed product:
//   pfas: X@Wl_pg (f16), X@Wl_ps (f16), X@(Wr_gp+Wr_sp) (f32 R_pf)
//   gw:   X@Wl_gp (f16), X@Wr_pg (f16 R_gw)
//   sw:   X@Wl_sp (f16), X@Wr_ps (f16 R_sw)
// launch_bounds(256,2): lift VGPR cap so the 32 preloaded B-frags stay in regs.
// ---------------------------------------------------------------------------
__global__ __launch_bounds__(256, 2) void mfma_trans_kernel(
    const float* __restrict__ x_pfas, const float* __restrict__ x_gw,
    const float* __restrict__ x_sw,
    const _Float16* __restrict__ WtF_pg, const _Float16* __restrict__ WtF_ps,
    const _Float16* __restrict__ WtFR_pf,
    const _Float16* __restrict__ WtF_gp, const _Float16* __restrict__ WtFR_gw,
    const _Float16* __restrict__ WtF_sp, const _Float16* __restrict__ WtFR_sw,
    _Float16* __restrict__ bufT_pg, _Float16* __restrict__ bufT_ps,
    float* __restrict__ R_pf,
    _Float16* __restrict__ bufT_gp, _Float16* __restrict__ R_gw,
    _Float16* __restrict__ bufT_sp, _Float16* __restrict__ R_sw)
{
    const int b = blockIdx.x;
    int mode, tile, n; const float* X;
    if (b < T64_PF)               { mode = 0; tile = b;                    X = x_pfas; n = N_PFAS; }
    else if (b < T64_PF + T64_GW) { mode = 1; tile = b - T64_PF;           X = x_gw;   n = N_GW; }
    else                          { mode = 2; tile = b - T64_PF - T64_GW;  X = x_sw;   n = N_SW; }
    const int lane = threadIdx.x & 63;
    const int w    = threadIdx.x >> 6;
    const int rbase = tile * 64 + w * 16;
    const int rA = rbase + (lane & 15);
    const int ko = (lane >> 4) * 8;

    f16x8 a[4];
#pragma unroll
    for (int ks = 0; ks < 4; ++ks) {
        float4 x0 = make_float4(0.f, 0.f, 0.f, 0.f), x1 = x0;
        if (rA < n) {
            const float* xp = X + ((size_t)rA << 7) + ks * 32 + ko;
            x0 = *(const float4*)xp;
            x1 = *(const float4*)(xp + 4);
        }
        f16x8 v;
        v[0] = (_Float16)x0.x; v[1] = (_Float16)x0.y; v[2] = (_Float16)x0.z; v[3] = (_Float16)x0.w;
        v[4] = (_Float16)x1.x; v[5] = (_Float16)x1.y; v[6] = (_Float16)x1.z; v[7] = (_Float16)x1.w;
        a[ks] = v;
    }
    if (mode == 0) {
        mfma_one_B<true >(WtF_pg,  a, rbase, n, lane, bufT_pg, nullptr);
        mfma_one_B<true >(WtF_ps,  a, rbase, n, lane, bufT_ps, nullptr);
        mfma_one_B<false>(WtFR_pf, a, rbase, n, lane, nullptr, R_pf);
    } else if (mode == 1) {
        mfma_one_B<true>(WtF_gp,  a, rbase, n, lane, bufT_gp, nullptr);
        mfma_one_B<true>(WtFR_gw, a, rbase, n, lane, R_gw,    nullptr);
    } else {
        mfma_one_B<true>(WtF_sp,  a, rbase, n, lane, bufT_sp, nullptr);
        mfma_one_B<true>(WtFR_sw, a, rbase, n, lane, R_sw,    nullptr);
    }
}

// ---------------------------------------------------------------------------
// Merged gather dispatch: GEMM-free, LDS-free, barrier-free.
//  blocks [0, GW+SW): gw/sw node pass — gather-mean + R row + relu + head
//  blocks [GW+SW, +2*SEGP): pfas seg contributions (gp then sp), 1 node/group
// ---------------------------------------------------------------------------
__global__ __launch_bounds__(512, 8) void gather_all_kernel(
    const _Float16* __restrict__ R_gw, const _Float16* __restrict__ R_sw,
    const float* __restrict__ bl_pg, const float* __restrict__ bl_ps,
    const unsigned short* __restrict__ bufT_pg,
    const unsigned short* __restrict__ bufT_ps,
    const unsigned short* __restrict__ bufT_gp,
    const unsigned short* __restrict__ bufT_sp,
    const int* __restrict__ perm, const int* __restrict__ off_all,
    const float* __restrict__ W_gw, const float* __restrict__ b_gw,
    const float* __restrict__ W_sw, const float* __restrict__ b_sw,
    float* __restrict__ o_gw, float* __restrict__ o_sw,
    float* __restrict__ contrib_gp, float* __restrict__ contrib_sp)
{
    const int b = blockIdx.x;
    const int tid = threadIdx.x;
    const int tx = tid & 31;
    const int g = tid >> 5;

    if (b < GW_BLKS + SW_BLKS) {
        int n; const _Float16* R; const float* bl; const unsigned short* bufT16;
        const int* off; const float* wout; const float* bout; float* out; int tile;
        if (b < GW_BLKS) {
            n = N_GW; R = R_gw; bl = bl_pg; bufT16 = bufT_pg; off = off_all + BASE_PG;
            wout = W_gw; bout = b_gw; out = o_gw; tile = b;
        } else {
            n = N_SW; R = R_sw; bl = bl_ps; bufT16 = bufT_ps; off = off_all + BASE_PS;
            wout = W_sw; bout = b_sw; out = o_sw; tile = b - GW_BLKS;
        }
        const int rbase = tile * 64 + g * 4;
        float4 bv = ((const float4*)bl)[tx];
        float4 wo = ((const float4*)wout)[tx];
        float bo = bout[0];
#pragma unroll
        for (int rr = 0; rr < 4; ++rr) {
            int r = rbase + rr;
            int lo = 0, hi = 0;
            if (r < n) { lo = off[r]; hi = off[r + 1]; }
            h2_t tl, th;
            gather_sum_f16(bufT16, perm, lo, hi, tx, tl, th);
            float4 rf = make_float4(0.f, 0.f, 0.f, 0.f);
            if (r < n) {
                uint2 rv = *(const uint2*)((const unsigned short*)R + ((size_t)r << 7) + tx * 4);
                h2_t r01 = u2h2(rv.x), r23 = u2h2(rv.y);
                rf = make_float4((float)r01.x, (float)r01.y, (float)r23.x, (float)r23.y);
            }
            float inv = 1.0f / fmaxf((float)(hi - lo), 1.0f);
            float h0  = fmaxf(rf.x + bv.x + (float)tl.x * inv, 0.f);
            float h1  = fmaxf(rf.y + bv.y + (float)tl.y * inv, 0.f);
            float h2v = fmaxf(rf.z + bv.z + (float)th.x * inv, 0.f);
            float h3  = fmaxf(rf.w + bv.w + (float)th.y * inv, 0.f);
            float pv = h0 * wo.x + h1 * wo.y + h2v * wo.z + h3 * wo.w;
            pv += __shfl_xor(pv, 1, 32);
            pv += __shfl_xor(pv, 2, 32);
            pv += __shfl_xor(pv, 4, 32);
            pv += __shfl_xor(pv, 8, 32);
            pv += __shfl_xor(pv, 16, 32);
            if (tx == 0 && r < n) out[r] = pv + bo;
        }
    } else {
        const int b2 = b - (GW_BLKS + SW_BLKS);
        const unsigned short* bufT; const int* off; float* contrib; int node;
        if (b2 < SEGP_BLKS) {
            bufT = bufT_gp; off = off_all + BASE_GP; contrib = contrib_gp; node = b2 * 16 + g;
        } else {
            bufT = bufT_sp; off = off_all + BASE_SP; contrib = contrib_sp; node = (b2 - SEGP_BLKS) * 16 + g;
        }
        int lo = off[node], hi = off[node + 1];
        h2_t tl, th;
        gather_sum_f16(bufT, perm, lo, hi, tx, tl, th);
        float inv = 1.0f / fmaxf((float)(hi - lo), 1.0f);
        float4 o;
        o.x = (float)tl.x * inv; o.y = (float)tl.y * inv;
        o.z = (float)th.x * inv; o.w = (float)th.y * inv;
        ((float4*)contrib)[(size_t)node * 32 + tx] = o;
    }
}

// ---------------------------------------------------------------------------
// pfas finalize: h_pf = relu(R_pf + contrib_gp + contrib_sp + bl_gp + bl_sp)
// ---------------------------------------------------------------------------
__global__ __launch_bounds__(256) void pf_final_kernel(
    const float* __restrict__ R_pf,
    const float* __restrict__ contrib_gp, const float* __restrict__ contrib_sp,
    const float* __restrict__ blG, const float* __restrict__ blS,
    float* __restrict__ out)
{
    int t = blockIdx.x * 256 + threadIdx.x;   // over N_PFAS*32 float4 lanes
    if (t >= N_PFAS * 32) return;
    int c4 = t & 31;
    float4 b1 = ((const float4*)blG)[c4];
    float4 b2 = ((const float4*)blS)[c4];
    float4 rv = ((const float4*)R_pf)[t];
    float4 cg = ((const float4*)contrib_gp)[t];
    float4 cs = ((const float4*)contrib_sp)[t];
    float4 o;
    o.x = fmaxf(rv.x + cg.x + cs.x + b1.x + b2.x, 0.f);
    o.y = fmaxf(rv.y + cg.y + cs.y + b1.y + b2.y, 0.f);
    o.z = fmaxf(rv.z + cg.z + cs.z + b1.z + b2.z, 0.f);
    o.w = fmaxf(rv.w + cg.w + cs.w + b1.w + b2.w, 0.f);
    ((float4*)out)[t] = o;
}

// ---------------------------------------------------------------------------
// Bucket-level histogram: LDS-privatized per block (665 counters), then one
// global atomicAdd per nonzero bucket per block.
// ---------------------------------------------------------------------------
__global__ __launch_bounds__(1024) void bucket_hist_kernel(
    const int* __restrict__ d_pg, const int* __restrict__ d_ps,
    const int* __restrict__ d_gp, const int* __restrict__ d_sp,
    int* __restrict__ bucketCounts)
{
    __shared__ int hist[NB];
    const int tid = threadIdx.x;
    for (int i = tid; i < NB; i += 1024) hist[i] = 0;
    __syncthreads();
    for (int e = blockIdx.x * 1024 + tid; e < E_TOT; e += H_NBLK * 1024) {
        int idx;
        if (e < E_PG)                    idx = BASE_PG + d_pg[e];
        else if (e < E_PG + E_PS)        idx = BASE_PS + d_ps[e - E_PG];
        else if (e < E_PG + E_PS + E_GP) idx = BASE_GP + d_gp[e - E_PG - E_PS];
        else                             idx = BASE_SP + d_sp[e - E_PG - E_PS - E_GP];
        atomicAdd(&hist[idx >> 8], 1);
    }
    __syncthreads();
    for (int i = tid; i < NB; i += 1024) {
        int c = hist[i];
        if (c) atomicAdd(&bucketCounts[i], c);
    }
}

// ---------------------------------------------------------------------------
// Single-block exclusive scan over the 665 bucket counts. Seeds gcursor with
// bucket start offsets.
// ---------------------------------------------------------------------------
__global__ __launch_bounds__(1024) void bucket_scan_kernel(
    const int* __restrict__ bucketCounts, int* __restrict__ bucketOff,
    int* __restrict__ gcursor, int* __restrict__ off_all)
{
    __shared__ int sp[1024];
    const int t = threadIdx.x;
    int v = (t < NB) ? bucketCounts[t] : 0;
    sp[t] = v;
    __syncthreads();
    for (int ofs = 1; ofs < 1024; ofs <<= 1) {
        int add = (t >= ofs) ? sp[t - ofs] : 0;
        __syncthreads();
        sp[t] += add;
        __syncthreads();
    }
    if (t < NB) {
        int excl = sp[t] - v;
        bucketOff[t] = excl;
        gcursor[t] = excl;
    }
    if (t == 0) { bucketOff[NB] = E_TOT; off_all[NTOT] = E_TOT; }
}

// ---------------------------------------------------------------------------
// Pass 1: bin edges into 256-node buckets. Entry packed: (idx&255) | (src<<8).
// ---------------------------------------------------------------------------
__global__ __launch_bounds__(1024) void bin_kernel(
    const int* __restrict__ s_pg, const int* __restrict__ d_pg,
    const int* __restrict__ s_ps, const int* __restrict__ d_ps,
    const int* __restrict__ s_gp, const int* __restrict__ d_gp,
    const int* __restrict__ s_sp, const int* __restrict__ d_sp,
    int* __restrict__ gcursor, unsigned* __restrict__ pairs)
{
    __shared__ int hist[NB];
    __shared__ int chunkBase[NB];
    const int tid = threadIdx.x;
    for (int i = tid; i < NB; i += 1024) hist[i] = 0;
    __syncthreads();

    const int base = blockIdx.x * BIN_EPB;
    int bkt[BIN_EPT], rnk[BIN_EPT];
    unsigned pk[BIN_EPT];
#pragma unroll
    for (int k = 0; k < BIN_EPT; ++k) {
        int e = base + k * 1024 + tid;
        int idx = -1, src = 0;
        if (e < E_PG) { idx = BASE_PG + d_pg[e]; src = s_pg[e]; }
        else if (e < E_PG + E_PS) { int i2 = e - E_PG; idx = BASE_PS + d_ps[i2]; src = s_ps[i2]; }
        else if (e < E_PG + E_PS + E_GP) { int i2 = e - E_PG - E_PS; idx = BASE_GP + d_gp[i2]; src = s_gp[i2]; }
        else if (e < E_TOT) { int i2 = e - E_PG - E_PS - E_GP; idx = BASE_SP + d_sp[i2]; src = s_sp[i2]; }
        if (idx >= 0) {
            int b = idx >> 8;
            bkt[k] = b;
            rnk[k] = atomicAdd(&hist[b], 1);
            pk[k] = (unsigned)(idx & 255) | ((unsigned)src << 8);
        } else bkt[k] = -1;
    }
    __syncthreads();
    for (int i = tid; i < NB; i += 1024) {
        int c = hist[i];
        chunkBase[i] = c ? atomicAdd(&gcursor[i], c) : 0;
    }
    __syncthreads();
#pragma unroll
    for (int k = 0; k < BIN_EPT; ++k)
        if (bkt[k] >= 0) pairs[chunkBase[bkt[k]] + rnk[k]] = pk[k];
}

// ---------------------------------------------------------------------------
// Pass 2: one block per bucket. Per-node counts recovered from the packed
// pairs with LDS atomics, scanned in LDS to produce off_all for this bucket,
// then scatter into the LDS segment and stream out coalesced.
// ---------------------------------------------------------------------------
__global__ __launch_bounds__(1024) void unbin_kernel(
    const unsigned* __restrict__ pairs, const int* __restrict__ bucketOff,
    int* __restrict__ off_all, int* __restrict__ perm_all)
{
    __shared__ int sPerm[SEG_CAP];
    __shared__ int cnt[256];
    __shared__ int sp[256];
    __shared__ int cur[256];
    const int b = blockIdx.x;
    const int nb0 = b << 8;
    const int nb1 = min(nb0 + 256, NTOT);
    const int tid = threadIdx.x;
    const int base = bucketOff[b];
    const int end  = bucketOff[b + 1];
    const int len = end - base;

    if (tid < 256) cnt[tid] = 0;
    __syncthreads();
    for (int i = base + tid; i < end; i += 1024)
        atomicAdd(&cnt[pairs[i] & 255u], 1);
    __syncthreads();
    int v = (tid < 256) ? cnt[tid] : 0;
    if (tid < 256) sp[tid] = v;
    __syncthreads();
    for (int ofs = 1; ofs < 256; ofs <<= 1) {
        int add = (tid < 256 && tid >= ofs) ? sp[tid - ofs] : 0;
        __syncthreads();
        if (tid < 256) sp[tid] += add;
        __syncthreads();
    }
    if (tid < 256) {
        int excl = sp[tid] - v;
        cur[tid] = excl;
        if (nb0 + tid < nb1) off_all[nb0 + tid] = base + excl;
    }
    __syncthreads();

    if (len <= SEG_CAP) {
        for (int i = base + tid; i < end; i += 1024) {
            unsigned p = pairs[i];
            int pos = atomicAdd(&cur[p & 255u], 1);
            sPerm[pos] = (int)(p >> 8);
        }
        __syncthreads();
        for (int i = tid; i < len; i += 1024)
            perm_all[base + i] = sPerm[i];
    } else {
        for (int i = base + tid; i < end; i += 1024) {
            unsigned p = pairs[i];
            int pos = atomicAdd(&cur[p & 255u], 1);
            perm_all[base + pos] = (int)(p >> 8);
        }
    }
}

// ---------------------------------------------------------------------------
// Launch
// ---------------------------------------------------------------------------
extern "C" void kernel_launch(void* const* d_in, const int* in_sizes, int n_in,
                              void* d_out, int out_size, void* d_ws, size_t ws_size,
                              hipStream_t stream)
{
    const float* x_pfas = (const float*)d_in[0];
    const float* x_gw   = (const float*)d_in[1];
    const float* x_sw   = (const float*)d_in[2];
    const int* ei_pg_src = (const int*)d_in[3];
    const int* ei_pg_dst = (const int*)d_in[4];
    const int* ei_gp_src = (const int*)d_in[5];
    const int* ei_gp_dst = (const int*)d_in[6];
    const int* ei_ps_src = (const int*)d_in[7];
    const int* ei_ps_dst = (const int*)d_in[8];
    const int* ei_sp_src = (const int*)d_in[9];
    const int* ei_sp_dst = (const int*)d_in[10];
    const float* Wl_pg = (const float*)d_in[11];
    const float* bl_pg = (const float*)d_in[12];
    const float* Wr_pg = (const float*)d_in[13];
    const float* Wl_gp = (const float*)d_in[14];
    const float* bl_gp = (const float*)d_in[15];
    const float* Wr_gp = (const float*)d_in[16];
    const float* Wl_ps = (const float*)d_in[17];
    const float* bl_ps = (const float*)d_in[18];
    const float* Wr_ps = (const float*)d_in[19];
    const float* Wl_sp = (const float*)d_in[20];
    const float* bl_sp = (const float*)d_in[21];
    const float* Wr_sp = (const float*)d_in[22];
    const float* W_gw = (const float*)d_in[23];
    const float* b_gw = (const float*)d_in[24];
    const float* W_sw = (const float*)d_in[25];
    const float* b_sw = (const float*)d_in[26];

    float* out  = (float*)d_out;
    float* h_pf = out;                         // 20000*128
    float* o_gw = out + (size_t)N_PFAS * 128;  // 100000
    float* o_sw = o_gw + N_GW;                 // 30000

    // ---- workspace layout (~130 MB) ----
    char* p = (char*)d_ws;
    auto alloc = [&](size_t bytes) { char* q = p; p += (bytes + 15) & ~(size_t)15; return q; };
    unsigned short* bufT_pg = (unsigned short*)alloc((size_t)N_PFAS * 128 * 2);
    unsigned short* bufT_ps = (unsigned short*)alloc((size_t)N_PFAS * 128 * 2);
    unsigned short* bufT_gp = (unsigned short*)alloc((size_t)N_GW * 128 * 2);
    unsigned short* bufT_sp = (unsigned short*)alloc((size_t)N_SW * 128 * 2);
    _Float16* R_gw = (_Float16*)alloc((size_t)N_GW * 128 * 2);
    _Float16* R_sw = (_Float16*)alloc((size_t)N_SW * 128 * 2);
    float* R_pf = (float*)alloc((size_t)N_PFAS * 128 * 4);
    float* contrib_gp = (float*)alloc((size_t)N_PFAS * 128 * 4);
    float* contrib_sp = (float*)alloc((size_t)N_PFAS * 128 * 4);
    int* perm_all   = (int*)alloc((size_t)E_TOT * 4);
    unsigned* pairs = (unsigned*)alloc((size_t)E_TOT * 4);
    int* off_all    = (int*)alloc((size_t)(NTOT + 1) * 4);
    int* bucketCounts = (int*)alloc((size_t)NB * 4);
    int* bucketOff    = (int*)alloc((size_t)(NB + 1) * 4);
    int* gcursor    = (int*)alloc((size_t)NB * 4);
    _Float16* WtF_pg  = (_Float16*)alloc(16384 * 2);
    _Float16* WtF_ps  = (_Float16*)alloc(16384 * 2);
    _Float16* WtFR_pf = (_Float16*)alloc(16384 * 2);
    _Float16* WtF_gp  = (_Float16*)alloc(16384 * 2);
    _Float16* WtFR_gw = (_Float16*)alloc(16384 * 2);
    _Float16* WtF_sp  = (_Float16*)alloc(16384 * 2);
    _Float16* WtFR_sw = (_Float16*)alloc(16384 * 2);

    // ---- 1. fragment-linear weight prep + unified MFMA transforms ----
    prep_wt_kernel<<<7, 256, 0, stream>>>(
        Wl_pg, Wl_ps, Wr_gp, Wr_sp, Wl_gp, Wr_pg, Wl_sp, Wr_ps,
        WtF_pg, WtF_ps, WtFR_pf, WtF_gp, WtFR_gw, WtF_sp, WtFR_sw);
    mfma_trans_kernel<<<T64_ALL, 256, 0, stream>>>(
        x_pfas, x_gw, x_sw,
        WtF_pg, WtF_ps, WtFR_pf, WtF_gp, WtFR_gw, WtF_sp, WtFR_sw,
        (_Float16*)bufT_pg, (_Float16*)bufT_ps, R_pf,
        (_Float16*)bufT_gp, R_gw, (_Float16*)bufT_sp, R_sw);

    // ---- 2. CSR build: bucket hist -> bucket scan -> bucketed permute ----
    hipMemsetAsync(bucketCounts, 0, (size_t)NB * 4, stream);
    bucket_hist_kernel<<<H_NBLK, 1024, 0, stream>>>(
        ei_pg_dst, ei_ps_dst, ei_gp_dst, ei_sp_dst, bucketCounts);
    bucket_scan_kernel<<<1, 1024, 0, stream>>>(
        bucketCounts, bucketOff, gcursor, off_all);
    bin_kernel<<<BIN_NBLK, 1024, 0, stream>>>(
        ei_pg_src, ei_pg_dst, ei_ps_src, ei_ps_dst,
        ei_gp_src, ei_gp_dst, ei_sp_src, ei_sp_dst, gcursor, pairs);
    unbin_kernel<<<NB, 1024, 0, stream>>>(pairs, bucketOff, off_all, perm_all);

    // ---- 3. merged gather dispatch: gw/sw node passes + pfas seg contribs ----
    gather_all_kernel<<<GW_BLKS + SW_BLKS + 2 * SEGP_BLKS, 512, 0, stream>>>(
        R_gw, R_sw, bl_pg, bl_ps, bufT_pg, bufT_ps, bufT_gp, bufT_sp,
        perm_all, off_all, W_gw, b_gw, W_sw, b_sw, o_gw, o_sw,
        contrib_gp, contrib_sp);

    // ---- 4. pfas finalize ----
    pf_final_kernel<<<(N_PFAS * 32 + 255) / 256, 256, 0, stream>>>(
        R_pf, contrib_gp, contrib_sp, bl_gp, bl_sp, h_pf);
}

// Round 6
// 374.450 us; speedup vs baseline: 1.6899x; 1.0244x over previous
//
#include <hip/hip_runtime.h>

// ---------------------------------------------------------------------------
// Problem constants
// ---------------------------------------------------------------------------
#define N_PFAS 20000
#define N_GW   100000
#define N_SW   30000
#define E_PG   1600000
#define E_GP   640000
#define E_PS   480000
#define E_SP   320000
#define E_TOT  (E_PG + E_PS + E_GP + E_SP)
// Concatenated node-count layout: [pg: N_GW][ps: N_SW][gp: N_PFAS][sp: N_PFAS]
#define BASE_PG 0
#define BASE_PS (N_GW)
#define BASE_GP (N_GW + N_SW)
#define BASE_SP (N_GW + N_SW + N_PFAS)
#define NTOT    (N_GW + N_SW + 2 * N_PFAS)
// Bucketed permute: 256 nodes per bucket.
#define NB        ((NTOT + 255) / 256)       // 665
#define BIN_EPT   8
#define BIN_EPB   (512 * BIN_EPT)            // 4096 edges/block
#define BIN_NBLK  ((E_TOT + BIN_EPB - 1) / BIN_EPB)   // 743
#define SEG_CAP   9216                       // 36KB sPerm -> 4 blocks/CU
// MFMA transform tiles (64 rows each)
#define T64_PF ((N_PFAS + 63) / 64)          // 313
#define T64_GW ((N_GW + 63) / 64)            // 1563
#define T64_SW ((N_SW + 63) / 64)            // 469
#define T64_ALL (T64_PF + T64_GW + T64_SW)
#define TH_HIST_BLKS 512                     // hist blocks folded into trans dispatch
// Merged gather dispatch
#define GW_BLKS   ((N_GW + 63) / 64)         // 1563  (64 nodes/block)
#define SW_BLKS   ((N_SW + 63) / 64)         // 469
#define SEGP_BLKS (N_PFAS / 16)              // 1250  (16 nodes/block, exact)
// LDS stage stride (f16 elems): 136 = 272B, 16B-aligned rows, 4-way max conflict
#define SSTR 136

// ---------------------------------------------------------------------------
// f16 helpers: transformed rows stored f16; aggregation via v_pk_add_f16.
// ---------------------------------------------------------------------------
typedef _Float16 h2_t  __attribute__((ext_vector_type(2)));
typedef _Float16 f16x8 __attribute__((ext_vector_type(8)));
typedef float    f32x4 __attribute__((ext_vector_type(4)));
union HU { unsigned u; h2_t h; };
__device__ __forceinline__ h2_t u2h2(unsigned u) { HU x; x.u = u; return x.h; }

// ---------------------------------------------------------------------------
// 8-ILP f16 gather-sum over a CSR segment: tl = sum of channels (4tx,4tx+1),
// th = (4tx+2, 4tx+3).
// ---------------------------------------------------------------------------
__device__ __forceinline__ void gather_sum_f16(
    const unsigned short* __restrict__ bufT16, const int* __restrict__ perm,
    int lo, int hi, int tx, h2_t& tl, h2_t& th)
{
    h2_t hz; hz.x = (_Float16)0.f; hz.y = (_Float16)0.f;
    h2_t a0 = hz, a1 = hz, a2 = hz, a3 = hz, a4 = hz, a5 = hz, a6 = hz, a7 = hz;
    int i = lo;
    for (; i + 8 <= hi; i += 8) {
        uint2 v0 = *(const uint2*)(bufT16 + (size_t)perm[i + 0] * 128 + tx * 4);
        uint2 v1 = *(const uint2*)(bufT16 + (size_t)perm[i + 1] * 128 + tx * 4);
        uint2 v2 = *(const uint2*)(bufT16 + (size_t)perm[i + 2] * 128 + tx * 4);
        uint2 v3 = *(const uint2*)(bufT16 + (size_t)perm[i + 3] * 128 + tx * 4);
        uint2 v4 = *(const uint2*)(bufT16 + (size_t)perm[i + 4] * 128 + tx * 4);
        uint2 v5 = *(const uint2*)(bufT16 + (size_t)perm[i + 5] * 128 + tx * 4);
        uint2 v6 = *(const uint2*)(bufT16 + (size_t)perm[i + 6] * 128 + tx * 4);
        uint2 v7 = *(const uint2*)(bufT16 + (size_t)perm[i + 7] * 128 + tx * 4);
        a0 += u2h2(v0.x); a1 += u2h2(v0.y);
        a2 += u2h2(v1.x); a3 += u2h2(v1.y);
        a4 += u2h2(v2.x); a5 += u2h2(v2.y);
        a6 += u2h2(v3.x); a7 += u2h2(v3.y);
        a0 += u2h2(v4.x); a1 += u2h2(v4.y);
        a2 += u2h2(v5.x); a3 += u2h2(v5.y);
        a4 += u2h2(v6.x); a5 += u2h2(v6.y);
        a6 += u2h2(v7.x); a7 += u2h2(v7.y);
    }
    for (; i + 2 <= hi; i += 2) {
        uint2 v0 = *(const uint2*)(bufT16 + (size_t)perm[i + 0] * 128 + tx * 4);
        uint2 v1 = *(const uint2*)(bufT16 + (size_t)perm[i + 1] * 128 + tx * 4);
        a0 += u2h2(v0.x); a1 += u2h2(v0.y);
        a2 += u2h2(v1.x); a3 += u2h2(v1.y);
    }
    if (i < hi) {
        uint2 v0 = *(const uint2*)(bufT16 + (size_t)perm[i] * 128 + tx * 4);
        a0 += u2h2(v0.x); a1 += u2h2(v0.y);
    }
    tl = (a0 + a2) + (a4 + a6);
    th = (a1 + a3) + (a5 + a7);
}

// ---------------------------------------------------------------------------
// Weight prep: write each W (f32 [k][n]) as FRAGMENT-LINEAR f16 WtF:
//   WtF[((ct*4+ks)*64 + lane)*8 + j] = W[ks*32 + (lane>>4)*8 + j][ct*16 + (lane&15)]
// Block 0 additionally zeroes bucketCounts (replaces hipMemsetAsync).
// m==2 sums Wr_gp+Wr_sp (pfas HeteroConv fusion).
// ---------------------------------------------------------------------------
__global__ __launch_bounds__(256) void prep_wt_kernel(
    const float* __restrict__ Wl_pg, const float* __restrict__ Wl_ps,
    const float* __restrict__ Wr_gp, const float* __restrict__ Wr_sp,
    const float* __restrict__ Wl_gp, const float* __restrict__ Wr_pg,
    const float* __restrict__ Wl_sp, const float* __restrict__ Wr_ps,
    _Float16* __restrict__ WtF_pg, _Float16* __restrict__ WtF_ps,
    _Float16* __restrict__ WtFR_pf,
    _Float16* __restrict__ WtF_gp, _Float16* __restrict__ WtFR_gw,
    _Float16* __restrict__ WtF_sp, _Float16* __restrict__ WtFR_sw,
    int* __restrict__ bucketCounts)
{
    const int m = blockIdx.x;
    if (m == 0) {
        for (int i = threadIdx.x; i < NB; i += 256) bucketCounts[i] = 0;
    }
    const float* A = nullptr; const float* B = nullptr; _Float16* O = nullptr;
    switch (m) {
        case 0: A = Wl_pg; O = WtF_pg;  break;
        case 1: A = Wl_ps; O = WtF_ps;  break;
        case 2: A = Wr_gp; B = Wr_sp; O = WtFR_pf; break;
        case 3: A = Wl_gp; O = WtF_gp;  break;
        case 4: A = Wr_pg; O = WtFR_gw; break;
        case 5: A = Wl_sp; O = WtF_sp;  break;
        default: A = Wr_ps; O = WtFR_sw; break;
    }
    for (int t = threadIdx.x; t < 2048; t += 256) {
        int lane = t & 63, g = t >> 6;      // g = ct*4+ks
        int ks = g & 3, ct = g >> 2;
        int nn = ct * 16 + (lane & 15);
        int k0 = ks * 32 + (lane >> 4) * 8;
        f16x8 v;
#pragma unroll
        for (int j = 0; j < 8; ++j) {
            float x = A[(k0 + j) * 128 + nn];
            if (B) x += B[(k0 + j) * 128 + nn];
            v[j] = (_Float16)x;
        }
        *(f16x8*)(O + (size_t)t * 8) = v;
    }
}

// ---------------------------------------------------------------------------
// f16-output MFMA pass with per-wave LDS staging: MFMA -> LDS tile (stride
// 136) -> f16x8 readback -> fully coalesced 16B/lane global stores (4 store
// instrs/wave instead of 32 partial-line scalar stores).
// ---------------------------------------------------------------------------
__device__ __forceinline__ void mfma_one_B16(
    const _Float16* __restrict__ WtF, const f16x8* a, _Float16* sstage,
    int rbase, int n, int lane, _Float16* __restrict__ o16)
{
    f16x8 bf[8][4];
#pragma unroll
    for (int ct = 0; ct < 8; ++ct)
#pragma unroll
        for (int ks = 0; ks < 4; ++ks)
            bf[ct][ks] = *(const f16x8*)(WtF + (size_t)((ct * 4 + ks) * 64 + lane) * 8);

    f32x4 acc[8];
#pragma unroll
    for (int ct = 0; ct < 8; ++ct) acc[ct] = (f32x4){0.f, 0.f, 0.f, 0.f};
#pragma unroll
    for (int ct = 0; ct < 8; ++ct)
#pragma unroll
        for (int ks = 0; ks < 4; ++ks)
            acc[ct] = __builtin_amdgcn_mfma_f32_16x16x32_f16(a[ks], bf[ct][ks], acc[ct], 0, 0, 0);

    const int rl = (lane >> 4) * 4;      // local row base for C-frag
    const int cb = lane & 15;
#pragma unroll
    for (int ct = 0; ct < 8; ++ct)
#pragma unroll
        for (int e = 0; e < 4; ++e)
            sstage[(rl + e) * SSTR + ct * 16 + cb] = (_Float16)acc[ct][e];

#pragma unroll
    for (int i = 0; i < 4; ++i) {
        int lr = i * 4 + (lane >> 4);
        int r = rbase + lr;
        if (r < n) {
            f16x8 v = *(const f16x8*)(sstage + lr * SSTR + cb * 8);
            *(f16x8*)(o16 + ((size_t)r << 7) + cb * 8) = v;
        }
    }
}

// f32-output pass (R_pf only, 6% of tiles): scalar stores, no staging.
__device__ __forceinline__ void mfma_one_B32(
    const _Float16* __restrict__ WtF, const f16x8* a,
    int rbase, int n, int lane, float* __restrict__ o32)
{
    f16x8 bf[8][4];
#pragma unroll
    for (int ct = 0; ct < 8; ++ct)
#pragma unroll
        for (int ks = 0; ks < 4; ++ks)
            bf[ct][ks] = *(const f16x8*)(WtF + (size_t)((ct * 4 + ks) * 64 + lane) * 8);
    f32x4 acc[8];
#pragma unroll
    for (int ct = 0; ct < 8; ++ct) acc[ct] = (f32x4){0.f, 0.f, 0.f, 0.f};
#pragma unroll
    for (int ct = 0; ct < 8; ++ct)
#pragma unroll
        for (int ks = 0; ks < 4; ++ks)
            acc[ct] = __builtin_amdgcn_mfma_f32_16x16x32_f16(a[ks], bf[ct][ks], acc[ct], 0, 0, 0);
    const int rowb = rbase + (lane >> 4) * 4;
    const int bcol = lane & 15;
#pragma unroll
    for (int ct = 0; ct < 8; ++ct) {
        const int col = ct * 16 + bcol;
#pragma unroll
        for (int e = 0; e < 4; ++e) {
            int r = rowb + e;
            if (r < n) o32[((size_t)r << 7) + col] = acc[ct][e];
        }
    }
}

// ---------------------------------------------------------------------------
// Merged dispatch: blocks [0,TH_HIST_BLKS) do the bucket histogram (grid-
// stride, LDS-privatized); remaining blocks do the unified MFMA transforms.
// Independent work -> one dispatch hides hist under trans.
// ---------------------------------------------------------------------------
__global__ __launch_bounds__(256, 2) void trans_hist_kernel(
    const float* __restrict__ x_pfas, const float* __restrict__ x_gw,
    const float* __restrict__ x_sw,
    const _Float16* __restrict__ WtF_pg, const _Float16* __restrict__ WtF_ps,
    const _Float16* __restrict__ WtFR_pf,
    const _Float16* __restrict__ WtF_gp, const _Float16* __restrict__ WtFR_gw,
    const _Float16* __restrict__ WtF_sp, const _Float16* __restrict__ WtFR_sw,
    _Float16* __restrict__ bufT_pg, _Float16* __restrict__ bufT_ps,
    float* __restrict__ R_pf,
    _Float16* __restrict__ bufT_gp, _Float16* __restrict__ R_gw,
    _Float16* __restrict__ bufT_sp, _Float16* __restrict__ R_sw,
    const int* __restrict__ d_pg, const int* __restrict__ d_ps,
    const int* __restrict__ d_gp, const int* __restrict__ d_sp,
    int* __restrict__ bucketCounts)
{
    __shared__ char smem[4 * 16 * SSTR * 2];   // 17408 B; hist reuses 2660 B
    const int tid = threadIdx.x;

    if (blockIdx.x < TH_HIST_BLKS) {
        int* hist = (int*)smem;
        for (int i = tid; i < NB; i += 256) hist[i] = 0;
        __syncthreads();
        for (int e = blockIdx.x * 256 + tid; e < E_TOT; e += TH_HIST_BLKS * 256) {
            int idx;
            if (e < E_PG)                    idx = BASE_PG + d_pg[e];
            else if (e < E_PG + E_PS)        idx = BASE_PS + d_ps[e - E_PG];
            else if (e < E_PG + E_PS + E_GP) idx = BASE_GP + d_gp[e - E_PG - E_PS];
            else                             idx = BASE_SP + d_sp[e - E_PG - E_PS - E_GP];
            atomicAdd(&hist[idx >> 8], 1);
        }
        __syncthreads();
        for (int i = tid; i < NB; i += 256) {
            int c = hist[i];
            if (c) atomicAdd(&bucketCounts[i], c);
        }
        return;
    }

    const int b = blockIdx.x - TH_HIST_BLKS;
    int mode, tile, n; const float* X;
    if (b < T64_PF)               { mode = 0; tile = b;                    X = x_pfas; n = N_PFAS; }
    else if (b < T64_PF + T64_GW) { mode = 1; tile = b - T64_PF;           X = x_gw;   n = N_GW; }
    else                          { mode = 2; tile = b - T64_PF - T64_GW;  X = x_sw;   n = N_SW; }
    const int lane = tid & 63;
    const int w    = tid >> 6;
    const int rbase = tile * 64 + w * 16;
    const int rA = rbase + (lane & 15);
    const int ko = (lane >> 4) * 8;
    _Float16* sstage = (_Float16*)smem + (size_t)w * 16 * SSTR;

    f16x8 a[4];
#pragma unroll
    for (int ks = 0; ks < 4; ++ks) {
        float4 x0 = make_float4(0.f, 0.f, 0.f, 0.f), x1 = x0;
        if (rA < n) {
            const float* xp = X + ((size_t)rA << 7) + ks * 32 + ko;
            x0 = *(const float4*)xp;
            x1 = *(const float4*)(xp + 4);
        }
        f16x8 v;
        v[0] = (_Float16)x0.x; v[1] = (_Float16)x0.y; v[2] = (_Float16)x0.z; v[3] = (_Float16)x0.w;
        v[4] = (_Float16)x1.x; v[5] = (_Float16)x1.y; v[6] = (_Float16)x1.z; v[7] = (_Float16)x1.w;
        a[ks] = v;
    }
    if (mode == 0) {
        mfma_one_B16(WtF_pg,  a, sstage, rbase, n, lane, bufT_pg);
        mfma_one_B16(WtF_ps,  a, sstage, rbase, n, lane, bufT_ps);
        mfma_one_B32(WtFR_pf, a, rbase, n, lane, R_pf);
    } else if (mode == 1) {
        mfma_one_B16(WtF_gp,  a, sstage, rbase, n, lane, bufT_gp);
        mfma_one_B16(WtFR_gw, a, sstage, rbase, n, lane, R_gw);
    } else {
        mfma_one_B16(WtF_sp,  a, sstage, rbase, n, lane, bufT_sp);
        mfma_one_B16(WtFR_sw, a, sstage, rbase, n, lane, R_sw);
    }
}

// ---------------------------------------------------------------------------
// Merged gather dispatch: GEMM-free, LDS-free, barrier-free. (unchanged)
// ---------------------------------------------------------------------------
__global__ __launch_bounds__(512, 8) void gather_all_kernel(
    const _Float16* __restrict__ R_gw, const _Float16* __restrict__ R_sw,
    const float* __restrict__ bl_pg, const float* __restrict__ bl_ps,
    const unsigned short* __restrict__ bufT_pg,
    const unsigned short* __restrict__ bufT_ps,
    const unsigned short* __restrict__ bufT_gp,
    const unsigned short* __restrict__ bufT_sp,
    const int* __restrict__ perm, const int* __restrict__ off_all,
    const float* __restrict__ W_gw, const float* __restrict__ b_gw,
    const float* __restrict__ W_sw, const float* __restrict__ b_sw,
    float* __restrict__ o_gw, float* __restrict__ o_sw,
    float* __restrict__ contrib_gp, float* __restrict__ contrib_sp)
{
    const int b = blockIdx.x;
    const int tid = threadIdx.x;
    const int tx = tid & 31;
    const int g = tid >> 5;

    if (b < GW_BLKS + SW_BLKS) {
        int n; const _Float16* R; const float* bl; const unsigned short* bufT16;
        const int* off; const float* wout; const float* bout; float* out; int tile;
        if (b < GW_BLKS) {
            n = N_GW; R = R_gw; bl = bl_pg; bufT16 = bufT_pg; off = off_all + BASE_PG;
            wout = W_gw; bout = b_gw; out = o_gw; tile = b;
        } else {
            n = N_SW; R = R_sw; bl = bl_ps; bufT16 = bufT_ps; off = off_all + BASE_PS;
            wout = W_sw; bout = b_sw; out = o_sw; tile = b - GW_BLKS;
        }
        const int rbase = tile * 64 + g * 4;
        float4 bv = ((const float4*)bl)[tx];
        float4 wo = ((const float4*)wout)[tx];
        float bo = bout[0];
#pragma unroll
        for (int rr = 0; rr < 4; ++rr) {
            int r = rbase + rr;
            int lo = 0, hi = 0;
            if (r < n) { lo = off[r]; hi = off[r + 1]; }
            h2_t tl, th;
            gather_sum_f16(bufT16, perm, lo, hi, tx, tl, th);
            float4 rf = make_float4(0.f, 0.f, 0.f, 0.f);
            if (r < n) {
                uint2 rv = *(const uint2*)((const unsigned short*)R + ((size_t)r << 7) + tx * 4);
                h2_t r01 = u2h2(rv.x), r23 = u2h2(rv.y);
                rf = make_float4((float)r01.x, (float)r01.y, (float)r23.x, (float)r23.y);
            }
            float inv = 1.0f / fmaxf((float)(hi - lo), 1.0f);
            float h0  = fmaxf(rf.x + bv.x + (float)tl.x * inv, 0.f);
            float h1  = fmaxf(rf.y + bv.y + (float)tl.y * inv, 0.f);
            float h2v = fmaxf(rf.z + bv.z + (float)th.x * inv, 0.f);
            float h3  = fmaxf(rf.w + bv.w + (float)th.y * inv, 0.f);
            float pv = h0 * wo.x + h1 * wo.y + h2v * wo.z + h3 * wo.w;
            pv += __shfl_xor(pv, 1, 32);
            pv += __shfl_xor(pv, 2, 32);
            pv += __shfl_xor(pv, 4, 32);
            pv += __shfl_xor(pv, 8, 32);
            pv += __shfl_xor(pv, 16, 32);
            if (tx == 0 && r < n) out[r] = pv + bo;
        }
    } else {
        const int b2 = b - (GW_BLKS + SW_BLKS);
        const unsigned short* bufT; const int* off; float* contrib; int node;
        if (b2 < SEGP_BLKS) {
            bufT = bufT_gp; off = off_all + BASE_GP; contrib = contrib_gp; node = b2 * 16 + g;
        } else {
            bufT = bufT_sp; off = off_all + BASE_SP; contrib = contrib_sp; node = (b2 - SEGP_BLKS) * 16 + g;
        }
        int lo = off[node], hi = off[node + 1];
        h2_t tl, th;
        gather_sum_f16(bufT, perm, lo, hi, tx, tl, th);
        float inv = 1.0f / fmaxf((float)(hi - lo), 1.0f);
        float4 o;
        o.x = (float)tl.x * inv; o.y = (float)tl.y * inv;
        o.z = (float)th.x * inv; o.w = (float)th.y * inv;
        ((float4*)contrib)[(size_t)node * 32 + tx] = o;
    }
}

// ---------------------------------------------------------------------------
// pfas finalize: h_pf = relu(R_pf + contrib_gp + contrib_sp + bl_gp + bl_sp)
// ---------------------------------------------------------------------------
__global__ __launch_bounds__(256) void pf_final_kernel(
    const float* __restrict__ R_pf,
    const float* __restrict__ contrib_gp, const float* __restrict__ contrib_sp,
    const float* __restrict__ blG, const float* __restrict__ blS,
    float* __restrict__ out)
{
    int t = blockIdx.x * 256 + threadIdx.x;   // over N_PFAS*32 float4 lanes
    if (t >= N_PFAS * 32) return;
    int c4 = t & 31;
    float4 b1 = ((const float4*)blG)[c4];
    float4 b2 = ((const float4*)blS)[c4];
    float4 rv = ((const float4*)R_pf)[t];
    float4 cg = ((const float4*)contrib_gp)[t];
    float4 cs = ((const float4*)contrib_sp)[t];
    float4 o;
    o.x = fmaxf(rv.x + cg.x + cs.x + b1.x + b2.x, 0.f);
    o.y = fmaxf(rv.y + cg.y + cs.y + b1.y + b2.y, 0.f);
    o.z = fmaxf(rv.z + cg.z + cs.z + b1.z + b2.z, 0.f);
    o.w = fmaxf(rv.w + cg.w + cs.w + b1.w + b2.w, 0.f);
    ((float4*)out)[t] = o;
}

// ---------------------------------------------------------------------------
// Single-block exclusive scan over the 665 bucket counts. Seeds gcursor.
// ---------------------------------------------------------------------------
__global__ __launch_bounds__(1024) void bucket_scan_kernel(
    const int* __restrict__ bucketCounts, int* __restrict__ bucketOff,
    int* __restrict__ gcursor, int* __restrict__ off_all)
{
    __shared__ int sp[1024];
    const int t = threadIdx.x;
    int v = (t < NB) ? bucketCounts[t] : 0;
    sp[t] = v;
    __syncthreads();
    for (int ofs = 1; ofs < 1024; ofs <<= 1) {
        int add = (t >= ofs) ? sp[t - ofs] : 0;
        __syncthreads();
        sp[t] += add;
        __syncthreads();
    }
    if (t < NB) {
        int excl = sp[t] - v;
        bucketOff[t] = excl;
        gcursor[t] = excl;
    }
    if (t == 0) { bucketOff[NB] = E_TOT; off_all[NTOT] = E_TOT; }
}

// ---------------------------------------------------------------------------
// Pass 1: bin edges into 256-node buckets. 512 threads (4 blocks/CU vs the
// old 1024-thread 2-block cap), 8 edges/thread. Packed: (idx&255)|(src<<8).
// ---------------------------------------------------------------------------
__global__ __launch_bounds__(512) void bin_kernel(
    const int* __restrict__ s_pg, const int* __restrict__ d_pg,
    const int* __restrict__ s_ps, const int* __restrict__ d_ps,
    const int* __restrict__ s_gp, const int* __restrict__ d_gp,
    const int* __restrict__ s_sp, const int* __restrict__ d_sp,
    int* __restrict__ gcursor, unsigned* __restrict__ pairs)
{
    __shared__ int hist[NB];
    __shared__ int chunkBase[NB];
    const int tid = threadIdx.x;
    for (int i = tid; i < NB; i += 512) hist[i] = 0;
    __syncthreads();

    const int base = blockIdx.x * BIN_EPB;
    int bkt[BIN_EPT], rnk[BIN_EPT];
    unsigned pk[BIN_EPT];
#pragma unroll
    for (int k = 0; k < BIN_EPT; ++k) {
        int e = base + k * 512 + tid;
        int idx = -1, src = 0;
        if (e < E_PG) { idx = BASE_PG + d_pg[e]; src = s_pg[e]; }
        else if (e < E_PG + E_PS) { int i2 = e - E_PG; idx = BASE_PS + d_ps[i2]; src = s_ps[i2]; }
        else if (e < E_PG + E_PS + E_GP) { int i2 = e - E_PG - E_PS; idx = BASE_GP + d_gp[i2]; src = s_gp[i2]; }
        else if (e < E_TOT) { int i2 = e - E_PG - E_PS - E_GP; idx = BASE_SP + d_sp[i2]; src = s_sp[i2]; }
        if (idx >= 0) {
            int b = idx >> 8;
            bkt[k] = b;
            rnk[k] = atomicAdd(&hist[b], 1);
            pk[k] = (unsigned)(idx & 255) | ((unsigned)src << 8);
        } else bkt[k] = -1;
    }
    __syncthreads();
    for (int i = tid; i < NB; i += 512) {
        int c = hist[i];
        chunkBase[i] = c ? atomicAdd(&gcursor[i], c) : 0;
    }
    __syncthreads();
#pragma unroll
    for (int k = 0; k < BIN_EPT; ++k)
        if (bkt[k] >= 0) pairs[chunkBase[bkt[k]] + rnk[k]] = pk[k];
}

// ---------------------------------------------------------------------------
// Pass 2: one 512-thread block per bucket (SEG_CAP 9216 -> 40KB LDS -> 4
// blocks/CU). Per-node counts from pairs via LDS atomics, LDS scan ->
// off_all, scatter into LDS segment, stream out coalesced.
// ---------------------------------------------------------------------------
__global__ __launch_bounds__(512) void unbin_kernel(
    const unsigned* __restrict__ pairs, const int* __restrict__ bucketOff,
    int* __restrict__ off_all, int* __restrict__ perm_all)
{
    __shared__ int sPerm[SEG_CAP];
    __shared__ int cnt[256];
    __shared__ int sp[256];
    __shared__ int cur[256];
    const int b = blockIdx.x;
    const int nb0 = b << 8;
    const int nb1 = min(nb0 + 256, NTOT);
    const int tid = threadIdx.x;
    const int base = bucketOff[b];
    const int end  = bucketOff[b + 1];
    const int len = end - base;

    if (tid < 256) cnt[tid] = 0;
    __syncthreads();
    for (int i = base + tid; i < end; i += 512)
        atomicAdd(&cnt[pairs[i] & 255u], 1);
    __syncthreads();
    int v = (tid < 256) ? cnt[tid] : 0;
    if (tid < 256) sp[tid] = v;
    __syncthreads();
    for (int ofs = 1; ofs < 256; ofs <<= 1) {
        int add = (tid < 256 && tid >= ofs) ? sp[tid - ofs] : 0;
        __syncthreads();
        if (tid < 256) sp[tid] += add;
        __syncthreads();
    }
    if (tid < 256) {
        int excl = sp[tid] - v;
        cur[tid] = excl;
        if (nb0 + tid < nb1) off_all[nb0 + tid] = base + excl;
    }
    __syncthreads();

    if (len <= SEG_CAP) {
        for (int i = base + tid; i < end; i += 512) {
            unsigned p = pairs[i];
            int pos = atomicAdd(&cur[p & 255u], 1);
            sPerm[pos] = (int)(p >> 8);
        }
        __syncthreads();
        for (int i = tid; i < len; i += 512)
            perm_all[base + i] = sPerm[i];
    } else {
        for (int i = base + tid; i < end; i += 512) {
            unsigned p = pairs[i];
            int pos = atomicAdd(&cur[p & 255u], 1);
            perm_all[base + pos] = (int)(p >> 8);
        }
    }
}

// ---------------------------------------------------------------------------
// Launch
// ---------------------------------------------------------------------------
extern "C" void kernel_launch(void* const* d_in, const int* in_sizes, int n_in,
                              void* d_out, int out_size, void* d_ws, size_t ws_size,
                              hipStream_t stream)
{
    const float* x_pfas = (const float*)d_in[0];
    const float* x_gw   = (const float*)d_in[1];
    const float* x_sw   = (const float*)d_in[2];
    const int* ei_pg_src = (const int*)d_in[3];
    const int* ei_pg_dst = (const int*)d_in[4];
    const int* ei_gp_src = (const int*)d_in[5];
    const int* ei_gp_dst = (const int*)d_in[6];
    const int* ei_ps_src = (const int*)d_in[7];
    const int* ei_ps_dst = (const int*)d_in[8];
    const int* ei_sp_src = (const int*)d_in[9];
    const int* ei_sp_dst = (const int*)d_in[10];
    const float* Wl_pg = (const float*)d_in[11];
    const float* bl_pg = (const float*)d_in[12];
    const float* Wr_pg = (const float*)d_in[13];
    const float* Wl_gp = (const float*)d_in[14];
    const float* bl_gp = (const float*)d_in[15];
    const float* Wr_gp = (const float*)d_in[16];
    const float* Wl_ps = (const float*)d_in[17];
    const float* bl_ps = (const float*)d_in[18];
    const float* Wr_ps = (const float*)d_in[19];
    const float* Wl_sp = (const float*)d_in[20];
    const float* bl_sp = (const float*)d_in[21];
    const float* Wr_sp = (const float*)d_in[22];
    const float* W_gw = (const float*)d_in[23];
    const float* b_gw = (const float*)d_in[24];
    const float* W_sw = (const float*)d_in[25];
    const float* b_sw = (const float*)d_in[26];

    float* out  = (float*)d_out;
    float* h_pf = out;                         // 20000*128
    float* o_gw = out + (size_t)N_PFAS * 128;  // 100000
    float* o_sw = o_gw + N_GW;                 // 30000

    // ---- workspace layout (~130 MB) ----
    char* p = (char*)d_ws;
    auto alloc = [&](size_t bytes) { char* q = p; p += (bytes + 15) & ~(size_t)15; return q; };
    unsigned short* bufT_pg = (unsigned short*)alloc((size_t)N_PFAS * 128 * 2);
    unsigned short* bufT_ps = (unsigned short*)alloc((size_t)N_PFAS * 128 * 2);
    unsigned short* bufT_gp = (unsigned short*)alloc((size_t)N_GW * 128 * 2);
    unsigned short* bufT_sp = (unsigned short*)alloc((size_t)N_SW * 128 * 2);
    _Float16* R_gw = (_Float16*)alloc((size_t)N_GW * 128 * 2);
    _Float16* R_sw = (_Float16*)alloc((size_t)N_SW * 128 * 2);
    float* R_pf = (float*)alloc((size_t)N_PFAS * 128 * 4);
    float* contrib_gp = (float*)alloc((size_t)N_PFAS * 128 * 4);
    float* contrib_sp = (float*)alloc((size_t)N_PFAS * 128 * 4);
    int* perm_all   = (int*)alloc((size_t)E_TOT * 4);
    unsigned* pairs = (unsigned*)alloc((size_t)E_TOT * 4);
    int* off_all    = (int*)alloc((size_t)(NTOT + 1) * 4);
    int* bucketCounts = (int*)alloc((size_t)NB * 4);
    int* bucketOff    = (int*)alloc((size_t)(NB + 1) * 4);
    int* gcursor    = (int*)alloc((size_t)NB * 4);
    _Float16* WtF_pg  = (_Float16*)alloc(16384 * 2);
    _Float16* WtF_ps  = (_Float16*)alloc(16384 * 2);
    _Float16* WtFR_pf = (_Float16*)alloc(16384 * 2);
    _Float16* WtF_gp  = (_Float16*)alloc(16384 * 2);
    _Float16* WtFR_gw = (_Float16*)alloc(16384 * 2);
    _Float16* WtF_sp  = (_Float16*)alloc(16384 * 2);
    _Float16* WtFR_sw = (_Float16*)alloc(16384 * 2);

    // ---- 1. weight prep (+ bucketCounts zero) ----
    prep_wt_kernel<<<7, 256, 0, stream>>>(
        Wl_pg, Wl_ps, Wr_gp, Wr_sp, Wl_gp, Wr_pg, Wl_sp, Wr_ps,
        WtF_pg, WtF_ps, WtFR_pf, WtF_gp, WtFR_gw, WtF_sp, WtFR_sw,
        bucketCounts);

    // ---- 2. merged MFMA transforms + bucket histogram ----
    trans_hist_kernel<<<TH_HIST_BLKS + T64_ALL, 256, 0, stream>>>(
        x_pfas, x_gw, x_sw,
        WtF_pg, WtF_ps, WtFR_pf, WtF_gp, WtFR_gw, WtF_sp, WtFR_sw,
        (_Float16*)bufT_pg, (_Float16*)bufT_ps, R_pf,
        (_Float16*)bufT_gp, R_gw, (_Float16*)bufT_sp, R_sw,
        ei_pg_dst, ei_ps_dst, ei_gp_dst, ei_sp_dst, bucketCounts);

    // ---- 3. CSR build: scan -> bin -> unbin ----
    bucket_scan_kernel<<<1, 1024, 0, stream>>>(
        bucketCounts, bucketOff, gcursor, off_all);
    bin_kernel<<<BIN_NBLK, 512, 0, stream>>>(
        ei_pg_src, ei_pg_dst, ei_ps_src, ei_ps_dst,
        ei_gp_src, ei_gp_dst, ei_sp_src, ei_sp_dst, gcursor, pairs);
    unbin_kernel<<<NB, 512, 0, stream>>>(pairs, bucketOff, off_all, perm_all);

    // ---- 4. merged gather dispatch: gw/sw node passes + pfas seg contribs ----
    gather_all_kernel<<<GW_BLKS + SW_BLKS + 2 * SEGP_BLKS, 512, 0, stream>>>(
        R_gw, R_sw, bl_pg, bl_ps, bufT_pg, bufT_ps, bufT_gp, bufT_sp,
        perm_all, off_all, W_gw, b_gw, W_sw, b_sw, o_gw, o_sw,
        contrib_gp, contrib_sp);

    // ---- 5. pfas finalize ----
    pf_final_kernel<<<(N_PFAS * 32 + 255) / 256, 256, 0, stream>>>(
        R_pf, contrib_gp, contrib_sp, bl_gp, bl_sp, h_pf);
}

// Round 7
// 358.425 us; speedup vs baseline: 1.7654x; 1.0447x over previous
//
#include <hip/hip_runtime.h>

// ---------------------------------------------------------------------------
// Problem constants
// ---------------------------------------------------------------------------
#define N_PFAS 20000
#define N_GW   100000
#define N_SW   30000
#define E_PG   1600000
#define E_GP   640000
#define E_PS   480000
#define E_SP   320000
#define E_TOT  (E_PG + E_PS + E_GP + E_SP)
// Concatenated node-count layout: [pg: N_GW][ps: N_SW][gp: N_PFAS][sp: N_PFAS]
#define BASE_PG 0
#define BASE_PS (N_GW)
#define BASE_GP (N_GW + N_SW)
#define BASE_SP (N_GW + N_SW + N_PFAS)
#define NTOT    (N_GW + N_SW + 2 * N_PFAS)
// Bucketed permute: 256 nodes per bucket.
#define NB        ((NTOT + 255) / 256)       // 665
#define BIN_EPT   8
#define BIN_EPB   (512 * BIN_EPT)            // 4096 edges/block
#define BIN_NBLK  ((E_TOT + BIN_EPB - 1) / BIN_EPB)   // 743
#define SEG_CAP   9216                       // 36KB sPerm -> 4 blocks/CU
// MFMA transform tiles (64 rows each)
#define T64_PF ((N_PFAS + 63) / 64)          // 313
#define T64_GW ((N_GW + 63) / 64)            // 1563
#define T64_SW ((N_SW + 63) / 64)            // 469
#define T64_ALL (T64_PF + T64_GW + T64_SW)
#define TH_HIST_BLKS 512                     // hist blocks folded into trans dispatch
// Merged gather dispatch: gw/sw 32 nodes/block (2 rows/group), segs 16/block
#define GW_BLKS   ((N_GW + 31) / 32)         // 3125
#define SW_BLKS   ((N_SW + 31) / 32)         // 938
#define SEGP_BLKS (N_PFAS / 16)              // 1250  (1 node/group, exact)
// LDS stage stride (f16 elems): 136 = 272B, 16B-aligned rows, 4-way max conflict
#define SSTR 136

// ---------------------------------------------------------------------------
// f16 helpers: transformed rows stored f16; aggregation via v_pk_add_f16.
// ---------------------------------------------------------------------------
typedef _Float16 h2_t  __attribute__((ext_vector_type(2)));
typedef _Float16 f16x8 __attribute__((ext_vector_type(8)));
typedef float    f32x4 __attribute__((ext_vector_type(4)));
union HU { unsigned u; h2_t h; };
__device__ __forceinline__ h2_t u2h2(unsigned u) { HU x; x.u = u; return x.h; }

// ---------------------------------------------------------------------------
// 8-ILP f16 gather-sum over a CSR segment: tl = sum of channels (4tx,4tx+1),
// th = (4tx+2, 4tx+3).
// ---------------------------------------------------------------------------
__device__ __forceinline__ void gather_sum_f16(
    const unsigned short* __restrict__ bufT16, const int* __restrict__ perm,
    int lo, int hi, int tx, h2_t& tl, h2_t& th)
{
    h2_t hz; hz.x = (_Float16)0.f; hz.y = (_Float16)0.f;
    h2_t a0 = hz, a1 = hz, a2 = hz, a3 = hz, a4 = hz, a5 = hz, a6 = hz, a7 = hz;
    int i = lo;
    for (; i + 8 <= hi; i += 8) {
        uint2 v0 = *(const uint2*)(bufT16 + (size_t)perm[i + 0] * 128 + tx * 4);
        uint2 v1 = *(const uint2*)(bufT16 + (size_t)perm[i + 1] * 128 + tx * 4);
        uint2 v2 = *(const uint2*)(bufT16 + (size_t)perm[i + 2] * 128 + tx * 4);
        uint2 v3 = *(const uint2*)(bufT16 + (size_t)perm[i + 3] * 128 + tx * 4);
        uint2 v4 = *(const uint2*)(bufT16 + (size_t)perm[i + 4] * 128 + tx * 4);
        uint2 v5 = *(const uint2*)(bufT16 + (size_t)perm[i + 5] * 128 + tx * 4);
        uint2 v6 = *(const uint2*)(bufT16 + (size_t)perm[i + 6] * 128 + tx * 4);
        uint2 v7 = *(const uint2*)(bufT16 + (size_t)perm[i + 7] * 128 + tx * 4);
        a0 += u2h2(v0.x); a1 += u2h2(v0.y);
        a2 += u2h2(v1.x); a3 += u2h2(v1.y);
        a4 += u2h2(v2.x); a5 += u2h2(v2.y);
        a6 += u2h2(v3.x); a7 += u2h2(v3.y);
        a0 += u2h2(v4.x); a1 += u2h2(v4.y);
        a2 += u2h2(v5.x); a3 += u2h2(v5.y);
        a4 += u2h2(v6.x); a5 += u2h2(v6.y);
        a6 += u2h2(v7.x); a7 += u2h2(v7.y);
    }
    for (; i + 2 <= hi; i += 2) {
        uint2 v0 = *(const uint2*)(bufT16 + (size_t)perm[i + 0] * 128 + tx * 4);
        uint2 v1 = *(const uint2*)(bufT16 + (size_t)perm[i + 1] * 128 + tx * 4);
        a0 += u2h2(v0.x); a1 += u2h2(v0.y);
        a2 += u2h2(v1.x); a3 += u2h2(v1.y);
    }
    if (i < hi) {
        uint2 v0 = *(const uint2*)(bufT16 + (size_t)perm[i] * 128 + tx * 4);
        a0 += u2h2(v0.x); a1 += u2h2(v0.y);
    }
    tl = (a0 + a2) + (a4 + a6);
    th = (a1 + a3) + (a5 + a7);
}

// ---------------------------------------------------------------------------
// Weight prep (28 blocks = 7 matrices x 4 chunks): fragment-linear f16 WtF.
//   WtF[((ct*4+ks)*64+lane)*8+j] = W[ks*32+(lane>>4)*8+j][ct*16+(lane&15)]
// Block (0,0) also zeroes bucketCounts. m==2 sums Wr_gp+Wr_sp.
// ---------------------------------------------------------------------------
__global__ __launch_bounds__(256) void prep_wt_kernel(
    const float* __restrict__ Wl_pg, const float* __restrict__ Wl_ps,
    const float* __restrict__ Wr_gp, const float* __restrict__ Wr_sp,
    const float* __restrict__ Wl_gp, const float* __restrict__ Wr_pg,
    const float* __restrict__ Wl_sp, const float* __restrict__ Wr_ps,
    _Float16* __restrict__ WtF_pg, _Float16* __restrict__ WtF_ps,
    _Float16* __restrict__ WtFR_pf,
    _Float16* __restrict__ WtF_gp, _Float16* __restrict__ WtFR_gw,
    _Float16* __restrict__ WtF_sp, _Float16* __restrict__ WtFR_sw,
    int* __restrict__ bucketCounts)
{
    const int m = blockIdx.x >> 2;
    const int chunk = blockIdx.x & 3;
    if (blockIdx.x == 0) {
        for (int i = threadIdx.x; i < NB; i += 256) bucketCounts[i] = 0;
    }
    const float* A = nullptr; const float* B = nullptr; _Float16* O = nullptr;
    switch (m) {
        case 0: A = Wl_pg; O = WtF_pg;  break;
        case 1: A = Wl_ps; O = WtF_ps;  break;
        case 2: A = Wr_gp; B = Wr_sp; O = WtFR_pf; break;
        case 3: A = Wl_gp; O = WtF_gp;  break;
        case 4: A = Wr_pg; O = WtFR_gw; break;
        case 5: A = Wl_sp; O = WtF_sp;  break;
        default: A = Wr_ps; O = WtFR_sw; break;
    }
    for (int t = chunk * 512 + threadIdx.x; t < (chunk + 1) * 512; t += 256) {
        int lane = t & 63, g = t >> 6;      // g = ct*4+ks
        int ks = g & 3, ct = g >> 2;
        int nn = ct * 16 + (lane & 15);
        int k0 = ks * 32 + (lane >> 4) * 8;
        f16x8 v;
#pragma unroll
        for (int j = 0; j < 8; ++j) {
            float x = A[(k0 + j) * 128 + nn];
            if (B) x += B[(k0 + j) * 128 + nn];
            v[j] = (_Float16)x;
        }
        *(f16x8*)(O + (size_t)t * 8) = v;
    }
}

// ---------------------------------------------------------------------------
// f16-output MFMA pass, ct-interleaved B-loads (coalesced, L2-hot; no full
// preload -> ~80 VGPR so 4 blocks/CU instead of 2). MFMA -> per-wave LDS
// stage (stride 136) -> f16x8 readback -> coalesced 16B/lane global stores.
// C layout (verified): col = lane&15, row = (lane>>4)*4 + reg.
// ---------------------------------------------------------------------------
__device__ __forceinline__ void mfma_one_B16(
    const _Float16* __restrict__ WtF, const f16x8* a, _Float16* sstage,
    int rbase, int n, int lane, _Float16* __restrict__ o16)
{
    f32x4 acc[8];
#pragma unroll
    for (int ct = 0; ct < 8; ++ct) acc[ct] = (f32x4){0.f, 0.f, 0.f, 0.f};
#pragma unroll
    for (int ct = 0; ct < 8; ++ct) {
        f16x8 b0 = *(const f16x8*)(WtF + (size_t)((ct * 4 + 0) * 64 + lane) * 8);
        f16x8 b1 = *(const f16x8*)(WtF + (size_t)((ct * 4 + 1) * 64 + lane) * 8);
        f16x8 b2 = *(const f16x8*)(WtF + (size_t)((ct * 4 + 2) * 64 + lane) * 8);
        f16x8 b3 = *(const f16x8*)(WtF + (size_t)((ct * 4 + 3) * 64 + lane) * 8);
        acc[ct] = __builtin_amdgcn_mfma_f32_16x16x32_f16(a[0], b0, acc[ct], 0, 0, 0);
        acc[ct] = __builtin_amdgcn_mfma_f32_16x16x32_f16(a[1], b1, acc[ct], 0, 0, 0);
        acc[ct] = __builtin_amdgcn_mfma_f32_16x16x32_f16(a[2], b2, acc[ct], 0, 0, 0);
        acc[ct] = __builtin_amdgcn_mfma_f32_16x16x32_f16(a[3], b3, acc[ct], 0, 0, 0);
    }

    const int rl = (lane >> 4) * 4;      // local row base for C-frag
    const int cb = lane & 15;
#pragma unroll
    for (int ct = 0; ct < 8; ++ct)
#pragma unroll
        for (int e = 0; e < 4; ++e)
            sstage[(rl + e) * SSTR + ct * 16 + cb] = (_Float16)acc[ct][e];

#pragma unroll
    for (int i = 0; i < 4; ++i) {
        int lr = i * 4 + (lane >> 4);
        int r = rbase + lr;
        if (r < n) {
            f16x8 v = *(const f16x8*)(sstage + lr * SSTR + cb * 8);
            *(f16x8*)(o16 + ((size_t)r << 7) + cb * 8) = v;
        }
    }
}

// f32-output pass (R_pf only, 6% of tiles): scalar stores, no staging.
__device__ __forceinline__ void mfma_one_B32(
    const _Float16* __restrict__ WtF, const f16x8* a,
    int rbase, int n, int lane, float* __restrict__ o32)
{
    f32x4 acc[8];
#pragma unroll
    for (int ct = 0; ct < 8; ++ct) acc[ct] = (f32x4){0.f, 0.f, 0.f, 0.f};
#pragma unroll
    for (int ct = 0; ct < 8; ++ct) {
        f16x8 b0 = *(const f16x8*)(WtF + (size_t)((ct * 4 + 0) * 64 + lane) * 8);
        f16x8 b1 = *(const f16x8*)(WtF + (size_t)((ct * 4 + 1) * 64 + lane) * 8);
        f16x8 b2 = *(const f16x8*)(WtF + (size_t)((ct * 4 + 2) * 64 + lane) * 8);
        f16x8 b3 = *(const f16x8*)(WtF + (size_t)((ct * 4 + 3) * 64 + lane) * 8);
        acc[ct] = __builtin_amdgcn_mfma_f32_16x16x32_f16(a[0], b0, acc[ct], 0, 0, 0);
        acc[ct] = __builtin_amdgcn_mfma_f32_16x16x32_f16(a[1], b1, acc[ct], 0, 0, 0);
        acc[ct] = __builtin_amdgcn_mfma_f32_16x16x32_f16(a[2], b2, acc[ct], 0, 0, 0);
        acc[ct] = __builtin_amdgcn_mfma_f32_16x16x32_f16(a[3], b3, acc[ct], 0, 0, 0);
    }
    const int rowb = rbase + (lane >> 4) * 4;
    const int bcol = lane & 15;
#pragma unroll
    for (int ct = 0; ct < 8; ++ct) {
        const int col = ct * 16 + bcol;
#pragma unroll
        for (int e = 0; e < 4; ++e) {
            int r = rowb + e;
            if (r < n) o32[((size_t)r << 7) + col] = acc[ct][e];
        }
    }
}

// ---------------------------------------------------------------------------
// Merged dispatch: blocks [0,TH_HIST_BLKS) do the bucket histogram; the rest
// do the unified MFMA transforms. launch_bounds(256,4): 16 waves/CU.
// ---------------------------------------------------------------------------
__global__ __launch_bounds__(256, 4) void trans_hist_kernel(
    const float* __restrict__ x_pfas, const float* __restrict__ x_gw,
    const float* __restrict__ x_sw,
    const _Float16* __restrict__ WtF_pg, const _Float16* __restrict__ WtF_ps,
    const _Float16* __restrict__ WtFR_pf,
    const _Float16* __restrict__ WtF_gp, const _Float16* __restrict__ WtFR_gw,
    const _Float16* __restrict__ WtF_sp, const _Float16* __restrict__ WtFR_sw,
    _Float16* __restrict__ bufT_pg, _Float16* __restrict__ bufT_ps,
    float* __restrict__ R_pf,
    _Float16* __restrict__ bufT_gp, _Float16* __restrict__ R_gw,
    _Float16* __restrict__ bufT_sp, _Float16* __restrict__ R_sw,
    const int* __restrict__ d_pg, const int* __restrict__ d_ps,
    const int* __restrict__ d_gp, const int* __restrict__ d_sp,
    int* __restrict__ bucketCounts)
{
    __shared__ char smem[4 * 16 * SSTR * 2];   // 17408 B; hist reuses 2660 B
    const int tid = threadIdx.x;

    if (blockIdx.x < TH_HIST_BLKS) {
        int* hist = (int*)smem;
        for (int i = tid; i < NB; i += 256) hist[i] = 0;
        __syncthreads();
        for (int e = blockIdx.x * 256 + tid; e < E_TOT; e += TH_HIST_BLKS * 256) {
            int idx;
            if (e < E_PG)                    idx = BASE_PG + d_pg[e];
            else if (e < E_PG + E_PS)        idx = BASE_PS + d_ps[e - E_PG];
            else if (e < E_PG + E_PS + E_GP) idx = BASE_GP + d_gp[e - E_PG - E_PS];
            else                             idx = BASE_SP + d_sp[e - E_PG - E_PS - E_GP];
            atomicAdd(&hist[idx >> 8], 1);
        }
        __syncthreads();
        for (int i = tid; i < NB; i += 256) {
            int c = hist[i];
            if (c) atomicAdd(&bucketCounts[i], c);
        }
        return;
    }

    const int b = blockIdx.x - TH_HIST_BLKS;
    int mode, tile, n; const float* X;
    if (b < T64_PF)               { mode = 0; tile = b;                    X = x_pfas; n = N_PFAS; }
    else if (b < T64_PF + T64_GW) { mode = 1; tile = b - T64_PF;           X = x_gw;   n = N_GW; }
    else                          { mode = 2; tile = b - T64_PF - T64_GW;  X = x_sw;   n = N_SW; }
    const int lane = tid & 63;
    const int w    = tid >> 6;
    const int rbase = tile * 64 + w * 16;
    const int rA = rbase + (lane & 15);
    const int ko = (lane >> 4) * 8;
    _Float16* sstage = (_Float16*)smem + (size_t)w * 16 * SSTR;

    f16x8 a[4];
#pragma unroll
    for (int ks = 0; ks < 4; ++ks) {
        float4 x0 = make_float4(0.f, 0.f, 0.f, 0.f), x1 = x0;
        if (rA < n) {
            const float* xp = X + ((size_t)rA << 7) + ks * 32 + ko;
            x0 = *(const float4*)xp;
            x1 = *(const float4*)(xp + 4);
        }
        f16x8 v;
        v[0] = (_Float16)x0.x; v[1] = (_Float16)x0.y; v[2] = (_Float16)x0.z; v[3] = (_Float16)x0.w;
        v[4] = (_Float16)x1.x; v[5] = (_Float16)x1.y; v[6] = (_Float16)x1.z; v[7] = (_Float16)x1.w;
        a[ks] = v;
    }
    if (mode == 0) {
        mfma_one_B16(WtF_pg,  a, sstage, rbase, n, lane, bufT_pg);
        mfma_one_B16(WtF_ps,  a, sstage, rbase, n, lane, bufT_ps);
        mfma_one_B32(WtFR_pf, a, rbase, n, lane, R_pf);
    } else if (mode == 1) {
        mfma_one_B16(WtF_gp,  a, sstage, rbase, n, lane, bufT_gp);
        mfma_one_B16(WtFR_gw, a, sstage, rbase, n, lane, R_gw);
    } else {
        mfma_one_B16(WtF_sp,  a, sstage, rbase, n, lane, bufT_sp);
        mfma_one_B16(WtFR_sw, a, sstage, rbase, n, lane, R_sw);
    }
}

// ---------------------------------------------------------------------------
// Merged gather dispatch: GEMM-free, LDS-free, barrier-free.
//  blocks [0, GW+SW): gw/sw node pass, 32 nodes/block -> 2 rows per 32-lane
//  group (halved serial chain vs round 6's 4).
//  blocks [GW+SW, +2*SEGP): pfas seg contributions (gp then sp), 1 node/group
// ---------------------------------------------------------------------------
__global__ __launch_bounds__(512, 8) void gather_all_kernel(
    const _Float16* __restrict__ R_gw, const _Float16* __restrict__ R_sw,
    const float* __restrict__ bl_pg, const float* __restrict__ bl_ps,
    const unsigned short* __restrict__ bufT_pg,
    const unsigned short* __restrict__ bufT_ps,
    const unsigned short* __restrict__ bufT_gp,
    const unsigned short* __restrict__ bufT_sp,
    const int* __restrict__ perm, const int* __restrict__ off_all,
    const float* __restrict__ W_gw, const float* __restrict__ b_gw,
    const float* __restrict__ W_sw, const float* __restrict__ b_sw,
    float* __restrict__ o_gw, float* __restrict__ o_sw,
    float* __restrict__ contrib_gp, float* __restrict__ contrib_sp)
{
    const int b = blockIdx.x;
    const int tid = threadIdx.x;
    const int tx = tid & 31;
    const int g = tid >> 5;

    if (b < GW_BLKS + SW_BLKS) {
        int n; const _Float16* R; const float* bl; const unsigned short* bufT16;
        const int* off; const float* wout; const float* bout; float* out; int tile;
        if (b < GW_BLKS) {
            n = N_GW; R = R_gw; bl = bl_pg; bufT16 = bufT_pg; off = off_all + BASE_PG;
            wout = W_gw; bout = b_gw; out = o_gw; tile = b;
        } else {
            n = N_SW; R = R_sw; bl = bl_ps; bufT16 = bufT_ps; off = off_all + BASE_PS;
            wout = W_sw; bout = b_sw; out = o_sw; tile = b - GW_BLKS;
        }
        const int rbase = tile * 32 + g * 2;
        float4 bv = ((const float4*)bl)[tx];
        float4 wo = ((const float4*)wout)[tx];
        float bo = bout[0];
#pragma unroll
        for (int rr = 0; rr < 2; ++rr) {
            int r = rbase + rr;
            int lo = 0, hi = 0;
            if (r < n) { lo = off[r]; hi = off[r + 1]; }
            h2_t tl, th;
            gather_sum_f16(bufT16, perm, lo, hi, tx, tl, th);
            float4 rf = make_float4(0.f, 0.f, 0.f, 0.f);
            if (r < n) {
                uint2 rv = *(const uint2*)((const unsigned short*)R + ((size_t)r << 7) + tx * 4);
                h2_t r01 = u2h2(rv.x), r23 = u2h2(rv.y);
                rf = make_float4((float)r01.x, (float)r01.y, (float)r23.x, (float)r23.y);
            }
            float inv = 1.0f / fmaxf((float)(hi - lo), 1.0f);
            float h0  = fmaxf(rf.x + bv.x + (float)tl.x * inv, 0.f);
            float h1  = fmaxf(rf.y + bv.y + (float)tl.y * inv, 0.f);
            float h2v = fmaxf(rf.z + bv.z + (float)th.x * inv, 0.f);
            float h3  = fmaxf(rf.w + bv.w + (float)th.y * inv, 0.f);
            float pv = h0 * wo.x + h1 * wo.y + h2v * wo.z + h3 * wo.w;
            pv += __shfl_xor(pv, 1, 32);
            pv += __shfl_xor(pv, 2, 32);
            pv += __shfl_xor(pv, 4, 32);
            pv += __shfl_xor(pv, 8, 32);
            pv += __shfl_xor(pv, 16, 32);
            if (tx == 0 && r < n) out[r] = pv + bo;
        }
    } else {
        const int b2 = b - (GW_BLKS + SW_BLKS);
        const unsigned short* bufT; const int* off; float* contrib; int node;
        if (b2 < SEGP_BLKS) {
            bufT = bufT_gp; off = off_all + BASE_GP; contrib = contrib_gp; node = b2 * 16 + g;
        } else {
            bufT = bufT_sp; off = off_all + BASE_SP; contrib = contrib_sp; node = (b2 - SEGP_BLKS) * 16 + g;
        }
        int lo = off[node], hi = off[node + 1];
        h2_t tl, th;
        gather_sum_f16(bufT, perm, lo, hi, tx, tl, th);
        float inv = 1.0f / fmaxf((float)(hi - lo), 1.0f);
        float4 o;
        o.x = (float)tl.x * inv; o.y = (float)tl.y * inv;
        o.z = (float)th.x * inv; o.w = (float)th.y * inv;
        ((float4*)contrib)[(size_t)node * 32 + tx] = o;
    }
}

// ---------------------------------------------------------------------------
// pfas finalize: h_pf = relu(R_pf + contrib_gp + contrib_sp + bl_gp + bl_sp)
// ---------------------------------------------------------------------------
__global__ __launch_bounds__(256) void pf_final_kernel(
    const float* __restrict__ R_pf,
    const float* __restrict__ contrib_gp, const float* __restrict__ contrib_sp,
    const float* __restrict__ blG, const float* __restrict__ blS,
    float* __restrict__ out)
{
    int t = blockIdx.x * 256 + threadIdx.x;   // over N_PFAS*32 float4 lanes
    if (t >= N_PFAS * 32) return;
    int c4 = t & 31;
    float4 b1 = ((const float4*)blG)[c4];
    float4 b2 = ((const float4*)blS)[c4];
    float4 rv = ((const float4*)R_pf)[t];
    float4 cg = ((const float4*)contrib_gp)[t];
    float4 cs = ((const float4*)contrib_sp)[t];
    float4 o;
    o.x = fmaxf(rv.x + cg.x + cs.x + b1.x + b2.x, 0.f);
    o.y = fmaxf(rv.y + cg.y + cs.y + b1.y + b2.y, 0.f);
    o.z = fmaxf(rv.z + cg.z + cs.z + b1.z + b2.z, 0.f);
    o.w = fmaxf(rv.w + cg.w + cs.w + b1.w + b2.w, 0.f);
    ((float4*)out)[t] = o;
}

// ---------------------------------------------------------------------------
// Single-block exclusive scan over the 665 bucket counts. Seeds gcursor.
// ---------------------------------------------------------------------------
__global__ __launch_bounds__(1024) void bucket_scan_kernel(
    const int* __restrict__ bucketCounts, int* __restrict__ bucketOff,
    int* __restrict__ gcursor, int* __restrict__ off_all)
{
    __shared__ int sp[1024];
    const int t = threadIdx.x;
    int v = (t < NB) ? bucketCounts[t] : 0;
    sp[t] = v;
    __syncthreads();
    for (int ofs = 1; ofs < 1024; ofs <<= 1) {
        int add = (t >= ofs) ? sp[t - ofs] : 0;
        __syncthreads();
        sp[t] += add;
        __syncthreads();
    }
    if (t < NB) {
        int excl = sp[t] - v;
        bucketOff[t] = excl;
        gcursor[t] = excl;
    }
    if (t == 0) { bucketOff[NB] = E_TOT; off_all[NTOT] = E_TOT; }
}

// ---------------------------------------------------------------------------
// Pass 1: bin edges into 256-node buckets. 512 threads, 8 edges/thread.
// Packed: (idx&255)|(src<<8).
// ---------------------------------------------------------------------------
__global__ __launch_bounds__(512) void bin_kernel(
    const int* __restrict__ s_pg, const int* __restrict__ d_pg,
    const int* __restrict__ s_ps, const int* __restrict__ d_ps,
    const int* __restrict__ s_gp, const int* __restrict__ d_gp,
    const int* __restrict__ s_sp, const int* __restrict__ d_sp,
    int* __restrict__ gcursor, unsigned* __restrict__ pairs)
{
    __shared__ int hist[NB];
    __shared__ int chunkBase[NB];
    const int tid = threadIdx.x;
    for (int i = tid; i < NB; i += 512) hist[i] = 0;
    __syncthreads();

    const int base = blockIdx.x * BIN_EPB;
    int bkt[BIN_EPT], rnk[BIN_EPT];
    unsigned pk[BIN_EPT];
#pragma unroll
    for (int k = 0; k < BIN_EPT; ++k) {
        int e = base + k * 512 + tid;
        int idx = -1, src = 0;
        if (e < E_PG) { idx = BASE_PG + d_pg[e]; src = s_pg[e]; }
        else if (e < E_PG + E_PS) { int i2 = e - E_PG; idx = BASE_PS + d_ps[i2]; src = s_ps[i2]; }
        else if (e < E_PG + E_PS + E_GP) { int i2 = e - E_PG - E_PS; idx = BASE_GP + d_gp[i2]; src = s_gp[i2]; }
        else if (e < E_TOT) { int i2 = e - E_PG - E_PS - E_GP; idx = BASE_SP + d_sp[i2]; src = s_sp[i2]; }
        if (idx >= 0) {
            int b = idx >> 8;
            bkt[k] = b;
            rnk[k] = atomicAdd(&hist[b], 1);
            pk[k] = (unsigned)(idx & 255) | ((unsigned)src << 8);
        } else bkt[k] = -1;
    }
    __syncthreads();
    for (int i = tid; i < NB; i += 512) {
        int c = hist[i];
        chunkBase[i] = c ? atomicAdd(&gcursor[i], c) : 0;
    }
    __syncthreads();
#pragma unroll
    for (int k = 0; k < BIN_EPT; ++k)
        if (bkt[k] >= 0) pairs[chunkBase[bkt[k]] + rnk[k]] = pk[k];
}

// ---------------------------------------------------------------------------
// Pass 2: one 512-thread block per bucket. Per-node counts from pairs via
// LDS atomics, LDS scan -> off_all, scatter into LDS segment, stream out.
// ---------------------------------------------------------------------------
__global__ __launch_bounds__(512) void unbin_kernel(
    const unsigned* __restrict__ pairs, const int* __restrict__ bucketOff,
    int* __restrict__ off_all, int* __restrict__ perm_all)
{
    __shared__ int sPerm[SEG_CAP];
    __shared__ int cnt[256];
    __shared__ int sp[256];
    __shared__ int cur[256];
    const int b = blockIdx.x;
    const int nb0 = b << 8;
    const int nb1 = min(nb0 + 256, NTOT);
    const int tid = threadIdx.x;
    const int base = bucketOff[b];
    const int end  = bucketOff[b + 1];
    const int len = end - base;

    if (tid < 256) cnt[tid] = 0;
    __syncthreads();
    for (int i = base + tid; i < end; i += 512)
        atomicAdd(&cnt[pairs[i] & 255u], 1);
    __syncthreads();
    int v = (tid < 256) ? cnt[tid] : 0;
    if (tid < 256) sp[tid] = v;
    __syncthreads();
    for (int ofs = 1; ofs < 256; ofs <<= 1) {
        int add = (tid < 256 && tid >= ofs) ? sp[tid - ofs] : 0;
        __syncthreads();
        if (tid < 256) sp[tid] += add;
        __syncthreads();
    }
    if (tid < 256) {
        int excl = sp[tid] - v;
        cur[tid] = excl;
        if (nb0 + tid < nb1) off_all[nb0 + tid] = base + excl;
    }
    __syncthreads();

    if (len <= SEG_CAP) {
        for (int i = base + tid; i < end; i += 512) {
            unsigned p = pairs[i];
            int pos = atomicAdd(&cur[p & 255u], 1);
            sPerm[pos] = (int)(p >> 8);
        }
        __syncthreads();
        for (int i = tid; i < len; i += 512)
            perm_all[base + i] = sPerm[i];
    } else {
        for (int i = base + tid; i < end; i += 512) {
            unsigned p = pairs[i];
            int pos = atomicAdd(&cur[p & 255u], 1);
            perm_all[base + pos] = (int)(p >> 8);
        }
    }
}

// ---------------------------------------------------------------------------
// Launch
// ---------------------------------------------------------------------------
extern "C" void kernel_launch(void* const* d_in, const int* in_sizes, int n_in,
                              void* d_out, int out_size, void* d_ws, size_t ws_size,
                              hipStream_t stream)
{
    const float* x_pfas = (const float*)d_in[0];
    const float* x_gw   = (const float*)d_in[1];
    const float* x_sw   = (const float*)d_in[2];
    const int* ei_pg_src = (const int*)d_in[3];
    const int* ei_pg_dst = (const int*)d_in[4];
    const int* ei_gp_src = (const int*)d_in[5];
    const int* ei_gp_dst = (const int*)d_in[6];
    const int* ei_ps_src = (const int*)d_in[7];
    const int* ei_ps_dst = (const int*)d_in[8];
    const int* ei_sp_src = (const int*)d_in[9];
    const int* ei_sp_dst = (const int*)d_in[10];
    const float* Wl_pg = (const float*)d_in[11];
    const float* bl_pg = (const float*)d_in[12];
    const float* Wr_pg = (const float*)d_in[13];
    const float* Wl_gp = (const float*)d_in[14];
    const float* bl_gp = (const float*)d_in[15];
    const float* Wr_gp = (const float*)d_in[16];
    const float* Wl_ps = (const float*)d_in[17];
    const float* bl_ps = (const float*)d_in[18];
    const float* Wr_ps = (const float*)d_in[19];
    const float* Wl_sp = (const float*)d_in[20];
    const float* bl_sp = (const float*)d_in[21];
    const float* Wr_sp = (const float*)d_in[22];
    const float* W_gw = (const float*)d_in[23];
    const float* b_gw = (const float*)d_in[24];
    const float* W_sw = (const float*)d_in[25];
    const float* b_sw = (const float*)d_in[26];

    float* out  = (float*)d_out;
    float* h_pf = out;                         // 20000*128
    float* o_gw = out + (size_t)N_PFAS * 128;  // 100000
    float* o_sw = o_gw + N_GW;                 // 30000

    // ---- workspace layout (~130 MB) ----
    char* p = (char*)d_ws;
    auto alloc = [&](size_t bytes) { char* q = p; p += (bytes + 15) & ~(size_t)15; return q; };
    unsigned short* bufT_pg = (unsigned short*)alloc((size_t)N_PFAS * 128 * 2);
    unsigned short* bufT_ps = (unsigned short*)alloc((size_t)N_PFAS * 128 * 2);
    unsigned short* bufT_gp = (unsigned short*)alloc((size_t)N_GW * 128 * 2);
    unsigned short* bufT_sp = (unsigned short*)alloc((size_t)N_SW * 128 * 2);
    _Float16* R_gw = (_Float16*)alloc((size_t)N_GW * 128 * 2);
    _Float16* R_sw = (_Float16*)alloc((size_t)N_SW * 128 * 2);
    float* R_pf = (float*)alloc((size_t)N_PFAS * 128 * 4);
    float* contrib_gp = (float*)alloc((size_t)N_PFAS * 128 * 4);
    float* contrib_sp = (float*)alloc((size_t)N_PFAS * 128 * 4);
    int* perm_all   = (int*)alloc((size_t)E_TOT * 4);
    unsigned* pairs = (unsigned*)alloc((size_t)E_TOT * 4);
    int* off_all    = (int*)alloc((size_t)(NTOT + 1) * 4);
    int* bucketCounts = (int*)alloc((size_t)NB * 4);
    int* bucketOff    = (int*)alloc((size_t)(NB + 1) * 4);
    int* gcursor    = (int*)alloc((size_t)NB * 4);
    _Float16* WtF_pg  = (_Float16*)alloc(16384 * 2);
    _Float16* WtF_ps  = (_Float16*)alloc(16384 * 2);
    _Float16* WtFR_pf = (_Float16*)alloc(16384 * 2);
    _Float16* WtF_gp  = (_Float16*)alloc(16384 * 2);
    _Float16* WtFR_gw = (_Float16*)alloc(16384 * 2);
    _Float16* WtF_sp  = (_Float16*)alloc(16384 * 2);
    _Float16* WtFR_sw = (_Float16*)alloc(16384 * 2);

    // ---- 1. weight prep (+ bucketCounts zero) ----
    prep_wt_kernel<<<28, 256, 0, stream>>>(
        Wl_pg, Wl_ps, Wr_gp, Wr_sp, Wl_gp, Wr_pg, Wl_sp, Wr_ps,
        WtF_pg, WtF_ps, WtFR_pf, WtF_gp, WtFR_gw, WtF_sp, WtFR_sw,
        bucketCounts);

    // ---- 2. merged MFMA transforms + bucket histogram ----
    trans_hist_kernel<<<TH_HIST_BLKS + T64_ALL, 256, 0, stream>>>(
        x_pfas, x_gw, x_sw,
        WtF_pg, WtF_ps, WtFR_pf, WtF_gp, WtFR_gw, WtF_sp, WtFR_sw,
        (_Float16*)bufT_pg, (_Float16*)bufT_ps, R_pf,
        (_Float16*)bufT_gp, R_gw, (_Float16*)bufT_sp, R_sw,
        ei_pg_dst, ei_ps_dst, ei_gp_dst, ei_sp_dst, bucketCounts);

    // ---- 3. CSR build: scan -> bin -> unbin ----
    bucket_scan_kernel<<<1, 1024, 0, stream>>>(
        bucketCounts, bucketOff, gcursor, off_all);
    bin_kernel<<<BIN_NBLK, 512, 0, stream>>>(
        ei_pg_src, ei_pg_dst, ei_ps_src, ei_ps_dst,
        ei_gp_src, ei_gp_dst, ei_sp_src, ei_sp_dst, gcursor, pairs);
    unbin_kernel<<<NB, 512, 0, stream>>>(pairs, bucketOff, off_all, perm_all);

    // ---- 4. merged gather dispatch: gw/sw node passes + pfas seg contribs ----
    gather_all_kernel<<<GW_BLKS + SW_BLKS + 2 * SEGP_BLKS, 512, 0, stream>>>(
        R_gw, R_sw, bl_pg, bl_ps, bufT_pg, bufT_ps, bufT_gp, bufT_sp,
        perm_all, off_all, W_gw, b_gw, W_sw, b_sw, o_gw, o_sw,
        contrib_gp, contrib_sp);

    // ---- 5. pfas finalize ----
    pf_final_kernel<<<(N_PFAS * 32 + 255) / 256, 256, 0, stream>>>(
        R_pf, contrib_gp, contrib_sp, bl_gp, bl_sp, h_pf);
}

// Round 8
// 351.597 us; speedup vs baseline: 1.7997x; 1.0194x over previous
//
#include <hip/hip_runtime.h>

// ---------------------------------------------------------------------------
// Problem constants
// ---------------------------------------------------------------------------
#define N_PFAS 20000
#define N_GW   100000
#define N_SW   30000
#define E_PG   1600000
#define E_GP   640000
#define E_PS   480000
#define E_SP   320000
#define E_TOT  (E_PG + E_PS + E_GP + E_SP)
// Concatenated node-count layout: [pg: N_GW][ps: N_SW][gp: N_PFAS][sp: N_PFAS]
#define BASE_PG 0
#define BASE_PS (N_GW)
#define BASE_GP (N_GW + N_SW)
#define BASE_SP (N_GW + N_SW + N_PFAS)
#define NTOT    (N_GW + N_SW + 2 * N_PFAS)
// Bucketed permute: 256 nodes per bucket; FIXED-CAPACITY pair regions so bin
// needs no pre-scan (its gcursor atomics produce the bucket counts).
#define NB        ((NTOT + 255) / 256)       // 665
#define SEG_CAP   9216                       // max bucket ~8.5K (gp: 32/node)
#define BIN_EPT   12
#define BIN_EPB   (256 * BIN_EPT)            // 3072 edges/block
#define BIN_NBLK  ((E_TOT + BIN_EPB - 1) / BIN_EPB)   // 990
// MFMA transform tiles (64 rows each)
#define T64_PF ((N_PFAS + 63) / 64)          // 313
#define T64_GW ((N_GW + 63) / 64)            // 1563
#define T64_SW ((N_SW + 63) / 64)            // 469
#define T64_ALL (T64_PF + T64_GW + T64_SW)
// Merged gather dispatch: gw/sw 32 nodes/block (2 rows/group), segs 16/block
#define GW_BLKS   ((N_GW + 31) / 32)         // 3125
#define SW_BLKS   ((N_SW + 31) / 32)         // 938
#define SEGP_BLKS (N_PFAS / 16)              // 1250  (1 node/group, exact)
// LDS stage stride (f16 elems): 136 = 272B, 16B-aligned rows, 4-way max conflict
#define SSTR 136

// ---------------------------------------------------------------------------
// f16 helpers
// ---------------------------------------------------------------------------
typedef _Float16 h2_t  __attribute__((ext_vector_type(2)));
typedef _Float16 f16x8 __attribute__((ext_vector_type(8)));
typedef float    f32x4 __attribute__((ext_vector_type(4)));
union HU { unsigned u; h2_t h; };
__device__ __forceinline__ h2_t u2h2(unsigned u) { HU x; x.u = u; return x.h; }

// ---------------------------------------------------------------------------
// 16B/lane gather-sum: 16 lanes cover a full 256B row (2 edges per load
// instruction -> half the VMEM instructions of the 8B/lane version). Lane
// (cx,half) accumulates channels 8cx..8cx+7 over edges of parity `half`;
// a shfl_xor(16) merge at the end combines both halves into every lane.
// ---------------------------------------------------------------------------
__device__ __forceinline__ void gather_sum16(
    const unsigned short* __restrict__ bufT16, const int* __restrict__ perm,
    int lo, int hi, int cx, int half,
    h2_t& A0, h2_t& A1, h2_t& A2, h2_t& A3)
{
    h2_t hz; hz.x = (_Float16)0.f; hz.y = (_Float16)0.f;
    h2_t a0 = hz, a1 = hz, a2 = hz, a3 = hz;
    h2_t b0 = hz, b1 = hz, b2 = hz, b3 = hz;
    const int co = cx * 8;                 // short offset within row (16B)
    int i = lo;
    for (; i + 12 <= hi; i += 12) {
        uint4 v0 = *(const uint4*)(bufT16 + (size_t)perm[i +  0 + half] * 128 + co);
        uint4 v1 = *(const uint4*)(bufT16 + (size_t)perm[i +  2 + half] * 128 + co);
        uint4 v2 = *(const uint4*)(bufT16 + (size_t)perm[i +  4 + half] * 128 + co);
        uint4 v3 = *(const uint4*)(bufT16 + (size_t)perm[i +  6 + half] * 128 + co);
        uint4 v4 = *(const uint4*)(bufT16 + (size_t)perm[i +  8 + half] * 128 + co);
        uint4 v5 = *(const uint4*)(bufT16 + (size_t)perm[i + 10 + half] * 128 + co);
        a0 += u2h2(v0.x); a1 += u2h2(v0.y); a2 += u2h2(v0.z); a3 += u2h2(v0.w);
        b0 += u2h2(v1.x); b1 += u2h2(v1.y); b2 += u2h2(v1.z); b3 += u2h2(v1.w);
        a0 += u2h2(v2.x); a1 += u2h2(v2.y); a2 += u2h2(v2.z); a3 += u2h2(v2.w);
        b0 += u2h2(v3.x); b1 += u2h2(v3.y); b2 += u2h2(v3.z); b3 += u2h2(v3.w);
        a0 += u2h2(v4.x); a1 += u2h2(v4.y); a2 += u2h2(v4.z); a3 += u2h2(v4.w);
        b0 += u2h2(v5.x); b1 += u2h2(v5.y); b2 += u2h2(v5.z); b3 += u2h2(v5.w);
    }
    for (; i + 2 <= hi; i += 2) {
        uint4 v = *(const uint4*)(bufT16 + (size_t)perm[i + half] * 128 + co);
        a0 += u2h2(v.x); a1 += u2h2(v.y); a2 += u2h2(v.z); a3 += u2h2(v.w);
    }
    if (i < hi && half == 0) {
        uint4 v = *(const uint4*)(bufT16 + (size_t)perm[i] * 128 + co);
        a0 += u2h2(v.x); a1 += u2h2(v.y); a2 += u2h2(v.z); a3 += u2h2(v.w);
    }
    a0 += b0; a1 += b1; a2 += b2; a3 += b3;
    // merge edge-parity halves (lane <-> lane^16); both halves end identical
    HU q, w;
    q.h = a0; w.u = (unsigned)__shfl_xor((int)q.u, 16, 32); A0 = a0 + w.h;
    q.h = a1; w.u = (unsigned)__shfl_xor((int)q.u, 16, 32); A1 = a1 + w.h;
    q.h = a2; w.u = (unsigned)__shfl_xor((int)q.u, 16, 32); A2 = a2 + w.h;
    q.h = a3; w.u = (unsigned)__shfl_xor((int)q.u, 16, 32); A3 = a3 + w.h;
}

// ---------------------------------------------------------------------------
// Weight prep (28 blocks = 7 matrices x 4 chunks): fragment-linear f16 WtF.
// Block 0 also zeroes gcursor (bin's per-bucket cursors). m==2 sums
// Wr_gp+Wr_sp (pfas HeteroConv fusion).
// ---------------------------------------------------------------------------
__global__ __launch_bounds__(256) void prep_wt_kernel(
    const float* __restrict__ Wl_pg, const float* __restrict__ Wl_ps,
    const float* __restrict__ Wr_gp, const float* __restrict__ Wr_sp,
    const float* __restrict__ Wl_gp, const float* __restrict__ Wr_pg,
    const float* __restrict__ Wl_sp, const float* __restrict__ Wr_ps,
    _Float16* __restrict__ WtF_pg, _Float16* __restrict__ WtF_ps,
    _Float16* __restrict__ WtFR_pf,
    _Float16* __restrict__ WtF_gp, _Float16* __restrict__ WtFR_gw,
    _Float16* __restrict__ WtF_sp, _Float16* __restrict__ WtFR_sw,
    int* __restrict__ gcursor)
{
    const int m = blockIdx.x >> 2;
    const int chunk = blockIdx.x & 3;
    if (blockIdx.x == 0) {
        for (int i = threadIdx.x; i < NB; i += 256) gcursor[i] = 0;
    }
    const float* A = nullptr; const float* B = nullptr; _Float16* O = nullptr;
    switch (m) {
        case 0: A = Wl_pg; O = WtF_pg;  break;
        case 1: A = Wl_ps; O = WtF_ps;  break;
        case 2: A = Wr_gp; B = Wr_sp; O = WtFR_pf; break;
        case 3: A = Wl_gp; O = WtF_gp;  break;
        case 4: A = Wr_pg; O = WtFR_gw; break;
        case 5: A = Wl_sp; O = WtF_sp;  break;
        default: A = Wr_ps; O = WtFR_sw; break;
    }
    for (int t = chunk * 512 + threadIdx.x; t < (chunk + 1) * 512; t += 256) {
        int lane = t & 63, g = t >> 6;      // g = ct*4+ks
        int ks = g & 3, ct = g >> 2;
        int nn = ct * 16 + (lane & 15);
        int k0 = ks * 32 + (lane >> 4) * 8;
        f16x8 v;
#pragma unroll
        for (int j = 0; j < 8; ++j) {
            float x = A[(k0 + j) * 128 + nn];
            if (B) x += B[(k0 + j) * 128 + nn];
            v[j] = (_Float16)x;
        }
        *(f16x8*)(O + (size_t)t * 8) = v;
    }
}

// ---------------------------------------------------------------------------
// f16-output MFMA pass, ct-interleaved B-loads; MFMA -> per-wave LDS stage
// (stride 136) -> f16x8 readback -> coalesced 16B/lane global stores.
// C layout (verified): col = lane&15, row = (lane>>4)*4 + reg.
// ---------------------------------------------------------------------------
__device__ __forceinline__ void mfma_one_B16(
    const _Float16* __restrict__ WtF, const f16x8* a, _Float16* sstage,
    int rbase, int n, int lane, _Float16* __restrict__ o16)
{
    f32x4 acc[8];
#pragma unroll
    for (int ct = 0; ct < 8; ++ct) acc[ct] = (f32x4){0.f, 0.f, 0.f, 0.f};
#pragma unroll
    for (int ct = 0; ct < 8; ++ct) {
        f16x8 b0 = *(const f16x8*)(WtF + (size_t)((ct * 4 + 0) * 64 + lane) * 8);
        f16x8 b1 = *(const f16x8*)(WtF + (size_t)((ct * 4 + 1) * 64 + lane) * 8);
        f16x8 b2 = *(const f16x8*)(WtF + (size_t)((ct * 4 + 2) * 64 + lane) * 8);
        f16x8 b3 = *(const f16x8*)(WtF + (size_t)((ct * 4 + 3) * 64 + lane) * 8);
        acc[ct] = __builtin_amdgcn_mfma_f32_16x16x32_f16(a[0], b0, acc[ct], 0, 0, 0);
        acc[ct] = __builtin_amdgcn_mfma_f32_16x16x32_f16(a[1], b1, acc[ct], 0, 0, 0);
        acc[ct] = __builtin_amdgcn_mfma_f32_16x16x32_f16(a[2], b2, acc[ct], 0, 0, 0);
        acc[ct] = __builtin_amdgcn_mfma_f32_16x16x32_f16(a[3], b3, acc[ct], 0, 0, 0);
    }

    const int rl = (lane >> 4) * 4;
    const int cb = lane & 15;
#pragma unroll
    for (int ct = 0; ct < 8; ++ct)
#pragma unroll
        for (int e = 0; e < 4; ++e)
            sstage[(rl + e) * SSTR + ct * 16 + cb] = (_Float16)acc[ct][e];

#pragma unroll
    for (int i = 0; i < 4; ++i) {
        int lr = i * 4 + (lane >> 4);
        int r = rbase + lr;
        if (r < n) {
            f16x8 v = *(const f16x8*)(sstage + lr * SSTR + cb * 8);
            *(f16x8*)(o16 + ((size_t)r << 7) + cb * 8) = v;
        }
    }
}

// f32-output pass (R_pf only, 6% of tiles): scalar stores, no staging.
__device__ __forceinline__ void mfma_one_B32(
    const _Float16* __restrict__ WtF, const f16x8* a,
    int rbase, int n, int lane, float* __restrict__ o32)
{
    f32x4 acc[8];
#pragma unroll
    for (int ct = 0; ct < 8; ++ct) acc[ct] = (f32x4){0.f, 0.f, 0.f, 0.f};
#pragma unroll
    for (int ct = 0; ct < 8; ++ct) {
        f16x8 b0 = *(const f16x8*)(WtF + (size_t)((ct * 4 + 0) * 64 + lane) * 8);
        f16x8 b1 = *(const f16x8*)(WtF + (size_t)((ct * 4 + 1) * 64 + lane) * 8);
        f16x8 b2 = *(const f16x8*)(WtF + (size_t)((ct * 4 + 2) * 64 + lane) * 8);
        f16x8 b3 = *(const f16x8*)(WtF + (size_t)((ct * 4 + 3) * 64 + lane) * 8);
        acc[ct] = __builtin_amdgcn_mfma_f32_16x16x32_f16(a[0], b0, acc[ct], 0, 0, 0);
        acc[ct] = __builtin_amdgcn_mfma_f32_16x16x32_f16(a[1], b1, acc[ct], 0, 0, 0);
        acc[ct] = __builtin_amdgcn_mfma_f32_16x16x32_f16(a[2], b2, acc[ct], 0, 0, 0);
        acc[ct] = __builtin_amdgcn_mfma_f32_16x16x32_f16(a[3], b3, acc[ct], 0, 0, 0);
    }
    const int rowb = rbase + (lane >> 4) * 4;
    const int bcol = lane & 15;
#pragma unroll
    for (int ct = 0; ct < 8; ++ct) {
        const int col = ct * 16 + bcol;
#pragma unroll
        for (int e = 0; e < 4; ++e) {
            int r = rowb + e;
            if (r < n) o32[((size_t)r << 7) + col] = acc[ct][e];
        }
    }
}

// ---------------------------------------------------------------------------
// Mega dispatch: blocks [0,BIN_NBLK) bin edges into fixed-capacity bucket
// regions of `pairs` (no pre-scan needed: gcursor atomics double as bucket
// counters); remaining blocks do the unified MFMA transforms. Independent
// work -> bin hides under trans latency, and the hist pass is gone.
// ---------------------------------------------------------------------------
__global__ __launch_bounds__(256, 4) void trans_bin_kernel(
    const float* __restrict__ x_pfas, const float* __restrict__ x_gw,
    const float* __restrict__ x_sw,
    const _Float16* __restrict__ WtF_pg, const _Float16* __restrict__ WtF_ps,
    const _Float16* __restrict__ WtFR_pf,
    const _Float16* __restrict__ WtF_gp, const _Float16* __restrict__ WtFR_gw,
    const _Float16* __restrict__ WtF_sp, const _Float16* __restrict__ WtFR_sw,
    _Float16* __restrict__ bufT_pg, _Float16* __restrict__ bufT_ps,
    float* __restrict__ R_pf,
    _Float16* __restrict__ bufT_gp, _Float16* __restrict__ R_gw,
    _Float16* __restrict__ bufT_sp, _Float16* __restrict__ R_sw,
    const int* __restrict__ s_pg, const int* __restrict__ d_pg,
    const int* __restrict__ s_ps, const int* __restrict__ d_ps,
    const int* __restrict__ s_gp, const int* __restrict__ d_gp,
    const int* __restrict__ s_sp, const int* __restrict__ d_sp,
    int* __restrict__ gcursor, unsigned* __restrict__ pairs)
{
    __shared__ char smem[4 * 16 * SSTR * 2];   // 17408 B (bin reuses 5320 B)
    const int tid = threadIdx.x;

    if (blockIdx.x < BIN_NBLK) {
        int* hist = (int*)smem;            // NB
        int* chunkBase = hist + NB;        // NB
        for (int i = tid; i < NB; i += 256) hist[i] = 0;
        __syncthreads();

        const int base = blockIdx.x * BIN_EPB;
        int bkt[BIN_EPT], rnk[BIN_EPT];
        unsigned pk[BIN_EPT];
#pragma unroll
        for (int k = 0; k < BIN_EPT; ++k) {
            int e = base + k * 256 + tid;
            int idx = -1, src = 0;
            if (e < E_PG) { idx = BASE_PG + d_pg[e]; src = s_pg[e]; }
            else if (e < E_PG + E_PS) { int i2 = e - E_PG; idx = BASE_PS + d_ps[i2]; src = s_ps[i2]; }
            else if (e < E_PG + E_PS + E_GP) { int i2 = e - E_PG - E_PS; idx = BASE_GP + d_gp[i2]; src = s_gp[i2]; }
            else if (e < E_TOT) { int i2 = e - E_PG - E_PS - E_GP; idx = BASE_SP + d_sp[i2]; src = s_sp[i2]; }
            if (idx >= 0) {
                int b = idx >> 8;
                bkt[k] = b;
                rnk[k] = atomicAdd(&hist[b], 1);
                pk[k] = (unsigned)(idx & 255) | ((unsigned)src << 8);
            } else bkt[k] = -1;
        }
        __syncthreads();
        for (int i = tid; i < NB; i += 256) {
            int c = hist[i];
            chunkBase[i] = c ? atomicAdd(&gcursor[i], c) : 0;
        }
        __syncthreads();
#pragma unroll
        for (int k = 0; k < BIN_EPT; ++k) {
            if (bkt[k] >= 0) {
                int slot = chunkBase[bkt[k]] + rnk[k];
                if (slot < SEG_CAP)
                    pairs[(size_t)bkt[k] * SEG_CAP + slot] = pk[k];
            }
        }
        return;
    }

    const int b = blockIdx.x - BIN_NBLK;
    int mode, tile, n; const float* X;
    if (b < T64_PF)               { mode = 0; tile = b;                    X = x_pfas; n = N_PFAS; }
    else if (b < T64_PF + T64_GW) { mode = 1; tile = b - T64_PF;           X = x_gw;   n = N_GW; }
    else                          { mode = 2; tile = b - T64_PF - T64_GW;  X = x_sw;   n = N_SW; }
    const int lane = tid & 63;
    const int w    = tid >> 6;
    const int rbase = tile * 64 + w * 16;
    const int rA = rbase + (lane & 15);
    const int ko = (lane >> 4) * 8;
    _Float16* sstage = (_Float16*)smem + (size_t)w * 16 * SSTR;

    f16x8 a[4];
#pragma unroll
    for (int ks = 0; ks < 4; ++ks) {
        float4 x0 = make_float4(0.f, 0.f, 0.f, 0.f), x1 = x0;
        if (rA < n) {
            const float* xp = X + ((size_t)rA << 7) + ks * 32 + ko;
            x0 = *(const float4*)xp;
            x1 = *(const float4*)(xp + 4);
        }
        f16x8 v;
        v[0] = (_Float16)x0.x; v[1] = (_Float16)x0.y; v[2] = (_Float16)x0.z; v[3] = (_Float16)x0.w;
        v[4] = (_Float16)x1.x; v[5] = (_Float16)x1.y; v[6] = (_Float16)x1.z; v[7] = (_Float16)x1.w;
        a[ks] = v;
    }
    if (mode == 0) {
        mfma_one_B16(WtF_pg,  a, sstage, rbase, n, lane, bufT_pg);
        mfma_one_B16(WtF_ps,  a, sstage, rbase, n, lane, bufT_ps);
        mfma_one_B32(WtFR_pf, a, rbase, n, lane, R_pf);
    } else if (mode == 1) {
        mfma_one_B16(WtF_gp,  a, sstage, rbase, n, lane, bufT_gp);
        mfma_one_B16(WtFR_gw, a, sstage, rbase, n, lane, R_gw);
    } else {
        mfma_one_B16(WtF_sp,  a, sstage, rbase, n, lane, bufT_sp);
        mfma_one_B16(WtFR_sw, a, sstage, rbase, n, lane, R_sw);
    }
}

// ---------------------------------------------------------------------------
// Single-block exclusive scan over the 665 bucket counts (gcursor after bin).
// ---------------------------------------------------------------------------
__global__ __launch_bounds__(1024) void bucket_scan_kernel(
    const int* __restrict__ gcursor, int* __restrict__ bucketOff,
    int* __restrict__ off_all)
{
    __shared__ int sp[1024];
    const int t = threadIdx.x;
    int v = (t < NB) ? gcursor[t] : 0;
    sp[t] = v;
    __syncthreads();
    for (int ofs = 1; ofs < 1024; ofs <<= 1) {
        int add = (t >= ofs) ? sp[t - ofs] : 0;
        __syncthreads();
        sp[t] += add;
        __syncthreads();
    }
    if (t < NB) bucketOff[t] = sp[t] - v;
    if (t == 0) { bucketOff[NB] = E_TOT; off_all[NTOT] = E_TOT; }
}

// ---------------------------------------------------------------------------
// unbin: one 512-thread block per bucket. Reads the bucket's fixed-capacity
// region of pairs; per-node counts via LDS atomics, LDS scan -> off_all,
// scatter into LDS segment, stream out compacted at bucketOff[b].
// ---------------------------------------------------------------------------
__global__ __launch_bounds__(512) void unbin_kernel(
    const unsigned* __restrict__ pairs, const int* __restrict__ bucketOff,
    int* __restrict__ off_all, int* __restrict__ perm_all)
{
    __shared__ int sPerm[SEG_CAP];
    __shared__ int cnt[256];
    __shared__ int sp[256];
    __shared__ int cur[256];
    const int b = blockIdx.x;
    const int nb0 = b << 8;
    const int nb1 = min(nb0 + 256, NTOT);
    const int tid = threadIdx.x;
    const int obase = bucketOff[b];
    int len = bucketOff[b + 1] - obase;
    if (len > SEG_CAP) len = SEG_CAP;    // safety (cannot trigger by sizing)
    const unsigned* reg = pairs + (size_t)b * SEG_CAP;

    if (tid < 256) cnt[tid] = 0;
    __syncthreads();
    for (int i = tid; i < len; i += 512)
        atomicAdd(&cnt[reg[i] & 255u], 1);
    __syncthreads();
    int v = (tid < 256) ? cnt[tid] : 0;
    if (tid < 256) sp[tid] = v;
    __syncthreads();
    for (int ofs = 1; ofs < 256; ofs <<= 1) {
        int add = (tid < 256 && tid >= ofs) ? sp[tid - ofs] : 0;
        __syncthreads();
        if (tid < 256) sp[tid] += add;
        __syncthreads();
    }
    if (tid < 256) {
        int excl = sp[tid] - v;
        cur[tid] = excl;
        if (nb0 + tid < nb1) off_all[nb0 + tid] = obase + excl;
    }
    __syncthreads();

    for (int i = tid; i < len; i += 512) {
        unsigned p = reg[i];
        int pos = atomicAdd(&cur[p & 255u], 1);
        sPerm[pos] = (int)(p >> 8);
    }
    __syncthreads();
    for (int i = tid; i < len; i += 512)
        perm_all[obase + i] = sPerm[i];
}

// ---------------------------------------------------------------------------
// Merged gather dispatch: GEMM-free, LDS-free, barrier-free. 16B/lane rows.
//  blocks [0, GW+SW): gw/sw node pass, 32 nodes/block -> 2 rows/group.
//  blocks [GW+SW, +2*SEGP): pfas seg contributions (gp then sp), 1 node/group
// ---------------------------------------------------------------------------
__global__ __launch_bounds__(512, 6) void gather_all_kernel(
    const _Float16* __restrict__ R_gw, const _Float16* __restrict__ R_sw,
    const float* __restrict__ bl_pg, const float* __restrict__ bl_ps,
    const unsigned short* __restrict__ bufT_pg,
    const unsigned short* __restrict__ bufT_ps,
    const unsigned short* __restrict__ bufT_gp,
    const unsigned short* __restrict__ bufT_sp,
    const int* __restrict__ perm, const int* __restrict__ off_all,
    const float* __restrict__ W_gw, const float* __restrict__ b_gw,
    const float* __restrict__ W_sw, const float* __restrict__ b_sw,
    float* __restrict__ o_gw, float* __restrict__ o_sw,
    float* __restrict__ contrib_gp, float* __restrict__ contrib_sp)
{
    const int b = blockIdx.x;
    const int tid = threadIdx.x;
    const int tx = tid & 31;
    const int g = tid >> 5;
    const int cx = tx & 15;
    const int half = tx >> 4;

    if (b < GW_BLKS + SW_BLKS) {
        int n; const _Float16* R; const float* bl; const unsigned short* bufT16;
        const int* off; const float* wout; const float* bout; float* out; int tile;
        if (b < GW_BLKS) {
            n = N_GW; R = R_gw; bl = bl_pg; bufT16 = bufT_pg; off = off_all + BASE_PG;
            wout = W_gw; bout = b_gw; out = o_gw; tile = b;
        } else {
            n = N_SW; R = R_sw; bl = bl_ps; bufT16 = bufT_ps; off = off_all + BASE_PS;
            wout = W_sw; bout = b_sw; out = o_sw; tile = b - GW_BLKS;
        }
        const int rbase = tile * 32 + g * 2;
        float4 bv0 = ((const float4*)bl)[cx * 2];
        float4 bv1 = ((const float4*)bl)[cx * 2 + 1];
        float4 w0  = ((const float4*)wout)[cx * 2];
        float4 w1  = ((const float4*)wout)[cx * 2 + 1];
        float bo = bout[0];
#pragma unroll
        for (int rr = 0; rr < 2; ++rr) {
            int r = rbase + rr;
            int lo = 0, hi = 0;
            if (r < n) { lo = off[r]; hi = off[r + 1]; }
            h2_t A0, A1, A2, A3;
            gather_sum16(bufT16, perm, lo, hi, cx, half, A0, A1, A2, A3);
            float rf[8] = {0.f, 0.f, 0.f, 0.f, 0.f, 0.f, 0.f, 0.f};
            if (r < n) {
                uint4 rv = *(const uint4*)((const unsigned short*)R + ((size_t)r << 7) + cx * 8);
                h2_t r0 = u2h2(rv.x), r1 = u2h2(rv.y), r2 = u2h2(rv.z), r3 = u2h2(rv.w);
                rf[0] = (float)r0.x; rf[1] = (float)r0.y;
                rf[2] = (float)r1.x; rf[3] = (float)r1.y;
                rf[4] = (float)r2.x; rf[5] = (float)r2.y;
                rf[6] = (float)r3.x; rf[7] = (float)r3.y;
            }
            float inv = 1.0f / fmaxf((float)(hi - lo), 1.0f);
            float h0 = fmaxf(rf[0] + bv0.x + (float)A0.x * inv, 0.f);
            float h1 = fmaxf(rf[1] + bv0.y + (float)A0.y * inv, 0.f);
            float h2v= fmaxf(rf[2] + bv0.z + (float)A1.x * inv, 0.f);
            float h3 = fmaxf(rf[3] + bv0.w + (float)A1.y * inv, 0.f);
            float h4 = fmaxf(rf[4] + bv1.x + (float)A2.x * inv, 0.f);
            float h5 = fmaxf(rf[5] + bv1.y + (float)A2.y * inv, 0.f);
            float h6 = fmaxf(rf[6] + bv1.z + (float)A3.x * inv, 0.f);
            float h7 = fmaxf(rf[7] + bv1.w + (float)A3.y * inv, 0.f);
            float pv = h0 * w0.x + h1 * w0.y + h2v * w0.z + h3 * w0.w
                     + h4 * w1.x + h5 * w1.y + h6 * w1.z + h7 * w1.w;
            pv += __shfl_xor(pv, 1, 32);
            pv += __shfl_xor(pv, 2, 32);
            pv += __shfl_xor(pv, 4, 32);
            pv += __shfl_xor(pv, 8, 32);
            if (tx == 0 && r < n) out[r] = pv + bo;
        }
    } else {
        const int b2 = b - (GW_BLKS + SW_BLKS);
        const unsigned short* bufT; const int* off; float* contrib; int node;
        if (b2 < SEGP_BLKS) {
            bufT = bufT_gp; off = off_all + BASE_GP; contrib = contrib_gp; node = b2 * 16 + g;
        } else {
            bufT = bufT_sp; off = off_all + BASE_SP; contrib = contrib_sp; node = (b2 - SEGP_BLKS) * 16 + g;
        }
        int lo = off[node], hi = off[node + 1];
        h2_t A0, A1, A2, A3;
        gather_sum16(bufT, perm, lo, hi, cx, half, A0, A1, A2, A3);
        float inv = 1.0f / fmaxf((float)(hi - lo), 1.0f);
        if (half == 0) {
            float4 o0, o1;
            o0.x = (float)A0.x * inv; o0.y = (float)A0.y * inv;
            o0.z = (float)A1.x * inv; o0.w = (float)A1.y * inv;
            o1.x = (float)A2.x * inv; o1.y = (float)A2.y * inv;
            o1.z = (float)A3.x * inv; o1.w = (float)A3.y * inv;
            ((float4*)contrib)[(size_t)node * 32 + cx * 2]     = o0;
            ((float4*)contrib)[(size_t)node * 32 + cx * 2 + 1] = o1;
        }
    }
}

// ---------------------------------------------------------------------------
// pfas finalize: h_pf = relu(R_pf + contrib_gp + contrib_sp + bl_gp + bl_sp)
// ---------------------------------------------------------------------------
__global__ __launch_bounds__(256) void pf_final_kernel(
    const float* __restrict__ R_pf,
    const float* __restrict__ contrib_gp, const float* __restrict__ contrib_sp,
    const float* __restrict__ blG, const float* __restrict__ blS,
    float* __restrict__ out)
{
    int t = blockIdx.x * 256 + threadIdx.x;   // over N_PFAS*32 float4 lanes
    if (t >= N_PFAS * 32) return;
    int c4 = t & 31;
    float4 b1 = ((const float4*)blG)[c4];
    float4 b2 = ((const float4*)blS)[c4];
    float4 rv = ((const float4*)R_pf)[t];
    float4 cg = ((const float4*)contrib_gp)[t];
    float4 cs = ((const float4*)contrib_sp)[t];
    float4 o;
    o.x = fmaxf(rv.x + cg.x + cs.x + b1.x + b2.x, 0.f);
    o.y = fmaxf(rv.y + cg.y + cs.y + b1.y + b2.y, 0.f);
    o.z = fmaxf(rv.z + cg.z + cs.z + b1.z + b2.z, 0.f);
    o.w = fmaxf(rv.w + cg.w + cs.w + b1.w + b2.w, 0.f);
    ((float4*)out)[t] = o;
}

// ---------------------------------------------------------------------------
// Launch
// ---------------------------------------------------------------------------
extern "C" void kernel_launch(void* const* d_in, const int* in_sizes, int n_in,
                              void* d_out, int out_size, void* d_ws, size_t ws_size,
                              hipStream_t stream)
{
    const float* x_pfas = (const float*)d_in[0];
    const float* x_gw   = (const float*)d_in[1];
    const float* x_sw   = (const float*)d_in[2];
    const int* ei_pg_src = (const int*)d_in[3];
    const int* ei_pg_dst = (const int*)d_in[4];
    const int* ei_gp_src = (const int*)d_in[5];
    const int* ei_gp_dst = (const int*)d_in[6];
    const int* ei_ps_src = (const int*)d_in[7];
    const int* ei_ps_dst = (const int*)d_in[8];
    const int* ei_sp_src = (const int*)d_in[9];
    const int* ei_sp_dst = (const int*)d_in[10];
    const float* Wl_pg = (const float*)d_in[11];
    const float* bl_pg = (const float*)d_in[12];
    const float* Wr_pg = (const float*)d_in[13];
    const float* Wl_gp = (const float*)d_in[14];
    const float* bl_gp = (const float*)d_in[15];
    const float* Wr_gp = (const float*)d_in[16];
    const float* Wl_ps = (const float*)d_in[17];
    const float* bl_ps = (const float*)d_in[18];
    const float* Wr_ps = (const float*)d_in[19];
    const float* Wl_sp = (const float*)d_in[20];
    const float* bl_sp = (const float*)d_in[21];
    const float* Wr_sp = (const float*)d_in[22];
    const float* W_gw = (const float*)d_in[23];
    const float* b_gw = (const float*)d_in[24];
    const float* W_sw = (const float*)d_in[25];
    const float* b_sw = (const float*)d_in[26];

    float* out  = (float*)d_out;
    float* h_pf = out;                         // 20000*128
    float* o_gw = out + (size_t)N_PFAS * 128;  // 100000
    float* o_sw = o_gw + N_GW;                 // 30000

    // ---- workspace layout (~145 MB) ----
    char* p = (char*)d_ws;
    auto alloc = [&](size_t bytes) { char* q = p; p += (bytes + 15) & ~(size_t)15; return q; };
    unsigned short* bufT_pg = (unsigned short*)alloc((size_t)N_PFAS * 128 * 2);
    unsigned short* bufT_ps = (unsigned short*)alloc((size_t)N_PFAS * 128 * 2);
    unsigned short* bufT_gp = (unsigned short*)alloc((size_t)N_GW * 128 * 2);
    unsigned short* bufT_sp = (unsigned short*)alloc((size_t)N_SW * 128 * 2);
    _Float16* R_gw = (_Float16*)alloc((size_t)N_GW * 128 * 2);
    _Float16* R_sw = (_Float16*)alloc((size_t)N_SW * 128 * 2);
    float* R_pf = (float*)alloc((size_t)N_PFAS * 128 * 4);
    float* contrib_gp = (float*)alloc((size_t)N_PFAS * 128 * 4);
    float* contrib_sp = (float*)alloc((size_t)N_PFAS * 128 * 4);
    int* perm_all   = (int*)alloc((size_t)E_TOT * 4);
    unsigned* pairs = (unsigned*)alloc((size_t)NB * SEG_CAP * 4);   // 24.5 MB
    int* off_all    = (int*)alloc((size_t)(NTOT + 1) * 4);
    int* bucketOff  = (int*)alloc((size_t)(NB + 1) * 4);
    int* gcursor    = (int*)alloc((size_t)NB * 4);
    _Float16* WtF_pg  = (_Float16*)alloc(16384 * 2);
    _Float16* WtF_ps  = (_Float16*)alloc(16384 * 2);
    _Float16* WtFR_pf = (_Float16*)alloc(16384 * 2);
    _Float16* WtF_gp  = (_Float16*)alloc(16384 * 2);
    _Float16* WtFR_gw = (_Float16*)alloc(16384 * 2);
    _Float16* WtF_sp  = (_Float16*)alloc(16384 * 2);
    _Float16* WtFR_sw = (_Float16*)alloc(16384 * 2);

    // ---- 1. weight prep (+ gcursor zero) ----
    prep_wt_kernel<<<28, 256, 0, stream>>>(
        Wl_pg, Wl_ps, Wr_gp, Wr_sp, Wl_gp, Wr_pg, Wl_sp, Wr_ps,
        WtF_pg, WtF_ps, WtFR_pf, WtF_gp, WtFR_gw, WtF_sp, WtFR_sw,
        gcursor);

    // ---- 2. mega dispatch: MFMA transforms + edge binning ----
    trans_bin_kernel<<<BIN_NBLK + T64_ALL, 256, 0, stream>>>(
        x_pfas, x_gw, x_sw,
        WtF_pg, WtF_ps, WtFR_pf, WtF_gp, WtFR_gw, WtF_sp, WtFR_sw,
        (_Float16*)bufT_pg, (_Float16*)bufT_ps, R_pf,
        (_Float16*)bufT_gp, R_gw, (_Float16*)bufT_sp, R_sw,
        ei_pg_src, ei_pg_dst, ei_ps_src, ei_ps_dst,
        ei_gp_src, ei_gp_dst, ei_sp_src, ei_sp_dst,
        gcursor, pairs);

    // ---- 3. CSR finalize: scan -> unbin ----
    bucket_scan_kernel<<<1, 1024, 0, stream>>>(gcursor, bucketOff, off_all);
    unbin_kernel<<<NB, 512, 0, stream>>>(pairs, bucketOff, off_all, perm_all);

    // ---- 4. merged gather dispatch: gw/sw node passes + pfas seg contribs ----
    gather_all_kernel<<<GW_BLKS + SW_BLKS + 2 * SEGP_BLKS, 512, 0, stream>>>(
        R_gw, R_sw, bl_pg, bl_ps, bufT_pg, bufT_ps, bufT_gp, bufT_sp,
        perm_all, off_all, W_gw, b_gw, W_sw, b_sw, o_gw, o_sw,
        contrib_gp, contrib_sp);

    // ---- 5. pfas finalize ----
    pf_final_kernel<<<(N_PFAS * 32 + 255) / 256, 256, 0, stream>>>(
        R_pf, contrib_gp, contrib_sp, bl_gp, bl_sp, h_pf);
}

// Round 9
// 349.215 us; speedup vs baseline: 1.8120x; 1.0068x over previous
//
#include <hip/hip_runtime.h>

// ---------------------------------------------------------------------------
// Problem constants
// ---------------------------------------------------------------------------
#define N_PFAS 20000
#define N_GW   100000
#define N_SW   30000
#define E_PG   1600000
#define E_GP   640000
#define E_PS   480000
#define E_SP   320000
#define E_TOT  (E_PG + E_PS + E_GP + E_SP)
// Concatenated node-count layout: [pg: N_GW][ps: N_SW][gp: N_PFAS][sp: N_PFAS]
#define BASE_PG 0
#define BASE_PS (N_GW)
#define BASE_GP (N_GW + N_SW)
#define BASE_SP (N_GW + N_SW + N_PFAS)
#define NTOT    (N_GW + N_SW + 2 * N_PFAS)
// Bucketed permute: 256 nodes per bucket; fixed-capacity pair regions.
#define NB        ((NTOT + 255) / 256)       // 665
#define SEG_CAP   9216                       // max bucket ~8.5K (gp: 32/node)
#define BIN_EPT   12
#define BIN_EPB   (256 * BIN_EPT)            // 3072 edges/block
#define BIN_NBLK  ((E_TOT + BIN_EPB - 1) / BIN_EPB)   // 990
// MFMA transform tiles (64 rows each)
#define T64_PF ((N_PFAS + 63) / 64)          // 313
#define T64_GW ((N_GW + 63) / 64)            // 1563
#define T64_SW ((N_SW + 63) / 64)            // 469
#define T64_ALL (T64_PF + T64_GW + T64_SW)
// Merged gather dispatch: seg blocks first (fattest), then gw/sw.
#define SEGP_BLKS (N_PFAS / 16)              // 1250 (1 node/group; gp+sp+finalize)
#define GW_BLKS   ((N_GW + 31) / 32)         // 3125 (2 rows/group)
#define SW_BLKS   ((N_SW + 31) / 32)         // 938
// LDS stride (f16 elems): 136 = 272B; X-stage and C-stage union per wave.
#define SSTR 136

// ---------------------------------------------------------------------------
// f16 helpers
// ---------------------------------------------------------------------------
typedef _Float16 h2_t  __attribute__((ext_vector_type(2)));
typedef _Float16 f16x4 __attribute__((ext_vector_type(4)));
typedef _Float16 f16x8 __attribute__((ext_vector_type(8)));
typedef float    f32x4 __attribute__((ext_vector_type(4)));
union HU { unsigned u; h2_t h; };
__device__ __forceinline__ h2_t u2h2(unsigned u) { HU x; x.u = u; return x.h; }

// ---------------------------------------------------------------------------
// 8-ILP f16 gather-sum over a CSR segment (8B/lane, 32 lanes/row):
// tl = sum of channels (4tx,4tx+1), th = (4tx+2,4tx+3).
// ---------------------------------------------------------------------------
__device__ __forceinline__ void gather_sum_f16(
    const unsigned short* __restrict__ bufT16, const int* __restrict__ perm,
    int lo, int hi, int tx, h2_t& tl, h2_t& th)
{
    h2_t hz; hz.x = (_Float16)0.f; hz.y = (_Float16)0.f;
    h2_t a0 = hz, a1 = hz, a2 = hz, a3 = hz, a4 = hz, a5 = hz, a6 = hz, a7 = hz;
    int i = lo;
    for (; i + 8 <= hi; i += 8) {
        uint2 v0 = *(const uint2*)(bufT16 + (size_t)perm[i + 0] * 128 + tx * 4);
        uint2 v1 = *(const uint2*)(bufT16 + (size_t)perm[i + 1] * 128 + tx * 4);
        uint2 v2 = *(const uint2*)(bufT16 + (size_t)perm[i + 2] * 128 + tx * 4);
        uint2 v3 = *(const uint2*)(bufT16 + (size_t)perm[i + 3] * 128 + tx * 4);
        uint2 v4 = *(const uint2*)(bufT16 + (size_t)perm[i + 4] * 128 + tx * 4);
        uint2 v5 = *(const uint2*)(bufT16 + (size_t)perm[i + 5] * 128 + tx * 4);
        uint2 v6 = *(const uint2*)(bufT16 + (size_t)perm[i + 6] * 128 + tx * 4);
        uint2 v7 = *(const uint2*)(bufT16 + (size_t)perm[i + 7] * 128 + tx * 4);
        a0 += u2h2(v0.x); a1 += u2h2(v0.y);
        a2 += u2h2(v1.x); a3 += u2h2(v1.y);
        a4 += u2h2(v2.x); a5 += u2h2(v2.y);
        a6 += u2h2(v3.x); a7 += u2h2(v3.y);
        a0 += u2h2(v4.x); a1 += u2h2(v4.y);
        a2 += u2h2(v5.x); a3 += u2h2(v5.y);
        a4 += u2h2(v6.x); a5 += u2h2(v6.y);
        a6 += u2h2(v7.x); a7 += u2h2(v7.y);
    }
    for (; i + 2 <= hi; i += 2) {
        uint2 v0 = *(const uint2*)(bufT16 + (size_t)perm[i + 0] * 128 + tx * 4);
        uint2 v1 = *(const uint2*)(bufT16 + (size_t)perm[i + 1] * 128 + tx * 4);
        a0 += u2h2(v0.x); a1 += u2h2(v0.y);
        a2 += u2h2(v1.x); a3 += u2h2(v1.y);
    }
    if (i < hi) {
        uint2 v0 = *(const uint2*)(bufT16 + (size_t)perm[i] * 128 + tx * 4);
        a0 += u2h2(v0.x); a1 += u2h2(v0.y);
    }
    tl = (a0 + a2) + (a4 + a6);
    th = (a1 + a3) + (a5 + a7);
}

// ---------------------------------------------------------------------------
// Weight prep (28 blocks = 7 matrices x 4 chunks): fragment-linear f16 WtF.
// Block 0 also zeroes gcursor and writes off_all[NTOT]. m==2 sums Wr_gp+Wr_sp.
// ---------------------------------------------------------------------------
__global__ __launch_bounds__(256) void prep_wt_kernel(
    const float* __restrict__ Wl_pg, const float* __restrict__ Wl_ps,
    const float* __restrict__ Wr_gp, const float* __restrict__ Wr_sp,
    const float* __restrict__ Wl_gp, const float* __restrict__ Wr_pg,
    const float* __restrict__ Wl_sp, const float* __restrict__ Wr_ps,
    _Float16* __restrict__ WtF_pg, _Float16* __restrict__ WtF_ps,
    _Float16* __restrict__ WtFR_pf,
    _Float16* __restrict__ WtF_gp, _Float16* __restrict__ WtFR_gw,
    _Float16* __restrict__ WtF_sp, _Float16* __restrict__ WtFR_sw,
    int* __restrict__ gcursor, int* __restrict__ off_all)
{
    const int m = blockIdx.x >> 2;
    const int chunk = blockIdx.x & 3;
    if (blockIdx.x == 0) {
        for (int i = threadIdx.x; i < NB; i += 256) gcursor[i] = 0;
        if (threadIdx.x == 0) off_all[NTOT] = E_TOT;
    }
    const float* A = nullptr; const float* B = nullptr; _Float16* O = nullptr;
    switch (m) {
        case 0: A = Wl_pg; O = WtF_pg;  break;
        case 1: A = Wl_ps; O = WtF_ps;  break;
        case 2: A = Wr_gp; B = Wr_sp; O = WtFR_pf; break;
        case 3: A = Wl_gp; O = WtF_gp;  break;
        case 4: A = Wr_pg; O = WtFR_gw; break;
        case 5: A = Wl_sp; O = WtF_sp;  break;
        default: A = Wr_ps; O = WtFR_sw; break;
    }
    for (int t = chunk * 512 + threadIdx.x; t < (chunk + 1) * 512; t += 256) {
        int lane = t & 63, g = t >> 6;      // g = ct*4+ks
        int ks = g & 3, ct = g >> 2;
        int nn = ct * 16 + (lane & 15);
        int k0 = ks * 32 + (lane >> 4) * 8;
        f16x8 v;
#pragma unroll
        for (int j = 0; j < 8; ++j) {
            float x = A[(k0 + j) * 128 + nn];
            if (B) x += B[(k0 + j) * 128 + nn];
            v[j] = (_Float16)x;
        }
        *(f16x8*)(O + (size_t)t * 8) = v;
    }
}

// ---------------------------------------------------------------------------
// f16-output MFMA pass: ct-interleaved coalesced B-loads; MFMA -> per-wave
// LDS stage (stride 136, reuses the X-stage region: wave-local in-order DS)
// -> f16x8 readback -> coalesced 16B/lane global stores.
// C layout (verified): col = lane&15, row = (lane>>4)*4 + reg.
// ---------------------------------------------------------------------------
__device__ __forceinline__ void mfma_one_B16(
    const _Float16* __restrict__ WtF, const f16x8* a, _Float16* sstage,
    int rbase, int n, int lane, _Float16* __restrict__ o16)
{
    f32x4 acc[8];
#pragma unroll
    for (int ct = 0; ct < 8; ++ct) acc[ct] = (f32x4){0.f, 0.f, 0.f, 0.f};
#pragma unroll
    for (int ct = 0; ct < 8; ++ct) {
        f16x8 b0 = *(const f16x8*)(WtF + (size_t)((ct * 4 + 0) * 64 + lane) * 8);
        f16x8 b1 = *(const f16x8*)(WtF + (size_t)((ct * 4 + 1) * 64 + lane) * 8);
        f16x8 b2 = *(const f16x8*)(WtF + (size_t)((ct * 4 + 2) * 64 + lane) * 8);
        f16x8 b3 = *(const f16x8*)(WtF + (size_t)((ct * 4 + 3) * 64 + lane) * 8);
        acc[ct] = __builtin_amdgcn_mfma_f32_16x16x32_f16(a[0], b0, acc[ct], 0, 0, 0);
        acc[ct] = __builtin_amdgcn_mfma_f32_16x16x32_f16(a[1], b1, acc[ct], 0, 0, 0);
        acc[ct] = __builtin_amdgcn_mfma_f32_16x16x32_f16(a[2], b2, acc[ct], 0, 0, 0);
        acc[ct] = __builtin_amdgcn_mfma_f32_16x16x32_f16(a[3], b3, acc[ct], 0, 0, 0);
    }

    const int rl = (lane >> 4) * 4;
    const int cb = lane & 15;
#pragma unroll
    for (int ct = 0; ct < 8; ++ct)
#pragma unroll
        for (int e = 0; e < 4; ++e)
            sstage[(rl + e) * SSTR + ct * 16 + cb] = (_Float16)acc[ct][e];

#pragma unroll
    for (int i = 0; i < 4; ++i) {
        int lr = i * 4 + (lane >> 4);
        int r = rbase + lr;
        if (r < n) {
            f16x8 v = *(const f16x8*)(sstage + lr * SSTR + cb * 8);
            *(f16x8*)(o16 + ((size_t)r << 7) + cb * 8) = v;
        }
    }
}

// f32-output pass (R_pf only, 6% of tiles): scalar stores, no staging.
__device__ __forceinline__ void mfma_one_B32(
    const _Float16* __restrict__ WtF, const f16x8* a,
    int rbase, int n, int lane, float* __restrict__ o32)
{
    f32x4 acc[8];
#pragma unroll
    for (int ct = 0; ct < 8; ++ct) acc[ct] = (f32x4){0.f, 0.f, 0.f, 0.f};
#pragma unroll
    for (int ct = 0; ct < 8; ++ct) {
        f16x8 b0 = *(const f16x8*)(WtF + (size_t)((ct * 4 + 0) * 64 + lane) * 8);
        f16x8 b1 = *(const f16x8*)(WtF + (size_t)((ct * 4 + 1) * 64 + lane) * 8);
        f16x8 b2 = *(const f16x8*)(WtF + (size_t)((ct * 4 + 2) * 64 + lane) * 8);
        f16x8 b3 = *(const f16x8*)(WtF + (size_t)((ct * 4 + 3) * 64 + lane) * 8);
        acc[ct] = __builtin_amdgcn_mfma_f32_16x16x32_f16(a[0], b0, acc[ct], 0, 0, 0);
        acc[ct] = __builtin_amdgcn_mfma_f32_16x16x32_f16(a[1], b1, acc[ct], 0, 0, 0);
        acc[ct] = __builtin_amdgcn_mfma_f32_16x16x32_f16(a[2], b2, acc[ct], 0, 0, 0);
        acc[ct] = __builtin_amdgcn_mfma_f32_16x16x32_f16(a[3], b3, acc[ct], 0, 0, 0);
    }
    const int rowb = rbase + (lane >> 4) * 4;
    const int bcol = lane & 15;
#pragma unroll
    for (int ct = 0; ct < 8; ++ct) {
        const int col = ct * 16 + bcol;
#pragma unroll
        for (int e = 0; e < 4; ++e) {
            int r = rowb + e;
            if (r < n) o32[((size_t)r << 7) + col] = acc[ct][e];
        }
    }
}

// ---------------------------------------------------------------------------
// Mega dispatch: blocks [0,BIN_NBLK) bin edges into fixed-capacity bucket
// regions (gcursor atomics double as bucket counters); remaining blocks do
// the MFMA transforms with a COALESCED per-wave LDS X-stage (f32->f16 during
// staging) — removes the last 16-line divergent load pattern (A-frags).
// ---------------------------------------------------------------------------
__global__ __launch_bounds__(256, 4) void trans_bin_kernel(
    const float* __restrict__ x_pfas, const float* __restrict__ x_gw,
    const float* __restrict__ x_sw,
    const _Float16* __restrict__ WtF_pg, const _Float16* __restrict__ WtF_ps,
    const _Float16* __restrict__ WtFR_pf,
    const _Float16* __restrict__ WtF_gp, const _Float16* __restrict__ WtFR_gw,
    const _Float16* __restrict__ WtF_sp, const _Float16* __restrict__ WtFR_sw,
    _Float16* __restrict__ bufT_pg, _Float16* __restrict__ bufT_ps,
    float* __restrict__ R_pf,
    _Float16* __restrict__ bufT_gp, _Float16* __restrict__ R_gw,
    _Float16* __restrict__ bufT_sp, _Float16* __restrict__ R_sw,
    const int* __restrict__ s_pg, const int* __restrict__ d_pg,
    const int* __restrict__ s_ps, const int* __restrict__ d_ps,
    const int* __restrict__ s_gp, const int* __restrict__ d_gp,
    const int* __restrict__ s_sp, const int* __restrict__ d_sp,
    int* __restrict__ gcursor, unsigned* __restrict__ pairs)
{
    __shared__ char smem[4 * 16 * SSTR * 2];   // 17408 B (bin reuses 5320 B)
    const int tid = threadIdx.x;

    if (blockIdx.x < BIN_NBLK) {
        int* hist = (int*)smem;            // NB
        int* chunkBase = hist + NB;        // NB
        for (int i = tid; i < NB; i += 256) hist[i] = 0;
        __syncthreads();

        const int base = blockIdx.x * BIN_EPB;
        int bkt[BIN_EPT], rnk[BIN_EPT];
        unsigned pk[BIN_EPT];
#pragma unroll
        for (int k = 0; k < BIN_EPT; ++k) {
            int e = base + k * 256 + tid;
            int idx = -1, src = 0;
            if (e < E_PG) { idx = BASE_PG + d_pg[e]; src = s_pg[e]; }
            else if (e < E_PG + E_PS) { int i2 = e - E_PG; idx = BASE_PS + d_ps[i2]; src = s_ps[i2]; }
            else if (e < E_PG + E_PS + E_GP) { int i2 = e - E_PG - E_PS; idx = BASE_GP + d_gp[i2]; src = s_gp[i2]; }
            else if (e < E_TOT) { int i2 = e - E_PG - E_PS - E_GP; idx = BASE_SP + d_sp[i2]; src = s_sp[i2]; }
            if (idx >= 0) {
                int b = idx >> 8;
                bkt[k] = b;
                rnk[k] = atomicAdd(&hist[b], 1);
                pk[k] = (unsigned)(idx & 255) | ((unsigned)src << 8);
            } else bkt[k] = -1;
        }
        __syncthreads();
        for (int i = tid; i < NB; i += 256) {
            int c = hist[i];
            chunkBase[i] = c ? atomicAdd(&gcursor[i], c) : 0;
        }
        __syncthreads();
#pragma unroll
        for (int k = 0; k < BIN_EPT; ++k) {
            if (bkt[k] >= 0) {
                int slot = chunkBase[bkt[k]] + rnk[k];
                if (slot < SEG_CAP)
                    pairs[(size_t)bkt[k] * SEG_CAP + slot] = pk[k];
            }
        }
        return;
    }

    const int b = blockIdx.x - BIN_NBLK;
    int mode, tile, n; const float* X;
    if (b < T64_PF)               { mode = 0; tile = b;                    X = x_pfas; n = N_PFAS; }
    else if (b < T64_PF + T64_GW) { mode = 1; tile = b - T64_PF;           X = x_gw;   n = N_GW; }
    else                          { mode = 2; tile = b - T64_PF - T64_GW;  X = x_sw;   n = N_SW; }
    const int lane = tid & 63;
    const int w    = tid >> 6;
    const int rbase = tile * 64 + w * 16;
    _Float16* sX = (_Float16*)smem + (size_t)w * 16 * SSTR;   // per-wave region

    // Coalesced X-stage: wave loads its 16-row (8KB contiguous) subtile,
    // converting f32->f16 in flight. Each lane: 8 float4 loads, 8B LDS writes.
    const float* Xt = X + (size_t)rbase * 128;
    const int rows_left = n - rbase;
#pragma unroll
    for (int t = 0; t < 8; ++t) {
        int idx = t * 64 + lane;
        int rr = idx >> 5, c4 = idx & 31;
        float4 xv = make_float4(0.f, 0.f, 0.f, 0.f);
        if (rr < rows_left) xv = *(const float4*)(Xt + rr * 128 + c4 * 4);
        f16x4 v;
        v[0] = (_Float16)xv.x; v[1] = (_Float16)xv.y;
        v[2] = (_Float16)xv.z; v[3] = (_Float16)xv.w;
        *(f16x4*)(sX + rr * SSTR + c4 * 4) = v;
    }
    // a-frags from LDS: single ds_read_b128 per ks, bank-uniform.
    f16x8 a[4];
#pragma unroll
    for (int ks = 0; ks < 4; ++ks)
        a[ks] = *(const f16x8*)(sX + (lane & 15) * SSTR + ks * 32 + (lane >> 4) * 8);

    if (mode == 0) {
        mfma_one_B16(WtF_pg,  a, sX, rbase, n, lane, bufT_pg);
        mfma_one_B16(WtF_ps,  a, sX, rbase, n, lane, bufT_ps);
        mfma_one_B32(WtFR_pf, a, rbase, n, lane, R_pf);
    } else if (mode == 1) {
        mfma_one_B16(WtF_gp,  a, sX, rbase, n, lane, bufT_gp);
        mfma_one_B16(WtFR_gw, a, sX, rbase, n, lane, R_gw);
    } else {
        mfma_one_B16(WtF_sp,  a, sX, rbase, n, lane, bufT_sp);
        mfma_one_B16(WtFR_sw, a, sX, rbase, n, lane, R_sw);
    }
}

// ---------------------------------------------------------------------------
// unbin: one 512-thread block per bucket. Computes its own bucket offset
// (prefix over gcursor, reduced in the sPerm space) — no scan dispatch.
// Per-node counts via LDS atomics, LDS scan -> off_all, scatter into LDS
// segment, stream out compacted.
// ---------------------------------------------------------------------------
__global__ __launch_bounds__(512) void unbin_kernel(
    const unsigned* __restrict__ pairs, const int* __restrict__ gcursor,
    int* __restrict__ off_all, int* __restrict__ perm_all)
{
    __shared__ int sPerm[SEG_CAP];
    __shared__ int cnt[256];
    __shared__ int sp[256];
    __shared__ int cur[256];
    const int b = blockIdx.x;
    const int nb0 = b << 8;
    const int nb1 = min(nb0 + 256, NTOT);
    const int tid = threadIdx.x;

    // bucket offset = prefix sum of gcursor[0..b-1] (reduce in sPerm space)
    int* red = sPerm;
    int part = 0;
    for (int i = tid; i < b; i += 512) part += gcursor[i];
    red[tid] = part;
    __syncthreads();
    for (int ofs = 256; ofs > 0; ofs >>= 1) {
        if (tid < ofs) red[tid] += red[tid + ofs];
        __syncthreads();
    }
    const int obase = red[0];
    int len = gcursor[b];
    if (len > SEG_CAP) len = SEG_CAP;
    const unsigned* reg = pairs + (size_t)b * SEG_CAP;

    if (tid < 256) cnt[tid] = 0;
    __syncthreads();                      // also fences red[0] reads vs sPerm reuse
    for (int i = tid; i < len; i += 512)
        atomicAdd(&cnt[reg[i] & 255u], 1);
    __syncthreads();
    int v = (tid < 256) ? cnt[tid] : 0;
    if (tid < 256) sp[tid] = v;
    __syncthreads();
    for (int ofs = 1; ofs < 256; ofs <<= 1) {
        int add = (tid < 256 && tid >= ofs) ? sp[tid - ofs] : 0;
        __syncthreads();
        if (tid < 256) sp[tid] += add;
        __syncthreads();
    }
    if (tid < 256) {
        int excl = sp[tid] - v;
        cur[tid] = excl;
        if (nb0 + tid < nb1) off_all[nb0 + tid] = obase + excl;
    }
    __syncthreads();

    for (int i = tid; i < len; i += 512) {
        unsigned p = reg[i];
        int pos = atomicAdd(&cur[p & 255u], 1);
        sPerm[pos] = (int)(p >> 8);
    }
    __syncthreads();
    for (int i = tid; i < len; i += 512)
        perm_all[obase + i] = sPerm[i];
}

// ---------------------------------------------------------------------------
// Merged gather dispatch: GEMM-free, LDS-free, barrier-free.
//  blocks [0, SEGP): pfas nodes — gp-gather + sp-gather + R_pf + biases +
//    relu -> h_pf directly (pf_final fused; contrib buffers eliminated).
//  blocks [SEGP, +GW+SW): gw/sw node pass, 32 nodes/block, 2 rows/group.
// ---------------------------------------------------------------------------
__global__ __launch_bounds__(512, 8) void gather_all_kernel(
    const _Float16* __restrict__ R_gw, const _Float16* __restrict__ R_sw,
    const float* __restrict__ bl_pg, const float* __restrict__ bl_ps,
    const unsigned short* __restrict__ bufT_pg,
    const unsigned short* __restrict__ bufT_ps,
    const unsigned short* __restrict__ bufT_gp,
    const unsigned short* __restrict__ bufT_sp,
    const int* __restrict__ perm, const int* __restrict__ off_all,
    const float* __restrict__ W_gw, const float* __restrict__ b_gw,
    const float* __restrict__ W_sw, const float* __restrict__ b_sw,
    float* __restrict__ o_gw, float* __restrict__ o_sw,
    const float* __restrict__ R_pf,
    const float* __restrict__ bl_gp, const float* __restrict__ bl_sp,
    float* __restrict__ h_pf)
{
    const int b = blockIdx.x;
    const int tid = threadIdx.x;
    const int tx = tid & 31;
    const int g = tid >> 5;

    if (b < SEGP_BLKS) {
        // pfas: both segment means + finalize, one node per 32-lane group
        const int node = b * 16 + g;
        int loG = off_all[BASE_GP + node], hiG = off_all[BASE_GP + node + 1];
        h2_t tlG, thG;
        gather_sum_f16(bufT_gp, perm, loG, hiG, tx, tlG, thG);
        int loS = off_all[BASE_SP + node], hiS = off_all[BASE_SP + node + 1];
        h2_t tlS, thS;
        gather_sum_f16(bufT_sp, perm, loS, hiS, tx, tlS, thS);
        float invG = 1.0f / fmaxf((float)(hiG - loG), 1.0f);
        float invS = 1.0f / fmaxf((float)(hiS - loS), 1.0f);
        float4 rv = ((const float4*)R_pf)[(size_t)node * 32 + tx];
        float4 b1 = ((const float4*)bl_gp)[tx];
        float4 b2 = ((const float4*)bl_sp)[tx];
        float4 o;
        o.x = fmaxf(rv.x + (float)tlG.x * invG + (float)tlS.x * invS + b1.x + b2.x, 0.f);
        o.y = fmaxf(rv.y + (float)tlG.y * invG + (float)tlS.y * invS + b1.y + b2.y, 0.f);
        o.z = fmaxf(rv.z + (float)thG.x * invG + (float)thS.x * invS + b1.z + b2.z, 0.f);
        o.w = fmaxf(rv.w + (float)thG.y * invG + (float)thS.y * invS + b1.w + b2.w, 0.f);
        ((float4*)h_pf)[(size_t)node * 32 + tx] = o;
    } else {
        const int bb = b - SEGP_BLKS;
        int n; const _Float16* R; const float* bl; const unsigned short* bufT16;
        const int* off; const float* wout; const float* bout; float* out; int tile;
        if (bb < GW_BLKS) {
            n = N_GW; R = R_gw; bl = bl_pg; bufT16 = bufT_pg; off = off_all + BASE_PG;
            wout = W_gw; bout = b_gw; out = o_gw; tile = bb;
        } else {
            n = N_SW; R = R_sw; bl = bl_ps; bufT16 = bufT_ps; off = off_all + BASE_PS;
            wout = W_sw; bout = b_sw; out = o_sw; tile = bb - GW_BLKS;
        }
        const int rbase = tile * 32 + g * 2;
        float4 bv = ((const float4*)bl)[tx];
        float4 wo = ((const float4*)wout)[tx];
        float bo = bout[0];
#pragma unroll
        for (int rr = 0; rr < 2; ++rr) {
            int r = rbase + rr;
            int lo = 0, hi = 0;
            if (r < n) { lo = off[r]; hi = off[r + 1]; }
            h2_t tl, th;
            gather_sum_f16(bufT16, perm, lo, hi, tx, tl, th);
            float4 rf = make_float4(0.f, 0.f, 0.f, 0.f);
            if (r < n) {
                uint2 rv = *(const uint2*)((const unsigned short*)R + ((size_t)r << 7) + tx * 4);
                h2_t r01 = u2h2(rv.x), r23 = u2h2(rv.y);
                rf = make_float4((float)r01.x, (float)r01.y, (float)r23.x, (float)r23.y);
            }
            float inv = 1.0f / fmaxf((float)(hi - lo), 1.0f);
            float h0  = fmaxf(rf.x + bv.x + (float)tl.x * inv, 0.f);
            float h1  = fmaxf(rf.y + bv.y + (float)tl.y * inv, 0.f);
            float h2v = fmaxf(rf.z + bv.z + (float)th.x * inv, 0.f);
            float h3  = fmaxf(rf.w + bv.w + (float)th.y * inv, 0.f);
            float pv = h0 * wo.x + h1 * wo.y + h2v * wo.z + h3 * wo.w;
            pv += __shfl_xor(pv, 1, 32);
            pv += __shfl_xor(pv, 2, 32);
            pv += __shfl_xor(pv, 4, 32);
            pv += __shfl_xor(pv, 8, 32);
            pv += __shfl_xor(pv, 16, 32);
            if (tx == 0 && r < n) out[r] = pv + bo;
        }
    }
}

// ---------------------------------------------------------------------------
// Launch: 4 dispatches (prep -> trans_bin -> unbin -> gather).
// ---------------------------------------------------------------------------
extern "C" void kernel_launch(void* const* d_in, const int* in_sizes, int n_in,
                              void* d_out, int out_size, void* d_ws, size_t ws_size,
                              hipStream_t stream)
{
    const float* x_pfas = (const float*)d_in[0];
    const float* x_gw   = (const float*)d_in[1];
    const float* x_sw   = (const float*)d_in[2];
    const int* ei_pg_src = (const int*)d_in[3];
    const int* ei_pg_dst = (const int*)d_in[4];
    const int* ei_gp_src = (const int*)d_in[5];
    const int* ei_gp_dst = (const int*)d_in[6];
    const int* ei_ps_src = (const int*)d_in[7];
    const int* ei_ps_dst = (const int*)d_in[8];
    const int* ei_sp_src = (const int*)d_in[9];
    const int* ei_sp_dst = (const int*)d_in[10];
    const float* Wl_pg = (const float*)d_in[11];
    const float* bl_pg = (const float*)d_in[12];
    const float* Wr_pg = (const float*)d_in[13];
    const float* Wl_gp = (const float*)d_in[14];
    const float* bl_gp = (const float*)d_in[15];
    const float* Wr_gp = (const float*)d_in[16];
    const float* Wl_ps = (const float*)d_in[17];
    const float* bl_ps = (const float*)d_in[18];
    const float* Wr_ps = (const float*)d_in[19];
    const float* Wl_sp = (const float*)d_in[20];
    const float* bl_sp = (const float*)d_in[21];
    const float* Wr_sp = (const float*)d_in[22];
    const float* W_gw = (const float*)d_in[23];
    const float* b_gw = (const float*)d_in[24];
    const float* W_sw = (const float*)d_in[25];
    const float* b_sw = (const float*)d_in[26];

    float* out  = (float*)d_out;
    float* h_pf = out;                         // 20000*128
    float* o_gw = out + (size_t)N_PFAS * 128;  // 100000
    float* o_sw = o_gw + N_GW;                 // 30000

    // ---- workspace layout (~125 MB) ----
    char* p = (char*)d_ws;
    auto alloc = [&](size_t bytes) { char* q = p; p += (bytes + 15) & ~(size_t)15; return q; };
    unsigned short* bufT_pg = (unsigned short*)alloc((size_t)N_PFAS * 128 * 2);
    unsigned short* bufT_ps = (unsigned short*)alloc((size_t)N_PFAS * 128 * 2);
    unsigned short* bufT_gp = (unsigned short*)alloc((size_t)N_GW * 128 * 2);
    unsigned short* bufT_sp = (unsigned short*)alloc((size_t)N_SW * 128 * 2);
    _Float16* R_gw = (_Float16*)alloc((size_t)N_GW * 128 * 2);
    _Float16* R_sw = (_Float16*)alloc((size_t)N_SW * 128 * 2);
    float* R_pf = (float*)alloc((size_t)N_PFAS * 128 * 4);
    int* perm_all   = (int*)alloc((size_t)E_TOT * 4);
    unsigned* pairs = (unsigned*)alloc((size_t)NB * SEG_CAP * 4);   // 24.5 MB
    int* off_all    = (int*)alloc((size_t)(NTOT + 1) * 4);
    int* gcursor    = (int*)alloc((size_t)NB * 4);
    _Float16* WtF_pg  = (_Float16*)alloc(16384 * 2);
    _Float16* WtF_ps  = (_Float16*)alloc(16384 * 2);
    _Float16* WtFR_pf = (_Float16*)alloc(16384 * 2);
    _Float16* WtF_gp  = (_Float16*)alloc(16384 * 2);
    _Float16* WtFR_gw = (_Float16*)alloc(16384 * 2);
    _Float16* WtF_sp  = (_Float16*)alloc(16384 * 2);
    _Float16* WtFR_sw = (_Float16*)alloc(16384 * 2);

    // ---- 1. weight prep (+ gcursor zero, off_all[NTOT]) ----
    prep_wt_kernel<<<28, 256, 0, stream>>>(
        Wl_pg, Wl_ps, Wr_gp, Wr_sp, Wl_gp, Wr_pg, Wl_sp, Wr_ps,
        WtF_pg, WtF_ps, WtFR_pf, WtF_gp, WtFR_gw, WtF_sp, WtFR_sw,
        gcursor, off_all);

    // ---- 2. mega dispatch: MFMA transforms + edge binning ----
    trans_bin_kernel<<<BIN_NBLK + T64_ALL, 256, 0, stream>>>(
        x_pfas, x_gw, x_sw,
        WtF_pg, WtF_ps, WtFR_pf, WtF_gp, WtFR_gw, WtF_sp, WtFR_sw,
        (_Float16*)bufT_pg, (_Float16*)bufT_ps, R_pf,
        (_Float16*)bufT_gp, R_gw, (_Float16*)bufT_sp, R_sw,
        ei_pg_src, ei_pg_dst, ei_ps_src, ei_ps_dst,
        ei_gp_src, ei_gp_dst, ei_sp_src, ei_sp_dst,
        gcursor, pairs);

    // ---- 3. CSR finalize (self-prefixing unbin) ----
    unbin_kernel<<<NB, 512, 0, stream>>>(pairs, gcursor, off_all, perm_all);

    // ---- 4. merged gather: pfas (gp+sp+finalize) + gw/sw node passes ----
    gather_all_kernel<<<SEGP_BLKS + GW_BLKS + SW_BLKS, 512, 0, stream>>>(
        R_gw, R_sw, bl_pg, bl_ps, bufT_pg, bufT_ps, bufT_gp, bufT_sp,
        perm_all, off_all, W_gw, b_gw, W_sw, b_sw, o_gw, o_sw,
        R_pf, bl_gp, bl_sp, h_pf);
}